// Round 2
// baseline (2066.094 us; speedup 1.0000x reference)
//
#include <hip/hip_runtime.h>
#include <hip/hip_bf16.h>

typedef __hip_bfloat16 bf16;
typedef short s8v __attribute__((ext_vector_type(8)));
typedef float f4v __attribute__((ext_vector_type(4)));

__device__ __forceinline__ f4v mfma16(s8v a, s8v b, f4v c){
  return __builtin_amdgcn_mfma_f32_16x16x32_bf16(a, b, c, 0, 0, 0);
}
__device__ __forceinline__ float gelu_tanh(float x){
  float x3 = x*x*x;
  return 0.5f*x*(1.0f + tanhf(0.7978845608028654f*(x + 0.044715f*x3)));
}

// ---------------- sentinel fill (encodes ws_size in MB * 16) ----------------
__global__ void k_fill(float* out, int n, float val){
  int i = blockIdx.x*256 + threadIdx.x;
  if (i < n) out[i] = val;
}

// ---------------- weight prep: transpose Wk/Wq to [d][j] bf16, cast conv1_w ----------------
__global__ __launch_bounds__(256) void k_prep(const float* __restrict__ Wk, const float* __restrict__ Wq,
                       const float* __restrict__ c1wf,
                       bf16* __restrict__ Wkt, bf16* __restrict__ Wqt, bf16* __restrict__ c1w){
  int tid = blockIdx.x*256 + threadIdx.x; // 98304 total
  if (tid < 32768){ int d = tid >> 7, j = tid & 127; Wkt[tid] = __float2bfloat16(Wk[j*256 + d]); }
  else if (tid < 65536){ int r = tid - 32768; int d = r >> 7, j = r & 127; Wqt[r] = __float2bfloat16(Wq[j*256 + d]); }
  else { int r = tid - 65536; c1w[r] = __float2bfloat16(c1wf[r]); }
}

// ---------------- patchify (one batch): NCHW f32 -> patches bf16 [n][1024] + optional Vt [1024][1600] ----------------
__global__ __launch_bounds__(256) void k_patchify(const float* __restrict__ src, int H, int W,
                           int n_off, bf16* __restrict__ dstP, bf16* __restrict__ dstVt){
  __shared__ float tile[64][33];
  int y = blockIdx.y, x0 = blockIdx.x*32;
  int t = threadIdx.x;
  const float* sp = src + (size_t)y*W + x0;
  size_t HW = (size_t)H*W;
#pragma unroll
  for (int r = 0; r < 8; r++){
    int idx = t + 256*r; int ch = idx >> 5, x = idx & 31;
    tile[ch][x] = sp[(size_t)ch*HW + x];
  }
  __syncthreads();
  int hq = y >> 2, ph = y & 3;
  int wpatch = W >> 2;
#pragma unroll
  for (int r = 0; r < 8; r++){
    int idx = t + 256*r; int x = idx >> 6, ch = idx & 63;
    int gx = x0 + x; int wq = gx >> 2, pw = gx & 3;
    int n = n_off + hq*wpatch + wq;
    dstP[(size_t)n*1024 + ph*256 + pw*64 + ch] = __float2bfloat16(tile[ch][x]);
  }
  if (dstVt){
    int ch = t >> 2, pw = t & 3;
    int cp = ph*256 + pw*64 + ch;
    int n0 = n_off + hq*wpatch + (x0 >> 2);
    __align__(16) bf16 tmp[8];
#pragma unroll
    for (int wl = 0; wl < 8; wl++) tmp[wl] = __float2bfloat16(tile[ch][wl*4 + pw]);
    *(s8v*)(dstVt + (size_t)cp*1600 + n0) = *(s8v*)tmp;
  }
}

// ---------------- embedding GEMM (one batch): A=(Np*8,128) bf16 @ Wt(256x128) + bias -> emb (h,n,256) ----------------
__global__ __launch_bounds__(256) void k_emb(const bf16* __restrict__ A, const bf16* __restrict__ Wt,
                      const float* __restrict__ bias, bf16* __restrict__ out, int Np){
  int t = threadIdx.x, w = t >> 6, l = t & 63;
  int l15 = l & 15, lh = l >> 4;
  int m0 = blockIdx.x*64 + w*16;
  const s8v* ap = (const s8v*)(A + (size_t)(m0 + l15)*128 + lh*8);
  s8v af[4];
#pragma unroll
  for (int ks = 0; ks < 4; ks++) af[ks] = ap[ks*4];
#pragma unroll
  for (int nt = 0; nt < 16; nt++){
    int d = nt*16 + l15;
    const s8v* bp = (const s8v*)(Wt + (size_t)d*128 + lh*8);
    f4v acc = {0.f,0.f,0.f,0.f};
#pragma unroll
    for (int ks = 0; ks < 4; ks++) acc = mfma16(af[ks], bp[ks*4], acc);
    float bv = bias[d];
#pragma unroll
    for (int j = 0; j < 4; j++){
      int m = m0 + lh*4 + j;
      int n = m >> 3; int h = m & 7;
      out[((size_t)h*Np + n)*256 + d] = __float2bfloat16(acc[j] + bv);
    }
  }
}

// ---------------- fused logits + softmax -> P bf16 (one batch, all heads) ----------------
__global__ __launch_bounds__(256) void k_attn(const bf16* __restrict__ Qemb, const bf16* __restrict__ Kemb,
                       bf16* __restrict__ P){
  __shared__ bf16 Plds[16][1608];
  __shared__ float wred[4][16];
  __shared__ float gred[16];
  int t = threadIdx.x, w = t >> 6, l = t & 63;
  int l15 = l & 15, lh = l >> 4;
  int h = blockIdx.y, qt = blockIdx.x;
  const bf16* qb = Qemb + ((size_t)h*1280 + qt*16 + l15)*256 + lh*8;
  s8v aq[8];
#pragma unroll
  for (int ks = 0; ks < 8; ks++) aq[ks] = *(const s8v*)(qb + ks*32);
  const bf16* kb = Kemb + ((size_t)h*1600)*256;
  f4v accs[25];
#pragma unroll
  for (int i = 0; i < 25; i++){
    int col0 = (w*25 + i)*16;
    const bf16* kp = kb + (size_t)(col0 + l15)*256 + lh*8;
    f4v acc = {0.f,0.f,0.f,0.f};
#pragma unroll
    for (int ks = 0; ks < 8; ks++) acc = mfma16(aq[ks], *(const s8v*)(kp + ks*32), acc);
    accs[i] = acc;
  }
  const float scale = 0.17677669529663687f;
#pragma unroll
  for (int i = 0; i < 25; i++){
#pragma unroll
    for (int j = 0; j < 4; j++) accs[i][j] *= scale;
  }
  float mx[4] = {-1e30f,-1e30f,-1e30f,-1e30f};
#pragma unroll
  for (int i = 0; i < 25; i++){
#pragma unroll
    for (int j = 0; j < 4; j++) mx[j] = fmaxf(mx[j], accs[i][j]);
  }
#pragma unroll
  for (int j = 0; j < 4; j++){
#pragma unroll
    for (int s = 1; s < 16; s <<= 1) mx[j] = fmaxf(mx[j], __shfl_xor(mx[j], s, 16));
  }
  if (l15 == 0){
#pragma unroll
    for (int j = 0; j < 4; j++) wred[w][lh*4 + j] = mx[j];
  }
  __syncthreads();
  if (t < 16) gred[t] = fmaxf(fmaxf(wred[0][t], wred[1][t]), fmaxf(wred[2][t], wred[3][t]));
  __syncthreads();
  float gm[4], sm[4] = {0.f,0.f,0.f,0.f};
#pragma unroll
  for (int j = 0; j < 4; j++) gm[j] = gred[lh*4 + j];
#pragma unroll
  for (int i = 0; i < 25; i++){
#pragma unroll
    for (int j = 0; j < 4; j++){
      float e = expf(accs[i][j] - gm[j]);
      accs[i][j] = e;
      sm[j] += e;
    }
  }
#pragma unroll
  for (int j = 0; j < 4; j++){
#pragma unroll
    for (int s = 1; s < 16; s <<= 1) sm[j] += __shfl_xor(sm[j], s, 16);
  }
  if (l15 == 0){
#pragma unroll
    for (int j = 0; j < 4; j++) wred[w][lh*4 + j] = sm[j];
  }
  __syncthreads();
  if (t < 16) gred[t] = wred[0][t] + wred[1][t] + wred[2][t] + wred[3][t];
  __syncthreads();
  float inv[4];
#pragma unroll
  for (int j = 0; j < 4; j++) inv[j] = 1.0f / gred[lh*4 + j];
#pragma unroll
  for (int i = 0; i < 25; i++){
    int col = (w*25 + i)*16 + l15;
#pragma unroll
    for (int j = 0; j < 4; j++) Plds[lh*4 + j][col] = __float2bfloat16(accs[i][j]*inv[j]);
  }
  __syncthreads();
  bf16* pg = P + ((size_t)h*1280 + qt*16)*1600;
#pragma unroll
  for (int rr = 0; rr < 16; rr++){
    for (int c = t; c < 1600; c += 256) pg[(size_t)rr*1600 + c] = Plds[rr][c];
  }
}

// ---------------- wv GEMM (one batch): O = P @ blockdiag(V0,V1), scatter into NHWC conv input ----------------
__global__ __launch_bounds__(256) void k_wv(const bf16* __restrict__ P, const bf16* __restrict__ Vt,
                     bf16* __restrict__ v0, bf16* __restrict__ v1){
  __shared__ bf16 At[128][40];
  __shared__ bf16 Bt[128][40];
  int mt = blockIdx.x, nt = blockIdx.y, h = blockIdx.z;
  int t = threadIdx.x, w = t >> 6, l = t & 63;
  int l15 = l & 15, lh = l >> 4;
  int wr = w >> 1, wc = w & 1;
  const bf16* Ab = P + ((size_t)h*1280 + mt*128)*1600;
  const bf16* Bb = Vt + ((size_t)nt*128)*1600;
  for (int ksrc = 0; ksrc < 2; ksrc++){
    int nkt = ksrc ? 18 : 32;
    int koff = ksrc ? 1024 : 0;
    f4v acc[4][4];
#pragma unroll
    for (int m = 0; m < 4; m++)
#pragma unroll
      for (int n = 0; n < 4; n++) acc[m][n] = (f4v){0.f,0.f,0.f,0.f};
    for (int kt = 0; kt < nkt; kt++){
      int kbase = koff + kt*32;
#pragma unroll
      for (int r = 0; r < 2; r++){
        int idx = r*256 + t; int row = idx >> 2, kc = idx & 3;
        *(uint4*)&At[row][kc*8] = *(const uint4*)(Ab + (size_t)row*1600 + kbase + kc*8);
        *(uint4*)&Bt[row][kc*8] = *(const uint4*)(Bb + (size_t)row*1600 + kbase + kc*8);
      }
      __syncthreads();
      s8v af[4], bfr[4];
#pragma unroll
      for (int m = 0; m < 4; m++) af[m] = *(const s8v*)&At[wr*64 + m*16 + l15][lh*8];
#pragma unroll
      for (int n = 0; n < 4; n++) bfr[n] = *(const s8v*)&Bt[wc*64 + n*16 + l15][lh*8];
#pragma unroll
      for (int m = 0; m < 4; m++)
#pragma unroll
        for (int n = 0; n < 4; n++) acc[m][n] = mfma16(af[m], bfr[n], acc[m][n]);
      __syncthreads();
    }
#pragma unroll
    for (int m = 0; m < 4; m++){
      int rq_base = mt*128 + wr*64 + m*16 + lh*4;
#pragma unroll
      for (int n = 0; n < 4; n++){
        int col = nt*128 + wc*64 + n*16 + l15;
        int ph = col >> 8, pw = (col >> 6) & 3, c = col & 63;
        int ch = h*128 + ksrc*64 + c;
#pragma unroll
        for (int j = 0; j < 4; j++){
          int rq = rq_base + j;
          float val = acc[m][n][j];
          if (rq < 1024){
            int hq = rq >> 5, wq = rq & 31;
            v0[((size_t)(hq*4 + ph)*128 + (wq*4 + pw))*1024 + ch] = __float2bfloat16(val);
          } else {
            int rl = rq - 1024; int hq = rl >> 4, wq = rl & 15;
            v1[((size_t)(hq*4 + ph)*64 + (wq*4 + pw))*1024 + ch] = __float2bfloat16(val);
          }
        }
      }
    }
  }
}

// ---------------- conv1 (grouped 1x1, 1024->256, groups=8) + GELU, NHWC ----------------
__global__ __launch_bounds__(256) void k_conv1(const bf16* __restrict__ v, const bf16* __restrict__ c1w,
                        const float* __restrict__ bias, bf16* __restrict__ h1){
  int t = threadIdx.x, w = t >> 6, l = t & 63;
  int l15 = l & 15, lh = l >> 4;
  size_t row0 = (size_t)blockIdx.x*64 + w*16;
  const s8v* ap = (const s8v*)(v + (row0 + l15)*1024 + lh*8);
#pragma unroll
  for (int g = 0; g < 8; g++){
    s8v af[4];
#pragma unroll
    for (int ks = 0; ks < 4; ks++) af[ks] = ap[g*16 + ks*4];
#pragma unroll
    for (int ntl = 0; ntl < 2; ntl++){
      int o = g*32 + ntl*16 + l15;
      const s8v* bp = (const s8v*)(c1w + (size_t)o*128 + lh*8);
      f4v acc = {0.f,0.f,0.f,0.f};
#pragma unroll
      for (int ks = 0; ks < 4; ks++) acc = mfma16(af[ks], bp[ks*4], acc);
      float bv = bias[o];
#pragma unroll
      for (int j = 0; j < 4; j++){
        size_t r = row0 + lh*4 + j;
        h1[r*256 + o] = __float2bfloat16(gelu_tanh(acc[j] + bv));
      }
    }
  }
}

// ---------------- depthwise 3x3 + GELU, NHWC (one batch) ----------------
__global__ __launch_bounds__(256) void k_dw(const bf16* __restrict__ h1, const float* __restrict__ wdw,
                     const float* __restrict__ bdw, bf16* __restrict__ h2, int H, int W){
  size_t tid = (size_t)blockIdx.x*256 + threadIdx.x;
  int cc = (int)(tid & 31);
  size_t pix = tid >> 5;
  int x = (int)(pix % W); size_t by = pix / W; int y = (int)(by % H);
  int ch0 = cc*8;
  float acc[8];
#pragma unroll
  for (int i = 0; i < 8; i++) acc[i] = bdw[ch0 + i];
  for (int dy = -1; dy <= 1; dy++){
    int yy = y + dy; if (yy < 0 || yy >= H) continue;
    for (int dx = -1; dx <= 1; dx++){
      int xx = x + dx; if (xx < 0 || xx >= W) continue;
      s8v vv = *(const s8v*)(h1 + ((size_t)yy*W + xx)*256 + ch0);
#pragma unroll
      for (int i = 0; i < 8; i++){
        float wv = wdw[(ch0 + i)*9 + (dy + 1)*3 + (dx + 1)];
        acc[i] += __bfloat162float(((const bf16*)&vv)[i]) * wv;
      }
    }
  }
  __align__(16) bf16 outv[8];
#pragma unroll
  for (int i = 0; i < 8; i++) outv[i] = __float2bfloat16(gelu_tanh(acc[i]));
  *(s8v*)(h2 + ((size_t)y*W + x)*256 + ch0) = *(s8v*)outv;
}

// ---------------- SE partial sums (one batch) ----------------
__global__ __launch_bounds__(256) void k_se_partial(const bf16* __restrict__ h2, float* __restrict__ partial, int HW){
  int chunk = blockIdx.x, t = threadIdx.x;
  int pc = HW/64;
  const bf16* p = h2 + ((size_t)chunk*pc)*256 + t;
  float s = 0.f;
  for (int i = 0; i < pc; i++) s += __bfloat162float(p[(size_t)i*256]);
  partial[((size_t)chunk*4)*256 + t] = s;
}

// ---------------- SE MLP (one batch): mean -> silu(fc1) -> sigmoid(fc2) ----------------
__global__ __launch_bounds__(256) void k_se_mlp(const float* __restrict__ partial, const float* __restrict__ w1,
                         const float* __restrict__ b1, const float* __restrict__ w2, const float* __restrict__ b2,
                         float* __restrict__ sca, int HW){
  __shared__ float mean[256];
  __shared__ float s1[64];
  int t = threadIdx.x;
  float s = 0.f;
  for (int c = 0; c < 64; c++) s += partial[((size_t)c*4)*256 + t];
  mean[t] = s / (float)HW;
  __syncthreads();
  if (t < 64){
    float a = b1[t];
    for (int k = 0; k < 256; k++) a += w1[t*256 + k]*mean[k];
    s1[t] = a / (1.0f + expf(-a));
  }
  __syncthreads();
  float a = b2[t];
#pragma unroll
  for (int k = 0; k < 64; k++) a += w2[t*64 + k]*s1[k];
  sca[t] = 1.0f/(1.0f + expf(-a));
}

// ---------------- SE scale + conv2 (grouped 1x1, 256->64, groups=8) -> NCHW f32 out (one batch) ----------------
__global__ __launch_bounds__(256) void k_conv2(const bf16* __restrict__ h2, const float* __restrict__ sca,
                        const float* __restrict__ w2c, const float* __restrict__ b2c,
                        float* __restrict__ out, int H, int W){
  __shared__ float wsm[64][32];
  __shared__ float scs[256];
  int t = threadIdx.x;
  size_t pix0 = (size_t)blockIdx.x*256;
  for (int i = t; i < 2048; i += 256) wsm[i >> 5][i & 31] = w2c[i];
  scs[t] = sca[t];
  __syncthreads();
  size_t pix = pix0 + t;
  int y = (int)(pix / W), x = (int)(pix % W);
  const bf16* hp = h2 + pix*256;
#pragma unroll
  for (int g = 0; g < 8; g++){
    float xs[32];
#pragma unroll
    for (int i = 0; i < 32; i++) xs[i] = __bfloat162float(hp[g*32 + i]) * scs[g*32 + i];
#pragma unroll
    for (int ol = 0; ol < 8; ol++){
      int o = g*8 + ol;
      float a = b2c[o];
#pragma unroll
      for (int i = 0; i < 32; i++) a += xs[i]*wsm[o][i];
      out[((size_t)o*H + y)*W + x] = a;
    }
  }
}

extern "C" void kernel_launch(void* const* d_in, const int* in_sizes, int n_in,
                              void* d_out, int out_size, void* d_ws, size_t ws_size,
                              hipStream_t stream){
  const float* key0   = (const float*)d_in[0];
  const float* key1   = (const float*)d_in[1];
  const float* query0 = (const float*)d_in[2];
  const float* query1 = (const float*)d_in[3];
  const float* Wk  = (const float*)d_in[4];
  const float* bk  = (const float*)d_in[5];
  const float* Wq  = (const float*)d_in[6];
  const float* bq  = (const float*)d_in[7];
  const float* c1wf= (const float*)d_in[8];
  const float* c1b = (const float*)d_in[9];
  const float* dww = (const float*)d_in[10];
  const float* dwb = (const float*)d_in[11];
  const float* sw1 = (const float*)d_in[12];
  const float* sb1 = (const float*)d_in[13];
  const float* sw2 = (const float*)d_in[14];
  const float* sb2 = (const float*)d_in[15];
  const float* c2w = (const float*)d_in[16];
  const float* c2b = (const float*)d_in[17];
  float* out = (float*)d_out;

  size_t off = 0;
  auto alloc = [&](size_t bytes){ size_t o = off; off += (bytes + 255) & ~(size_t)255; return o; };
  char* ws = (char*)d_ws;
  size_t oWkt = alloc(65536);
  size_t oWqt = alloc(65536);
  size_t oC1w = alloc(65536);
  size_t oPt  = alloc(262144);
  size_t oSsc = alloc(1024);
  size_t oVt  = alloc((size_t)1024*1600*2);           // 3.28 MB, live patchify->wv
  size_t oX   = alloc((size_t)33554432 + 8388608);    // 41.94 MB region X
  size_t oY   = alloc((size_t)8*1280*1600*2);         // 32.77 MB region Y
  if (ws_size < off){
    // sentinel: encode ws_size so we can decode the budget from absmax
    float v = 16.0f * (float)(ws_size >> 20);
    k_fill<<<(out_size + 255)/256, 256, 0, stream>>>(out, out_size, v);
    return;
  }
  bf16* Wkt = (bf16*)(ws + oWkt);
  bf16* Wqt = (bf16*)(ws + oWqt);
  bf16* C1w = (bf16*)(ws + oC1w);
  float* Pt  = (float*)(ws + oPt);
  float* Ssc = (float*)(ws + oSsc);
  bf16* Vt  = (bf16*)(ws + oVt);
  // region X: phase1 {Kp,Qp,Ke,Qe} -> phase2 {V0,V1}
  bf16* Kp  = (bf16*)(ws + oX);
  bf16* Qp  = (bf16*)(ws + oX + 3276800);
  bf16* Ke  = (bf16*)(ws + oX + 5898240);
  bf16* Qe  = (bf16*)(ws + oX + 12451840);
  bf16* V0  = (bf16*)(ws + oX);
  bf16* V1  = (bf16*)(ws + oX + 33554432);
  // region Y: phase1 {P8} -> phase2 {H1,H2}
  bf16* P8  = (bf16*)(ws + oY);
  bf16* H1  = (bf16*)(ws + oY);
  bf16* H2  = (bf16*)(ws + oY + 8388608);

  k_prep<<<384, 256, 0, stream>>>(Wk, Wq, c1wf, Wkt, Wqt, C1w);

  for (int b = 0; b < 4; b++){
    const float* k0b = key0   + (size_t)b*64*128*128;
    const float* k1b = key1   + (size_t)b*64*96*96;
    const float* q0b = query0 + (size_t)b*64*128*128;
    const float* q1b = query1 + (size_t)b*64*64*64;
    k_patchify<<<dim3(4,128,1), 256, 0, stream>>>(k0b, 128, 128,    0, Kp, Vt);
    k_patchify<<<dim3(3, 96,1), 256, 0, stream>>>(k1b,  96,  96, 1024, Kp, Vt);
    k_patchify<<<dim3(4,128,1), 256, 0, stream>>>(q0b, 128, 128,    0, Qp, nullptr);
    k_patchify<<<dim3(2, 64,1), 256, 0, stream>>>(q1b,  64,  64, 1024, Qp, nullptr);
    k_emb<<<200, 256, 0, stream>>>(Kp, Wkt, bk, Ke, 1600);
    k_emb<<<160, 256, 0, stream>>>(Qp, Wqt, bq, Qe, 1280);
    k_attn<<<dim3(80,8), 256, 0, stream>>>(Qe, Ke, P8);
    k_wv<<<dim3(10,8,8), 256, 0, stream>>>(P8, Vt, V0, V1);   // overwrites Kp..Qe region
    // mbconv source 0 (128x128)  -- H1/H2 overwrite P8 region
    k_conv1<<<256, 256, 0, stream>>>(V0, C1w, c1b, H1);
    k_dw<<<2048, 256, 0, stream>>>(H1, dww, dwb, H2, 128, 128);
    k_se_partial<<<64, 256, 0, stream>>>(H2, Pt, 16384);
    k_se_mlp<<<1, 256, 0, stream>>>(Pt, sw1, sb1, sw2, sb2, Ssc, 16384);
    k_conv2<<<64, 256, 0, stream>>>(H2, Ssc, c2w, c2b, out + (size_t)b*64*16384, 128, 128);
    // mbconv source 1 (64x64)
    k_conv1<<<64, 256, 0, stream>>>(V1, C1w, c1b, H1);
    k_dw<<<512, 256, 0, stream>>>(H1, dww, dwb, H2, 64, 64);
    k_se_partial<<<64, 256, 0, stream>>>(H2, Pt, 4096);
    k_se_mlp<<<1, 256, 0, stream>>>(Pt, sw1, sb1, sw2, sb2, Ssc, 4096);
    k_conv2<<<16, 256, 0, stream>>>(H2, Ssc, c2w, c2b, out + (size_t)4*64*16384 + (size_t)b*64*4096, 64, 64);
  }
}

// Round 3
// 1659.232 us; speedup vs baseline: 1.2452x; 1.2452x over previous
//
#include <hip/hip_runtime.h>
#include <hip/hip_bf16.h>

typedef __hip_bfloat16 bf16;
typedef short s8v __attribute__((ext_vector_type(8)));
typedef float f4v __attribute__((ext_vector_type(4)));

__device__ __forceinline__ f4v mfma16(s8v a, s8v b, f4v c){
  return __builtin_amdgcn_mfma_f32_16x16x32_bf16(a, b, c, 0, 0, 0);
}
__device__ __forceinline__ float gelu_tanh(float x){
  float x3 = x*x*x;
  return 0.5f*x*(1.0f + tanhf(0.7978845608028654f*(x + 0.044715f*x3)));
}

// ---------------- sentinel fill (encodes ws_size in MB * 16) ----------------
__global__ void k_fill(float* out, int n, float val){
  int i = blockIdx.x*256 + threadIdx.x;
  if (i < n) out[i] = val;
}

// ---------------- weight prep ----------------
__global__ __launch_bounds__(256) void k_prep(const float* __restrict__ Wk, const float* __restrict__ Wq,
                       const float* __restrict__ c1wf,
                       bf16* __restrict__ Wkt, bf16* __restrict__ Wqt, bf16* __restrict__ c1w){
  int tid = blockIdx.x*256 + threadIdx.x; // 98304 total
  if (tid < 32768){ int d = tid >> 7, j = tid & 127; Wkt[tid] = __float2bfloat16(Wk[j*256 + d]); }
  else if (tid < 65536){ int r = tid - 32768; int d = r >> 7, j = r & 127; Wqt[r] = __float2bfloat16(Wq[j*256 + d]); }
  else { int r = tid - 65536; c1w[r] = __float2bfloat16(c1wf[r]); }
}

// ---------------- patchify (one batch) ----------------
__global__ __launch_bounds__(256) void k_patchify(const float* __restrict__ src, int H, int W,
                           int n_off, bf16* __restrict__ dstP, bf16* __restrict__ dstVt){
  __shared__ float tile[64][33];
  int y = blockIdx.y, x0 = blockIdx.x*32;
  int t = threadIdx.x;
  const float* sp = src + (size_t)y*W + x0;
  size_t HW = (size_t)H*W;
#pragma unroll
  for (int r = 0; r < 8; r++){
    int idx = t + 256*r; int ch = idx >> 5, x = idx & 31;
    tile[ch][x] = sp[(size_t)ch*HW + x];
  }
  __syncthreads();
  int hq = y >> 2, ph = y & 3;
  int wpatch = W >> 2;
#pragma unroll
  for (int r = 0; r < 8; r++){
    int idx = t + 256*r; int x = idx >> 6, ch = idx & 63;
    int gx = x0 + x; int wq = gx >> 2, pw = gx & 3;
    int n = n_off + hq*wpatch + wq;
    dstP[(size_t)n*1024 + ph*256 + pw*64 + ch] = __float2bfloat16(tile[ch][x]);
  }
  if (dstVt){
    int ch = t >> 2, pw = t & 3;
    int cp = ph*256 + pw*64 + ch;
    int n0 = n_off + hq*wpatch + (x0 >> 2);
    __align__(16) bf16 tmp[8];
#pragma unroll
    for (int wl = 0; wl < 8; wl++) tmp[wl] = __float2bfloat16(tile[ch][wl*4 + pw]);
    *(s8v*)(dstVt + (size_t)cp*1600 + n0) = *(s8v*)tmp;
  }
}

// ---------------- embedding GEMM (one batch), scale folded in ----------------
__global__ __launch_bounds__(256) void k_emb(const bf16* __restrict__ A, const bf16* __restrict__ Wt,
                      const float* __restrict__ bias, bf16* __restrict__ out, int Np, float scale){
  int t = threadIdx.x, w = t >> 6, l = t & 63;
  int l15 = l & 15, lh = l >> 4;
  int m0 = blockIdx.x*64 + w*16;
  const s8v* ap = (const s8v*)(A + (size_t)(m0 + l15)*128 + lh*8);
  s8v af[4];
#pragma unroll
  for (int ks = 0; ks < 4; ks++) af[ks] = ap[ks*4];
#pragma unroll
  for (int nt = 0; nt < 16; nt++){
    int d = nt*16 + l15;
    const s8v* bp = (const s8v*)(Wt + (size_t)d*128 + lh*8);
    f4v acc = {0.f,0.f,0.f,0.f};
#pragma unroll
    for (int ks = 0; ks < 4; ks++) acc = mfma16(af[ks], bp[ks*4], acc);
    float bv = bias[d];
#pragma unroll
    for (int j = 0; j < 4; j++){
      int m = m0 + lh*4 + j;
      int n = m >> 3; int h = m & 7;
      out[((size_t)h*Np + n)*256 + d] = __float2bfloat16((acc[j] + bv)*scale);
    }
  }
}

// ---------------- pass 1: row max + sumexp (one batch), block = 128 q-rows x one head ----------------
__global__ __launch_bounds__(256) void k_stats(const bf16* __restrict__ Qe, const bf16* __restrict__ Ke,
                        float2* __restrict__ stats){
  __shared__ bf16 Ks[64][264];
  int t = threadIdx.x, w = t >> 6, l = t & 63, l15 = l & 15, lh = l >> 4;
  int qt = blockIdx.x, h = blockIdx.y;
  int row0 = qt*128 + w*32;
  s8v qf[2][8];
#pragma unroll
  for (int rt = 0; rt < 2; rt++)
#pragma unroll
    for (int ks = 0; ks < 8; ks++)
      qf[rt][ks] = *(const s8v*)(Qe + ((size_t)h*1280 + row0 + rt*16 + l15)*256 + ks*32 + lh*8);
  float m0[4], s0[4], m1[4], s1[4];
#pragma unroll
  for (int j = 0; j < 4; j++){ m0[j] = -1e30f; s0[j] = 0.f; m1[j] = -1e30f; s1[j] = 0.f; }
  int kr = t >> 2, kq = t & 3;
  for (int kt = 0; kt < 25; kt++){
    const bf16* src = Ke + ((size_t)h*1600 + kt*64 + kr)*256 + kq*64;
    if (kt) __syncthreads();
#pragma unroll
    for (int u = 0; u < 8; u++){
      int sw = (kq*8 + u) ^ (kr & 7);
      *(uint4*)&Ks[kr][sw*8] = *(const uint4*)(src + u*8);
    }
    __syncthreads();
    f4v a0[4], a1[4];
#pragma unroll
    for (int ct = 0; ct < 4; ct++){ a0[ct] = (f4v){0.f,0.f,0.f,0.f}; a1[ct] = (f4v){0.f,0.f,0.f,0.f}; }
#pragma unroll
    for (int ct = 0; ct < 4; ct++){
      int krow = ct*16 + l15;
#pragma unroll
      for (int ks = 0; ks < 8; ks++){
        s8v bf = *(const s8v*)&Ks[krow][((ks*4 + lh) ^ (krow & 7))*8];
        a0[ct] = mfma16(qf[0][ks], bf, a0[ct]);
        a1[ct] = mfma16(qf[1][ks], bf, a1[ct]);
      }
    }
#pragma unroll
    for (int j = 0; j < 4; j++){
      float vm = fmaxf(fmaxf(a0[0][j], a0[1][j]), fmaxf(a0[2][j], a0[3][j]));
      float mn = fmaxf(m0[j], vm);
      s0[j] = s0[j]*__expf(m0[j]-mn) + __expf(a0[0][j]-mn) + __expf(a0[1][j]-mn) + __expf(a0[2][j]-mn) + __expf(a0[3][j]-mn);
      m0[j] = mn;
      vm = fmaxf(fmaxf(a1[0][j], a1[1][j]), fmaxf(a1[2][j], a1[3][j]));
      mn = fmaxf(m1[j], vm);
      s1[j] = s1[j]*__expf(m1[j]-mn) + __expf(a1[0][j]-mn) + __expf(a1[1][j]-mn) + __expf(a1[2][j]-mn) + __expf(a1[3][j]-mn);
      m1[j] = mn;
    }
  }
#pragma unroll
  for (int j = 0; j < 4; j++){
    float mm = m0[j], ss = s0[j];
#pragma unroll
    for (int d = 1; d < 16; d <<= 1){
      float mo = __shfl_xor(mm, d); float so = __shfl_xor(ss, d);
      float mn = fmaxf(mm, mo); ss = ss*__expf(mm-mn) + so*__expf(mo-mn); mm = mn;
    }
    if (l15 == 0) stats[(size_t)h*1280 + row0 + lh*4 + j] = (float2){mm, 1.0f/ss};
    mm = m1[j]; ss = s1[j];
#pragma unroll
    for (int d = 1; d < 16; d <<= 1){
      float mo = __shfl_xor(mm, d); float so = __shfl_xor(ss, d);
      float mn = fmaxf(mm, mo); ss = ss*__expf(mm-mn) + so*__expf(mo-mn); mm = mn;
    }
    if (l15 == 0) stats[(size_t)h*1280 + row0 + 16 + lh*4 + j] = (float2){mm, 1.0f/ss};
  }
}

// ---------------- pass 2: recompute logits -> P bf16 (one batch) ----------------
__global__ __launch_bounds__(256) void k_psm(const bf16* __restrict__ Qe, const bf16* __restrict__ Ke,
                      const float2* __restrict__ stats, bf16* __restrict__ P){
  __shared__ bf16 Ks[64][264];
  __shared__ bf16 Pw[4][32][134];
  int t = threadIdx.x, w = t >> 6, l = t & 63, l15 = l & 15, lh = l >> 4;
  int qt = blockIdx.x, h = blockIdx.y;
  int row0 = qt*128 + w*32;
  s8v qf[2][8];
#pragma unroll
  for (int rt = 0; rt < 2; rt++)
#pragma unroll
    for (int ks = 0; ks < 8; ks++)
      qf[rt][ks] = *(const s8v*)(Qe + ((size_t)h*1280 + row0 + rt*16 + l15)*256 + ks*32 + lh*8);
  float mm0[4], iv0[4], mm1[4], iv1[4];
#pragma unroll
  for (int j = 0; j < 4; j++){
    float2 st = stats[(size_t)h*1280 + row0 + lh*4 + j];      mm0[j] = st.x; iv0[j] = st.y;
    float2 s2 = stats[(size_t)h*1280 + row0 + 16 + lh*4 + j]; mm1[j] = s2.x; iv1[j] = s2.y;
  }
  int kr = t >> 2, kq = t & 3;
  size_t prow_base = (size_t)h*1280 + row0;
  for (int kt = 0; kt < 25; kt++){
    const bf16* src = Ke + ((size_t)h*1600 + kt*64 + kr)*256 + kq*64;
    if (kt) __syncthreads();
#pragma unroll
    for (int u = 0; u < 8; u++){
      int sw = (kq*8 + u) ^ (kr & 7);
      *(uint4*)&Ks[kr][sw*8] = *(const uint4*)(src + u*8);
    }
    __syncthreads();
    f4v a0[4], a1[4];
#pragma unroll
    for (int ct = 0; ct < 4; ct++){ a0[ct] = (f4v){0.f,0.f,0.f,0.f}; a1[ct] = (f4v){0.f,0.f,0.f,0.f}; }
#pragma unroll
    for (int ct = 0; ct < 4; ct++){
      int krow = ct*16 + l15;
#pragma unroll
      for (int ks = 0; ks < 8; ks++){
        s8v bf = *(const s8v*)&Ks[krow][((ks*4 + lh) ^ (krow & 7))*8];
        a0[ct] = mfma16(qf[0][ks], bf, a0[ct]);
        a1[ct] = mfma16(qf[1][ks], bf, a1[ct]);
      }
    }
#pragma unroll
    for (int ct = 0; ct < 4; ct++){
      int local = (kt*4 + ct) & 7;
#pragma unroll
      for (int j = 0; j < 4; j++){
        Pw[w][lh*4 + j][local*16 + l15]      = __float2bfloat16(__expf(a0[ct][j] - mm0[j])*iv0[j]);
        Pw[w][16 + lh*4 + j][local*16 + l15] = __float2bfloat16(__expf(a1[ct][j] - mm1[j])*iv1[j]);
      }
    }
    if (kt & 1){
      int ci = kt >> 1;
#pragma unroll
      for (int p = 0; p < 8; p++){
        int s = p*8 + (l >> 3);
        int row = s >> 1, half = s & 1;
        *(uint4*)(P + (prow_base + row)*1600 + ci*128 + half*64 + (l & 7)*8) =
          *(uint4*)&Pw[w][row][half*64 + (l & 7)*8];
      }
    }
  }
  // tail: last 64 cols (col-tiles 96..99 at local 0..3)
#pragma unroll
  for (int p = 0; p < 4; p++){
    int row = p*8 + (l >> 3);
    *(uint4*)(P + (prow_base + row)*1600 + 1536 + (l & 7)*8) =
      *(uint4*)&Pw[w][row][(l & 7)*8];
  }
}

// ---------------- wv GEMM (one batch) + fused conv1+GELU -> H1 (NHWC) ----------------
__global__ __launch_bounds__(256) void k_wv(const bf16* __restrict__ P, const bf16* __restrict__ Vt,
                     const bf16* __restrict__ c1w, const float* __restrict__ c1b,
                     bf16* __restrict__ h1_0, bf16* __restrict__ h1_1){
  __shared__ bf16 At[128][40];
  __shared__ bf16 Bt[128][40];
  __shared__ bf16 Ot[256][70];
  __shared__ bf16 W1s[32][136];
  int mt = blockIdx.x, nt = blockIdx.y, h = blockIdx.z;
  int t = threadIdx.x, w = t >> 6, l = t & 63;
  int l15 = l & 15, lh = l >> 4;
  int wr = w >> 1, wc = w & 1;
  {
    int r = t >> 3, sg = (t & 7)*2;
    *(uint4*)&W1s[r][sg*8]     = *(const uint4*)(c1w + ((size_t)h*32 + r)*128 + sg*8);
    *(uint4*)&W1s[r][sg*8 + 8] = *(const uint4*)(c1w + ((size_t)h*32 + r)*128 + sg*8 + 8);
  }
  const bf16* Ab = P + ((size_t)h*1280 + mt*128)*1600;
  const bf16* Bb = Vt + ((size_t)nt*128)*1600;
  f4v acc2[4][2];
#pragma unroll
  for (int mm = 0; mm < 4; mm++)
#pragma unroll
    for (int nn = 0; nn < 2; nn++) acc2[mm][nn] = (f4v){0.f,0.f,0.f,0.f};
  for (int ksrc = 0; ksrc < 2; ksrc++){
    int nkt = ksrc ? 18 : 32;
    int koff = ksrc ? 1024 : 0;
    f4v acc[4][4];
#pragma unroll
    for (int m = 0; m < 4; m++)
#pragma unroll
      for (int n = 0; n < 4; n++) acc[m][n] = (f4v){0.f,0.f,0.f,0.f};
    for (int kt = 0; kt < nkt; kt++){
      int kbase = koff + kt*32;
#pragma unroll
      for (int r = 0; r < 2; r++){
        int idx = r*256 + t; int row = idx >> 2, kc = idx & 3;
        *(uint4*)&At[row][kc*8] = *(const uint4*)(Ab + (size_t)row*1600 + kbase + kc*8);
        *(uint4*)&Bt[row][kc*8] = *(const uint4*)(Bb + (size_t)row*1600 + kbase + kc*8);
      }
      __syncthreads();
      s8v af[4], bfr[4];
#pragma unroll
      for (int m = 0; m < 4; m++) af[m] = *(const s8v*)&At[wr*64 + m*16 + l15][lh*8];
#pragma unroll
      for (int n = 0; n < 4; n++) bfr[n] = *(const s8v*)&Bt[wc*64 + n*16 + l15][lh*8];
#pragma unroll
      for (int m = 0; m < 4; m++)
#pragma unroll
        for (int n = 0; n < 4; n++) acc[m][n] = mfma16(af[m], bfr[n], acc[m][n]);
      __syncthreads();
    }
    // stage O half-tile (64 cols of this ksrc) to LDS
#pragma unroll
    for (int m = 0; m < 4; m++){
      int rl = wr*64 + m*16 + lh*4;
#pragma unroll
      for (int n = 0; n < 4; n++)
#pragma unroll
        for (int j = 0; j < 4; j++)
          Ot[(rl + j)*2 + wc][n*16 + l15] = __float2bfloat16(acc[m][n][j]);
    }
    __syncthreads();
    // conv1 partial MFMA over this 64-wide K half
    int wpix0 = w*64;
    s8v afc[4][2], bfc[2][2];
#pragma unroll
    for (int mm = 0; mm < 4; mm++)
#pragma unroll
      for (int ks2 = 0; ks2 < 2; ks2++)
        afc[mm][ks2] = *(const s8v*)&Ot[wpix0 + mm*16 + l15][ks2*32 + lh*8];
#pragma unroll
    for (int nn = 0; nn < 2; nn++)
#pragma unroll
      for (int ks2 = 0; ks2 < 2; ks2++)
        bfc[nn][ks2] = *(const s8v*)&W1s[nn*16 + l15][ksrc*64 + ks2*32 + lh*8];
#pragma unroll
    for (int mm = 0; mm < 4; mm++)
#pragma unroll
      for (int nn = 0; nn < 2; nn++)
#pragma unroll
        for (int ks2 = 0; ks2 < 2; ks2++)
          acc2[mm][nn] = mfma16(afc[mm][ks2], bfc[nn][ks2], acc2[mm][nn]);
    __syncthreads();
  }
  float bia[2];
#pragma unroll
  for (int nn = 0; nn < 2; nn++) bia[nn] = c1b[h*32 + nn*16 + l15];
#pragma unroll
  for (int mm = 0; mm < 4; mm++){
#pragma unroll
    for (int nn = 0; nn < 2; nn++){
#pragma unroll
      for (int j = 0; j < 4; j++){
        float v = gelu_tanh(acc2[mm][nn][j] + bia[nn]);
        int pixl = w*64 + mm*16 + lh*4 + j;
        int rl = pixl >> 1, wc2 = pixl & 1;
        int rq = mt*128 + rl;
        int cell = nt*2 + wc2; int ph = cell >> 2, pw = cell & 3;
        int o = h*32 + nn*16 + l15;
        if (rq < 1024){
          int y = ((rq >> 5) << 2) + ph, x = ((rq & 31) << 2) + pw;
          h1_0[((size_t)y*128 + x)*256 + o] = __float2bfloat16(v);
        } else {
          int r2 = rq - 1024;
          int y = ((r2 >> 4) << 2) + ph, x = ((r2 & 15) << 2) + pw;
          h1_1[((size_t)y*64 + x)*256 + o] = __float2bfloat16(v);
        }
      }
    }
  }
}

// ---------------- depthwise 3x3 + GELU, NHWC (nb batches via flat grid) ----------------
__global__ __launch_bounds__(256) void k_dw(const bf16* __restrict__ h1, const float* __restrict__ wdw,
                     const float* __restrict__ bdw, bf16* __restrict__ h2, int H, int W){
  size_t tid = (size_t)blockIdx.x*256 + threadIdx.x;
  int cc = (int)(tid & 31);
  size_t pix = tid >> 5;
  int x = (int)(pix % W); size_t by = pix / W; int y = (int)(by % H); int b = (int)(by / H);
  int ch0 = cc*8;
  float acc[8];
#pragma unroll
  for (int i = 0; i < 8; i++) acc[i] = bdw[ch0 + i];
  for (int dy = -1; dy <= 1; dy++){
    int yy = y + dy; if (yy < 0 || yy >= H) continue;
    for (int dx = -1; dx <= 1; dx++){
      int xx = x + dx; if (xx < 0 || xx >= W) continue;
      s8v vv = *(const s8v*)(h1 + (((size_t)b*H + yy)*W + xx)*256 + ch0);
#pragma unroll
      for (int i = 0; i < 8; i++){
        float wv = wdw[(ch0 + i)*9 + (dy + 1)*3 + (dx + 1)];
        acc[i] += __bfloat162float(((const bf16*)&vv)[i]) * wv;
      }
    }
  }
  __align__(16) bf16 outv[8];
#pragma unroll
  for (int i = 0; i < 8; i++) outv[i] = __float2bfloat16(gelu_tanh(acc[i]));
  *(s8v*)(h2 + (((size_t)b*H + y)*W + x)*256 + ch0) = *(s8v*)outv;
}

// ---------------- SE partial sums, grid (64, nb) ----------------
__global__ __launch_bounds__(256) void k_se_partial(const bf16* __restrict__ h2, float* __restrict__ partial, int HW){
  int chunk = blockIdx.x, b = blockIdx.y, t = threadIdx.x;
  int pc = HW/64;
  const bf16* p = h2 + ((size_t)b*HW + (size_t)chunk*pc)*256 + t;
  float s = 0.f;
  for (int i = 0; i < pc; i++) s += __bfloat162float(p[(size_t)i*256]);
  partial[((size_t)b*64 + chunk)*256 + t] = s;
}

// ---------------- SE MLP, grid (nb) ----------------
__global__ __launch_bounds__(256) void k_se_mlp(const float* __restrict__ partial, const float* __restrict__ w1,
                         const float* __restrict__ b1, const float* __restrict__ w2, const float* __restrict__ b2,
                         float* __restrict__ sca, int HW){
  __shared__ float mean[256];
  __shared__ float s1[64];
  int b = blockIdx.x, t = threadIdx.x;
  float s = 0.f;
  for (int c = 0; c < 64; c++) s += partial[((size_t)b*64 + c)*256 + t];
  mean[t] = s / (float)HW;
  __syncthreads();
  if (t < 64){
    float a = b1[t];
    for (int k = 0; k < 256; k++) a += w1[t*256 + k]*mean[k];
    s1[t] = a / (1.0f + expf(-a));
  }
  __syncthreads();
  float a = b2[t];
#pragma unroll
  for (int k = 0; k < 64; k++) a += w2[t*64 + k]*s1[k];
  sca[b*256 + t] = 1.0f/(1.0f + expf(-a));
}

// ---------------- SE scale + conv2 -> NCHW f32, grid (HW/256, nb) ----------------
__global__ __launch_bounds__(256) void k_conv2(const bf16* __restrict__ h2, const float* __restrict__ sca,
                        const float* __restrict__ w2c, const float* __restrict__ b2c,
                        float* __restrict__ out, int H, int W){
  __shared__ float wsm[64][32];
  __shared__ float scs[256];
  int t = threadIdx.x, b = blockIdx.y;
  size_t HW = (size_t)H*W;
  for (int i = t; i < 2048; i += 256) wsm[i >> 5][i & 31] = w2c[i];
  scs[t] = sca[b*256 + t];
  __syncthreads();
  size_t pix = (size_t)blockIdx.x*256 + t;
  int y = (int)(pix / W), x = (int)(pix % W);
  const bf16* hp = h2 + ((size_t)b*HW + pix)*256;
  float* ob = out + (size_t)b*64*HW;
#pragma unroll
  for (int g = 0; g < 8; g++){
    float xs[32];
#pragma unroll
    for (int i = 0; i < 32; i++) xs[i] = __bfloat162float(hp[g*32 + i]) * scs[g*32 + i];
#pragma unroll
    for (int ol = 0; ol < 8; ol++){
      int o = g*8 + ol;
      float a = b2c[o];
#pragma unroll
      for (int i = 0; i < 32; i++) a += xs[i]*wsm[o][i];
      ob[((size_t)o*H + y)*W + x] = a;
    }
  }
}

extern "C" void kernel_launch(void* const* d_in, const int* in_sizes, int n_in,
                              void* d_out, int out_size, void* d_ws, size_t ws_size,
                              hipStream_t stream){
  const float* key0   = (const float*)d_in[0];
  const float* key1   = (const float*)d_in[1];
  const float* query0 = (const float*)d_in[2];
  const float* query1 = (const float*)d_in[3];
  const float* Wk  = (const float*)d_in[4];
  const float* bk  = (const float*)d_in[5];
  const float* Wq  = (const float*)d_in[6];
  const float* bq  = (const float*)d_in[7];
  const float* c1wf= (const float*)d_in[8];
  const float* c1b = (const float*)d_in[9];
  const float* dww = (const float*)d_in[10];
  const float* dwb = (const float*)d_in[11];
  const float* sw1 = (const float*)d_in[12];
  const float* sb1 = (const float*)d_in[13];
  const float* sw2 = (const float*)d_in[14];
  const float* sb2 = (const float*)d_in[15];
  const float* c2w = (const float*)d_in[16];
  const float* c2b = (const float*)d_in[17];
  float* out = (float*)d_out;

  size_t off = 0;
  auto alloc = [&](size_t bytes){ size_t o = off; off += (bytes + 255) & ~(size_t)255; return o; };
  char* ws = (char*)d_ws;
  size_t oWkt = alloc(65536);
  size_t oWqt = alloc(65536);
  size_t oC1w = alloc(65536);
  size_t oSt  = alloc(81920);        // stats 8*1280*float2
  size_t oPt  = alloc(262144);       // SE partials [4][64][256] f32
  size_t oSsc = alloc(4096);         // SE scales [4][256]
  size_t oVt  = alloc(3276800);      // per-batch Vt [1024][1600] bf16  (alias region starts here)
  size_t oKp  = alloc(3276800);
  size_t oQp  = alloc(2621440);
  size_t oKe  = alloc(6553600);
  size_t oQe  = alloc(5242880);
  size_t oP   = alloc(32768000);     // per-batch P [8][1280][1600] bf16
  size_t aliasEnd = off;             // alias span oVt..aliasEnd = ~53.7MB >= 41.94MB (H2 batched)
  size_t oH1  = alloc((size_t)41943040 + 256);   // batched H1: [4][16384][256] + [4][4096][256]
  size_t needA = off;
  bool tierA = ws_size >= needA;
  size_t oH1s = 0, oH2s = 0;
  if (!tierA){
    off = aliasEnd;
    oH1s = alloc(10485760);          // per-batch H1 (both sources)
    oH2s = alloc(10485760);
    if (ws_size < off){
      float v = 16.0f * (float)(ws_size >> 20);
      k_fill<<<(out_size + 255)/256, 256, 0, stream>>>(out, out_size, v);
      return;
    }
  }
  bf16* Wkt = (bf16*)(ws + oWkt);
  bf16* Wqt = (bf16*)(ws + oWqt);
  bf16* C1w = (bf16*)(ws + oC1w);
  float2* St = (float2*)(ws + oSt);
  float* Pt  = (float*)(ws + oPt);
  float* Ssc = (float*)(ws + oSsc);
  bf16* Vt  = (bf16*)(ws + oVt);
  bf16* Kp  = (bf16*)(ws + oKp);
  bf16* Qp  = (bf16*)(ws + oQp);
  bf16* Ke  = (bf16*)(ws + oKe);
  bf16* Qe  = (bf16*)(ws + oQe);
  bf16* P8  = (bf16*)(ws + oP);

  k_prep<<<384, 256, 0, stream>>>(Wk, Wq, c1wf, Wkt, Wqt, C1w);

  const float qscale = 0.17677669529663687f; // 1/sqrt(32)
  for (int b = 0; b < 4; b++){
    const float* k0b = key0   + (size_t)b*64*128*128;
    const float* k1b = key1   + (size_t)b*64*96*96;
    const float* q0b = query0 + (size_t)b*64*128*128;
    const float* q1b = query1 + (size_t)b*64*64*64;
    k_patchify<<<dim3(4,128,1), 256, 0, stream>>>(k0b, 128, 128,    0, Kp, Vt);
    k_patchify<<<dim3(3, 96,1), 256, 0, stream>>>(k1b,  96,  96, 1024, Kp, Vt);
    k_patchify<<<dim3(4,128,1), 256, 0, stream>>>(q0b, 128, 128,    0, Qp, nullptr);
    k_patchify<<<dim3(2, 64,1), 256, 0, stream>>>(q1b,  64,  64, 1024, Qp, nullptr);
    k_emb<<<200, 256, 0, stream>>>(Kp, Wkt, bk, Ke, 1600, 1.0f);
    k_emb<<<160, 256, 0, stream>>>(Qp, Wqt, bq, Qe, 1280, qscale);
    k_stats<<<dim3(10,8), 256, 0, stream>>>(Qe, Ke, St);
    k_psm<<<dim3(10,8), 256, 0, stream>>>(Qe, Ke, St, P8);
    bf16* h1_0 = tierA ? (bf16*)(ws + oH1) + (size_t)b*16384*256
                       : (bf16*)(ws + oH1s);
    bf16* h1_1 = tierA ? (bf16*)(ws + oH1 + 33554432) + (size_t)b*4096*256
                       : (bf16*)(ws + oH1s + 8388608);
    k_wv<<<dim3(10,8,8), 256, 0, stream>>>(P8, Vt, C1w, c1b, h1_0, h1_1);
    if (!tierA){
      bf16* H1a = (bf16*)(ws + oH1s);
      bf16* H1b = (bf16*)(ws + oH1s + 8388608);
      bf16* H2a = (bf16*)(ws + oH2s);
      bf16* H2b = (bf16*)(ws + oH2s + 8388608);
      k_dw<<<2048, 256, 0, stream>>>(H1a, dww, dwb, H2a, 128, 128);
      k_dw<<< 512, 256, 0, stream>>>(H1b, dww, dwb, H2b,  64,  64);
      k_se_partial<<<dim3(64,1), 256, 0, stream>>>(H2a, Pt, 16384);
      k_se_mlp<<<1, 256, 0, stream>>>(Pt, sw1, sb1, sw2, sb2, Ssc, 16384);
      k_conv2<<<dim3(64,1), 256, 0, stream>>>(H2a, Ssc, c2w, c2b, out + (size_t)b*64*16384, 128, 128);
      k_se_partial<<<dim3(64,1), 256, 0, stream>>>(H2b, Pt, 4096);
      k_se_mlp<<<1, 256, 0, stream>>>(Pt, sw1, sb1, sw2, sb2, Ssc, 4096);
      k_conv2<<<dim3(16,1), 256, 0, stream>>>(H2b, Ssc, c2w, c2b, out + (size_t)4*64*16384 + (size_t)b*64*4096, 64, 64);
    }
  }
  if (tierA){
    bf16* H1a = (bf16*)(ws + oH1);
    bf16* H1b = (bf16*)(ws + oH1 + 33554432);
    bf16* H2a = (bf16*)(ws + oVt);            // alias over dead Vt/Kp/Qp/Ke/Qe/P
    bf16* H2b = (bf16*)(ws + oVt + 33554432);
    k_dw<<<8192, 256, 0, stream>>>(H1a, dww, dwb, H2a, 128, 128);
    k_dw<<<2048, 256, 0, stream>>>(H1b, dww, dwb, H2b,  64,  64);
    k_se_partial<<<dim3(64,4), 256, 0, stream>>>(H2a, Pt, 16384);
    k_se_mlp<<<4, 256, 0, stream>>>(Pt, sw1, sb1, sw2, sb2, Ssc, 16384);
    k_conv2<<<dim3(64,4), 256, 0, stream>>>(H2a, Ssc, c2w, c2b, out, 128, 128);
    k_se_partial<<<dim3(64,4), 256, 0, stream>>>(H2b, Pt, 4096);
    k_se_mlp<<<4, 256, 0, stream>>>(Pt, sw1, sb1, sw2, sb2, Ssc, 4096);
    k_conv2<<<dim3(16,4), 256, 0, stream>>>(H2b, Ssc, c2w, c2b, out + (size_t)4*64*16384, 64, 64);
  }
}

// Round 4
// 1264.050 us; speedup vs baseline: 1.6345x; 1.3126x over previous
//
#include <hip/hip_runtime.h>
#include <hip/hip_bf16.h>

typedef __hip_bfloat16 bf16;
typedef short s8v __attribute__((ext_vector_type(8)));
typedef float f4v __attribute__((ext_vector_type(4)));

__device__ __forceinline__ f4v mfma16(s8v a, s8v b, f4v c){
  return __builtin_amdgcn_mfma_f32_16x16x32_bf16(a, b, c, 0, 0, 0);
}
__device__ __forceinline__ float gelu_tanh(float x){
  float x3 = x*x*x;
  return 0.5f*x*(1.0f + tanhf(0.7978845608028654f*(x + 0.044715f*x3)));
}

// ---------------- sentinel fill (encodes ws_size in MB * 16) ----------------
__global__ void k_fill(float* out, int n, float val){
  int i = blockIdx.x*256 + threadIdx.x;
  if (i < n) out[i] = val;
}

// ---------------- weight prep ----------------
__global__ __launch_bounds__(256) void k_prep(const float* __restrict__ Wk, const float* __restrict__ Wq,
                       const float* __restrict__ c1wf,
                       bf16* __restrict__ Wkt, bf16* __restrict__ Wqt, bf16* __restrict__ c1w){
  int tid = blockIdx.x*256 + threadIdx.x; // 98304 total
  if (tid < 32768){ int d = tid >> 7, j = tid & 127; Wkt[tid] = __float2bfloat16(Wk[j*256 + d]); }
  else if (tid < 65536){ int r = tid - 32768; int d = r >> 7, j = r & 127; Wqt[r] = __float2bfloat16(Wq[j*256 + d]); }
  else { int r = tid - 65536; c1w[r] = __float2bfloat16(c1wf[r]); }
}

// ---------------- fused patchify (one batch, all 4 tensors) ----------------
__global__ __launch_bounds__(256) void k_patch4(const float* __restrict__ k0, const float* __restrict__ k1,
                         const float* __restrict__ q0, const float* __restrict__ q1,
                         bf16* __restrict__ Kp, bf16* __restrict__ Qp, bf16* __restrict__ Vt){
  __shared__ float tile[64][33];
  int gy = blockIdx.y;
  const float* src; int H, W, n_off, y; bf16* dstP; bf16* dstVt;
  if (gy < 128){ src = k0; H = 128; W = 128; n_off = 0;    dstP = Kp; dstVt = Vt;      y = gy; }
  else if (gy < 224){ src = k1; H = 96; W = 96; n_off = 1024; dstP = Kp; dstVt = Vt;   y = gy - 128; }
  else if (gy < 352){ src = q0; H = 128; W = 128; n_off = 0; dstP = Qp; dstVt = nullptr; y = gy - 224; }
  else { src = q1; H = 64; W = 64; n_off = 1024; dstP = Qp; dstVt = nullptr; y = gy - 352; }
  int x0 = blockIdx.x*32;
  if (x0 >= W) return;
  int t = threadIdx.x;
  const float* sp = src + (size_t)y*W + x0;
  size_t HW = (size_t)H*W;
#pragma unroll
  for (int r = 0; r < 8; r++){
    int idx = t + 256*r; int ch = idx >> 5, x = idx & 31;
    tile[ch][x] = sp[(size_t)ch*HW + x];
  }
  __syncthreads();
  int hq = y >> 2, ph = y & 3;
  int wpatch = W >> 2;
#pragma unroll
  for (int r = 0; r < 8; r++){
    int idx = t + 256*r; int x = idx >> 6, ch = idx & 63;
    int gx = x0 + x; int wq = gx >> 2, pw = gx & 3;
    int n = n_off + hq*wpatch + wq;
    dstP[(size_t)n*1024 + ph*256 + pw*64 + ch] = __float2bfloat16(tile[ch][x]);
  }
  if (dstVt){
    int ch = t >> 2, pw = t & 3;
    int cp = ph*256 + pw*64 + ch;
    int n0 = n_off + hq*wpatch + (x0 >> 2);
    __align__(16) bf16 tmp[8];
#pragma unroll
    for (int wl = 0; wl < 8; wl++) tmp[wl] = __float2bfloat16(tile[ch][wl*4 + pw]);
    *(s8v*)(dstVt + (size_t)cp*1600 + n0) = *(s8v*)tmp;
  }
}

// ---------------- fused embedding GEMM (one batch, K+Q) ----------------
__global__ __launch_bounds__(256) void k_emb2(const bf16* __restrict__ Kp, const bf16* __restrict__ Qp,
                       const bf16* __restrict__ Wkt, const bf16* __restrict__ Wqt,
                       const float* __restrict__ bk, const float* __restrict__ bq,
                       bf16* __restrict__ Ke, bf16* __restrict__ Qe){
  int bx = blockIdx.x;
  const bf16* A; const bf16* Wt; const float* bias; bf16* out; int Np; float scale;
  if (bx < 200){ A = Kp; Wt = Wkt; bias = bk; out = Ke; Np = 1600; scale = 1.0f; }
  else { bx -= 200; A = Qp; Wt = Wqt; bias = bq; out = Qe; Np = 1280; scale = 0.17677669529663687f; }
  int t = threadIdx.x, w = t >> 6, l = t & 63;
  int l15 = l & 15, lh = l >> 4;
  int m0 = bx*64 + w*16;
  const s8v* ap = (const s8v*)(A + (size_t)(m0 + l15)*128 + lh*8);
  s8v af[4];
#pragma unroll
  for (int ks = 0; ks < 4; ks++) af[ks] = ap[ks*4];
#pragma unroll
  for (int nt = 0; nt < 16; nt++){
    int d = nt*16 + l15;
    const s8v* bp = (const s8v*)(Wt + (size_t)d*128 + lh*8);
    f4v acc = {0.f,0.f,0.f,0.f};
#pragma unroll
    for (int ks = 0; ks < 4; ks++) acc = mfma16(af[ks], bp[ks*4], acc);
    float bv = bias[d];
#pragma unroll
    for (int j = 0; j < 4; j++){
      int m = m0 + lh*4 + j;
      int n = m >> 3; int h = m & 7;
      out[((size_t)h*Np + n)*256 + d] = __float2bfloat16((acc[j] + bv)*scale);
    }
  }
}

// ---------------- pass 1: row max + sumexp (one batch), block = 128 q-rows x one head ----------------
__global__ __launch_bounds__(256) void k_stats(const bf16* __restrict__ Qe, const bf16* __restrict__ Ke,
                        float2* __restrict__ stats){
  __shared__ bf16 Ks[64][264];
  int t = threadIdx.x, w = t >> 6, l = t & 63, l15 = l & 15, lh = l >> 4;
  int qt = blockIdx.x, h = blockIdx.y;
  int row0 = qt*128 + w*32;
  s8v qf[2][8];
#pragma unroll
  for (int rt = 0; rt < 2; rt++)
#pragma unroll
    for (int ks = 0; ks < 8; ks++)
      qf[rt][ks] = *(const s8v*)(Qe + ((size_t)h*1280 + row0 + rt*16 + l15)*256 + ks*32 + lh*8);
  float m0[4], s0[4], m1[4], s1[4];
#pragma unroll
  for (int j = 0; j < 4; j++){ m0[j] = -1e30f; s0[j] = 0.f; m1[j] = -1e30f; s1[j] = 0.f; }
  int kr = t >> 2, kq = t & 3;
  for (int kt = 0; kt < 25; kt++){
    const bf16* src = Ke + ((size_t)h*1600 + kt*64 + kr)*256 + kq*64;
    if (kt) __syncthreads();
#pragma unroll
    for (int u = 0; u < 8; u++){
      int sw = (kq*8 + u) ^ (kr & 7);
      *(uint4*)&Ks[kr][sw*8] = *(const uint4*)(src + u*8);
    }
    __syncthreads();
    f4v a0[4], a1[4];
#pragma unroll
    for (int ct = 0; ct < 4; ct++){ a0[ct] = (f4v){0.f,0.f,0.f,0.f}; a1[ct] = (f4v){0.f,0.f,0.f,0.f}; }
#pragma unroll
    for (int ct = 0; ct < 4; ct++){
      int krow = ct*16 + l15;
#pragma unroll
      for (int ks = 0; ks < 8; ks++){
        s8v bf = *(const s8v*)&Ks[krow][((ks*4 + lh) ^ (krow & 7))*8];
        a0[ct] = mfma16(qf[0][ks], bf, a0[ct]);
        a1[ct] = mfma16(qf[1][ks], bf, a1[ct]);
      }
    }
#pragma unroll
    for (int j = 0; j < 4; j++){
      float vm = fmaxf(fmaxf(a0[0][j], a0[1][j]), fmaxf(a0[2][j], a0[3][j]));
      float mn = fmaxf(m0[j], vm);
      s0[j] = s0[j]*__expf(m0[j]-mn) + __expf(a0[0][j]-mn) + __expf(a0[1][j]-mn) + __expf(a0[2][j]-mn) + __expf(a0[3][j]-mn);
      m0[j] = mn;
      vm = fmaxf(fmaxf(a1[0][j], a1[1][j]), fmaxf(a1[2][j], a1[3][j]));
      mn = fmaxf(m1[j], vm);
      s1[j] = s1[j]*__expf(m1[j]-mn) + __expf(a1[0][j]-mn) + __expf(a1[1][j]-mn) + __expf(a1[2][j]-mn) + __expf(a1[3][j]-mn);
      m1[j] = mn;
    }
  }
#pragma unroll
  for (int j = 0; j < 4; j++){
    float mm = m0[j], ss = s0[j];
#pragma unroll
    for (int d = 1; d < 16; d <<= 1){
      float mo = __shfl_xor(mm, d); float so = __shfl_xor(ss, d);
      float mn = fmaxf(mm, mo); ss = ss*__expf(mm-mn) + so*__expf(mo-mn); mm = mn;
    }
    if (l15 == 0) stats[(size_t)h*1280 + row0 + lh*4 + j] = (float2){mm, 1.0f/ss};
    mm = m1[j]; ss = s1[j];
#pragma unroll
    for (int d = 1; d < 16; d <<= 1){
      float mo = __shfl_xor(mm, d); float so = __shfl_xor(ss, d);
      float mn = fmaxf(mm, mo); ss = ss*__expf(mm-mn) + so*__expf(mo-mn); mm = mn;
    }
    if (l15 == 0) stats[(size_t)h*1280 + row0 + 16 + lh*4 + j] = (float2){mm, 1.0f/ss};
  }
}

// ---------------- pass 2: recompute logits -> P bf16 (one batch) ----------------
__global__ __launch_bounds__(256) void k_psm(const bf16* __restrict__ Qe, const bf16* __restrict__ Ke,
                      const float2* __restrict__ stats, bf16* __restrict__ P){
  __shared__ bf16 Ks[64][264];
  __shared__ bf16 Pw[4][32][134];
  int t = threadIdx.x, w = t >> 6, l = t & 63, l15 = l & 15, lh = l >> 4;
  int qt = blockIdx.x, h = blockIdx.y;
  int row0 = qt*128 + w*32;
  s8v qf[2][8];
#pragma unroll
  for (int rt = 0; rt < 2; rt++)
#pragma unroll
    for (int ks = 0; ks < 8; ks++)
      qf[rt][ks] = *(const s8v*)(Qe + ((size_t)h*1280 + row0 + rt*16 + l15)*256 + ks*32 + lh*8);
  float mm0[4], iv0[4], mm1[4], iv1[4];
#pragma unroll
  for (int j = 0; j < 4; j++){
    float2 st = stats[(size_t)h*1280 + row0 + lh*4 + j];      mm0[j] = st.x; iv0[j] = st.y;
    float2 s2 = stats[(size_t)h*1280 + row0 + 16 + lh*4 + j]; mm1[j] = s2.x; iv1[j] = s2.y;
  }
  int kr = t >> 2, kq = t & 3;
  size_t prow_base = (size_t)h*1280 + row0;
  for (int kt = 0; kt < 25; kt++){
    const bf16* src = Ke + ((size_t)h*1600 + kt*64 + kr)*256 + kq*64;
    if (kt) __syncthreads();
#pragma unroll
    for (int u = 0; u < 8; u++){
      int sw = (kq*8 + u) ^ (kr & 7);
      *(uint4*)&Ks[kr][sw*8] = *(const uint4*)(src + u*8);
    }
    __syncthreads();
    f4v a0[4], a1[4];
#pragma unroll
    for (int ct = 0; ct < 4; ct++){ a0[ct] = (f4v){0.f,0.f,0.f,0.f}; a1[ct] = (f4v){0.f,0.f,0.f,0.f}; }
#pragma unroll
    for (int ct = 0; ct < 4; ct++){
      int krow = ct*16 + l15;
#pragma unroll
      for (int ks = 0; ks < 8; ks++){
        s8v bf = *(const s8v*)&Ks[krow][((ks*4 + lh) ^ (krow & 7))*8];
        a0[ct] = mfma16(qf[0][ks], bf, a0[ct]);
        a1[ct] = mfma16(qf[1][ks], bf, a1[ct]);
      }
    }
#pragma unroll
    for (int ct = 0; ct < 4; ct++){
      int local = (kt*4 + ct) & 7;
#pragma unroll
      for (int j = 0; j < 4; j++){
        Pw[w][lh*4 + j][local*16 + l15]      = __float2bfloat16(__expf(a0[ct][j] - mm0[j])*iv0[j]);
        Pw[w][16 + lh*4 + j][local*16 + l15] = __float2bfloat16(__expf(a1[ct][j] - mm1[j])*iv1[j]);
      }
    }
    if (kt & 1){
      int ci = kt >> 1;
#pragma unroll
      for (int p = 0; p < 8; p++){
        int s = p*8 + (l >> 3);
        int row = s >> 1, half = s & 1;
        *(uint4*)(P + (prow_base + row)*1600 + ci*128 + half*64 + (l & 7)*8) =
          *(uint4*)&Pw[w][row][half*64 + (l & 7)*8];
      }
    }
  }
#pragma unroll
  for (int p = 0; p < 4; p++){
    int row = p*8 + (l >> 3);
    *(uint4*)(P + (prow_base + row)*1600 + 1536 + (l & 7)*8) =
      *(uint4*)&Pw[w][row][(l & 7)*8];
  }
}

// ---------------- wv GEMM (one batch) + fused conv1+GELU -> H1 (NHWC) ----------------
__global__ __launch_bounds__(256) void k_wv(const bf16* __restrict__ P, const bf16* __restrict__ Vt,
                     const bf16* __restrict__ c1w, const float* __restrict__ c1b,
                     bf16* __restrict__ h1_0, bf16* __restrict__ h1_1){
  __shared__ bf16 At[128][40];
  __shared__ bf16 Bt[128][40];
  __shared__ bf16 Ot[256][70];
  __shared__ bf16 W1s[32][136];
  int mt = blockIdx.x, nt = blockIdx.y, h = blockIdx.z;
  int t = threadIdx.x, w = t >> 6, l = t & 63;
  int l15 = l & 15, lh = l >> 4;
  int wr = w >> 1, wc = w & 1;
  {
    int r = t >> 3, sg = (t & 7)*2;
    *(uint4*)&W1s[r][sg*8]     = *(const uint4*)(c1w + ((size_t)h*32 + r)*128 + sg*8);
    *(uint4*)&W1s[r][sg*8 + 8] = *(const uint4*)(c1w + ((size_t)h*32 + r)*128 + sg*8 + 8);
  }
  const bf16* Ab = P + ((size_t)h*1280 + mt*128)*1600;
  const bf16* Bb = Vt + ((size_t)nt*128)*1600;
  f4v acc2[4][2];
#pragma unroll
  for (int mm = 0; mm < 4; mm++)
#pragma unroll
    for (int nn = 0; nn < 2; nn++) acc2[mm][nn] = (f4v){0.f,0.f,0.f,0.f};
  for (int ksrc = 0; ksrc < 2; ksrc++){
    int nkt = ksrc ? 18 : 32;
    int koff = ksrc ? 1024 : 0;
    f4v acc[4][4];
#pragma unroll
    for (int m = 0; m < 4; m++)
#pragma unroll
      for (int n = 0; n < 4; n++) acc[m][n] = (f4v){0.f,0.f,0.f,0.f};
    for (int kt = 0; kt < nkt; kt++){
      int kbase = koff + kt*32;
#pragma unroll
      for (int r = 0; r < 2; r++){
        int idx = r*256 + t; int row = idx >> 2, kc = idx & 3;
        *(uint4*)&At[row][kc*8] = *(const uint4*)(Ab + (size_t)row*1600 + kbase + kc*8);
        *(uint4*)&Bt[row][kc*8] = *(const uint4*)(Bb + (size_t)row*1600 + kbase + kc*8);
      }
      __syncthreads();
      s8v af[4], bfr[4];
#pragma unroll
      for (int m = 0; m < 4; m++) af[m] = *(const s8v*)&At[wr*64 + m*16 + l15][lh*8];
#pragma unroll
      for (int n = 0; n < 4; n++) bfr[n] = *(const s8v*)&Bt[wc*64 + n*16 + l15][lh*8];
#pragma unroll
      for (int m = 0; m < 4; m++)
#pragma unroll
        for (int n = 0; n < 4; n++) acc[m][n] = mfma16(af[m], bfr[n], acc[m][n]);
      __syncthreads();
    }
#pragma unroll
    for (int m = 0; m < 4; m++){
      int rl = wr*64 + m*16 + lh*4;
#pragma unroll
      for (int n = 0; n < 4; n++)
#pragma unroll
        for (int j = 0; j < 4; j++)
          Ot[(rl + j)*2 + wc][n*16 + l15] = __float2bfloat16(acc[m][n][j]);
    }
    __syncthreads();
    int wpix0 = w*64;
    s8v afc[4][2], bfc[2][2];
#pragma unroll
    for (int mm = 0; mm < 4; mm++)
#pragma unroll
      for (int ks2 = 0; ks2 < 2; ks2++)
        afc[mm][ks2] = *(const s8v*)&Ot[wpix0 + mm*16 + l15][ks2*32 + lh*8];
#pragma unroll
    for (int nn = 0; nn < 2; nn++)
#pragma unroll
      for (int ks2 = 0; ks2 < 2; ks2++)
        bfc[nn][ks2] = *(const s8v*)&W1s[nn*16 + l15][ksrc*64 + ks2*32 + lh*8];
#pragma unroll
    for (int mm = 0; mm < 4; mm++)
#pragma unroll
      for (int nn = 0; nn < 2; nn++)
#pragma unroll
        for (int ks2 = 0; ks2 < 2; ks2++)
          acc2[mm][nn] = mfma16(afc[mm][ks2], bfc[nn][ks2], acc2[mm][nn]);
    __syncthreads();
  }
  float bia[2];
#pragma unroll
  for (int nn = 0; nn < 2; nn++) bia[nn] = c1b[h*32 + nn*16 + l15];
#pragma unroll
  for (int mm = 0; mm < 4; mm++){
#pragma unroll
    for (int nn = 0; nn < 2; nn++){
#pragma unroll
      for (int j = 0; j < 4; j++){
        float v = gelu_tanh(acc2[mm][nn][j] + bia[nn]);
        int pixl = w*64 + mm*16 + lh*4 + j;
        int rl = pixl >> 1, wc2 = pixl & 1;
        int rq = mt*128 + rl;
        int cell = nt*2 + wc2; int ph = cell >> 2, pw = cell & 3;
        int o = h*32 + nn*16 + l15;
        if (rq < 1024){
          int y = ((rq >> 5) << 2) + ph, x = ((rq & 31) << 2) + pw;
          h1_0[((size_t)y*128 + x)*256 + o] = __float2bfloat16(v);
        } else {
          int r2 = rq - 1024;
          int y = ((r2 >> 4) << 2) + ph, x = ((r2 & 15) << 2) + pw;
          h1_1[((size_t)y*64 + x)*256 + o] = __float2bfloat16(v);
        }
      }
    }
  }
}

// ---------------- depthwise 3x3 + GELU, NHWC: 8x4 pixel tile per block, full unroll ----------------
__global__ __launch_bounds__(256) void k_dw(const bf16* __restrict__ h1, const float* __restrict__ wdw,
                     const float* __restrict__ bdw, bf16* __restrict__ h2, int H, int W){
  __shared__ float wl[2304];
  __shared__ float bl[256];
  int t = threadIdx.x;
  for (int i = t; i < 2304; i += 256) wl[i] = wdw[i];
  bl[t] = bdw[t];
  __syncthreads();
  int cg = t & 31, xo = t >> 5;
  int ch0 = cg*8;
  int x = blockIdx.x*8 + xo;
  int y0 = blockIdx.y*4;
  int b = blockIdx.z;
  const bf16* base = h1 + (size_t)b*H*W*256;
  bf16* obase = h2 + (size_t)b*H*W*256;
  s8v ld[6][3];
  const s8v zz = (s8v){0,0,0,0,0,0,0,0};
#pragma unroll
  for (int r = 0; r < 6; r++){
    int yy = y0 - 1 + r;
    bool vy = (yy >= 0) && (yy < H);
    int yc = vy ? yy : 0;
#pragma unroll
    for (int d = 0; d < 3; d++){
      int xx = x - 1 + d;
      bool vx = (xx >= 0) && (xx < W);
      int xc = vx ? xx : 0;
      s8v v = *(const s8v*)(base + ((size_t)yc*W + xc)*256 + ch0);
      ld[r][d] = (vy && vx) ? v : zz;
    }
  }
#pragma unroll
  for (int p = 0; p < 4; p++){
    float acc[8];
#pragma unroll
    for (int i = 0; i < 8; i++) acc[i] = bl[ch0 + i];
#pragma unroll
    for (int dy = 0; dy < 3; dy++){
#pragma unroll
      for (int d = 0; d < 3; d++){
        s8v v = ld[p + dy][d];
#pragma unroll
        for (int i = 0; i < 8; i++){
          acc[i] += __bfloat162float(((const bf16*)&v)[i]) * wl[(ch0 + i)*9 + dy*3 + d];
        }
      }
    }
    __align__(16) bf16 outv[8];
#pragma unroll
    for (int i = 0; i < 8; i++) outv[i] = __float2bfloat16(gelu_tanh(acc[i]));
    *(s8v*)(obase + ((size_t)(y0 + p)*W + x)*256 + ch0) = *(s8v*)outv;
  }
}

// ---------------- SE partial sums, grid (64, nb), vectorized ----------------
__global__ __launch_bounds__(256) void k_se_partial(const bf16* __restrict__ h2, float* __restrict__ partial, int HW){
  __shared__ float red[8][256];
  int chunk = blockIdx.x, b = blockIdx.y, t = threadIdx.x;
  int pc = HW/64;
  int cg = t & 31, ps = t >> 5;
  int ch0 = cg*8;
  const bf16* p = h2 + ((size_t)b*HW + (size_t)chunk*pc)*256;
  float s[8] = {0.f,0.f,0.f,0.f,0.f,0.f,0.f,0.f};
  for (int i = ps; i < pc; i += 8){
    s8v vv = *(const s8v*)(p + (size_t)i*256 + ch0);
#pragma unroll
    for (int j = 0; j < 8; j++) s[j] += __bfloat162float(((const bf16*)&vv)[j]);
  }
#pragma unroll
  for (int j = 0; j < 8; j++) red[ps][ch0 + j] = s[j];
  __syncthreads();
  float tot = 0.f;
#pragma unroll
  for (int r = 0; r < 8; r++) tot += red[r][t];
  partial[((size_t)b*64 + chunk)*256 + t] = tot;
}

// ---------------- SE MLP, grid (nb) ----------------
__global__ __launch_bounds__(256) void k_se_mlp(const float* __restrict__ partial, const float* __restrict__ w1,
                         const float* __restrict__ b1, const float* __restrict__ w2, const float* __restrict__ b2,
                         float* __restrict__ sca, int HW){
  __shared__ float mean[256];
  __shared__ float s1[64];
  int b = blockIdx.x, t = threadIdx.x;
  float s = 0.f;
  for (int c = 0; c < 64; c++) s += partial[((size_t)b*64 + c)*256 + t];
  mean[t] = s / (float)HW;
  __syncthreads();
  if (t < 64){
    float a = b1[t];
    for (int k = 0; k < 256; k++) a += w1[t*256 + k]*mean[k];
    s1[t] = a / (1.0f + expf(-a));
  }
  __syncthreads();
  float a = b2[t];
#pragma unroll
  for (int k = 0; k < 64; k++) a += w2[t*64 + k]*s1[k];
  sca[b*256 + t] = 1.0f/(1.0f + expf(-a));
}

// ---------------- SE scale + conv2 -> NCHW f32, grid (HW/256, nb) ----------------
__global__ __launch_bounds__(256) void k_conv2(const bf16* __restrict__ h2, const float* __restrict__ sca,
                        const float* __restrict__ w2c, const float* __restrict__ b2c,
                        float* __restrict__ out, int H, int W){
  __shared__ float wsm[64][32];
  __shared__ float scs[256];
  int t = threadIdx.x, b = blockIdx.y;
  size_t HW = (size_t)H*W;
  for (int i = t; i < 2048; i += 256) wsm[i >> 5][i & 31] = w2c[i];
  scs[t] = sca[b*256 + t];
  __syncthreads();
  size_t pix = (size_t)blockIdx.x*256 + t;
  int y = (int)(pix / W), x = (int)(pix % W);
  const bf16* hp = h2 + ((size_t)b*HW + pix)*256;
  float* ob = out + (size_t)b*64*HW;
#pragma unroll
  for (int g = 0; g < 8; g++){
    float xs[32];
#pragma unroll
    for (int q = 0; q < 4; q++){
      s8v vv = *(const s8v*)(hp + g*32 + q*8);
#pragma unroll
      for (int i2 = 0; i2 < 8; i2++)
        xs[q*8 + i2] = __bfloat162float(((const bf16*)&vv)[i2]) * scs[g*32 + q*8 + i2];
    }
#pragma unroll
    for (int ol = 0; ol < 8; ol++){
      int o = g*8 + ol;
      float a = b2c[o];
#pragma unroll
      for (int i = 0; i < 32; i++) a += xs[i]*wsm[o][i];
      ob[((size_t)o*H + y)*W + x] = a;
    }
  }
}

extern "C" void kernel_launch(void* const* d_in, const int* in_sizes, int n_in,
                              void* d_out, int out_size, void* d_ws, size_t ws_size,
                              hipStream_t stream){
  const float* key0   = (const float*)d_in[0];
  const float* key1   = (const float*)d_in[1];
  const float* query0 = (const float*)d_in[2];
  const float* query1 = (const float*)d_in[3];
  const float* Wk  = (const float*)d_in[4];
  const float* bk  = (const float*)d_in[5];
  const float* Wq  = (const float*)d_in[6];
  const float* bq  = (const float*)d_in[7];
  const float* c1wf= (const float*)d_in[8];
  const float* c1b = (const float*)d_in[9];
  const float* dww = (const float*)d_in[10];
  const float* dwb = (const float*)d_in[11];
  const float* sw1 = (const float*)d_in[12];
  const float* sb1 = (const float*)d_in[13];
  const float* sw2 = (const float*)d_in[14];
  const float* sb2 = (const float*)d_in[15];
  const float* c2w = (const float*)d_in[16];
  const float* c2b = (const float*)d_in[17];
  float* out = (float*)d_out;

  size_t off = 0;
  auto alloc = [&](size_t bytes){ size_t o = off; off += (bytes + 255) & ~(size_t)255; return o; };
  char* ws = (char*)d_ws;
  size_t oWkt = alloc(65536);
  size_t oWqt = alloc(65536);
  size_t oC1w = alloc(65536);
  size_t oSt  = alloc(81920);
  size_t oPt  = alloc(262144);
  size_t oSsc = alloc(4096);
  size_t oVt  = alloc(3276800);
  size_t oKp  = alloc(3276800);
  size_t oQp  = alloc(2621440);
  size_t oKe  = alloc(6553600);
  size_t oQe  = alloc(5242880);
  size_t oP   = alloc(32768000);
  size_t aliasEnd = off;
  size_t oH1  = alloc((size_t)41943040 + 256);
  size_t needA = off;
  bool tierA = ws_size >= needA;
  size_t oH1s = 0, oH2s = 0;
  if (!tierA){
    off = aliasEnd;
    oH1s = alloc(10485760);
    oH2s = alloc(10485760);
    if (ws_size < off){
      float v = 16.0f * (float)(ws_size >> 20);
      k_fill<<<(out_size + 255)/256, 256, 0, stream>>>(out, out_size, v);
      return;
    }
  }
  bf16* Wkt = (bf16*)(ws + oWkt);
  bf16* Wqt = (bf16*)(ws + oWqt);
  bf16* C1w = (bf16*)(ws + oC1w);
  float2* St = (float2*)(ws + oSt);
  float* Pt  = (float*)(ws + oPt);
  float* Ssc = (float*)(ws + oSsc);
  bf16* Vt  = (bf16*)(ws + oVt);
  bf16* Kp  = (bf16*)(ws + oKp);
  bf16* Qp  = (bf16*)(ws + oQp);
  bf16* Ke  = (bf16*)(ws + oKe);
  bf16* Qe  = (bf16*)(ws + oQe);
  bf16* P8  = (bf16*)(ws + oP);

  k_prep<<<384, 256, 0, stream>>>(Wk, Wq, c1wf, Wkt, Wqt, C1w);

  for (int b = 0; b < 4; b++){
    const float* k0b = key0   + (size_t)b*64*128*128;
    const float* k1b = key1   + (size_t)b*64*96*96;
    const float* q0b = query0 + (size_t)b*64*128*128;
    const float* q1b = query1 + (size_t)b*64*64*64;
    k_patch4<<<dim3(4,416), 256, 0, stream>>>(k0b, k1b, q0b, q1b, Kp, Qp, Vt);
    k_emb2<<<360, 256, 0, stream>>>(Kp, Qp, Wkt, Wqt, bk, bq, Ke, Qe);
    k_stats<<<dim3(10,8), 256, 0, stream>>>(Qe, Ke, St);
    k_psm<<<dim3(10,8), 256, 0, stream>>>(Qe, Ke, St, P8);
    bf16* h1_0 = tierA ? (bf16*)(ws + oH1) + (size_t)b*16384*256
                       : (bf16*)(ws + oH1s);
    bf16* h1_1 = tierA ? (bf16*)(ws + oH1 + 33554432) + (size_t)b*4096*256
                       : (bf16*)(ws + oH1s + 8388608);
    k_wv<<<dim3(10,8,8), 256, 0, stream>>>(P8, Vt, C1w, c1b, h1_0, h1_1);
    if (!tierA){
      bf16* H1a = (bf16*)(ws + oH1s);
      bf16* H1b = (bf16*)(ws + oH1s + 8388608);
      bf16* H2a = (bf16*)(ws + oH2s);
      bf16* H2b = (bf16*)(ws + oH2s + 8388608);
      k_dw<<<dim3(16,32,1), 256, 0, stream>>>(H1a, dww, dwb, H2a, 128, 128);
      k_dw<<<dim3(8,16,1), 256, 0, stream>>>(H1b, dww, dwb, H2b, 64, 64);
      k_se_partial<<<dim3(64,1), 256, 0, stream>>>(H2a, Pt, 16384);
      k_se_mlp<<<1, 256, 0, stream>>>(Pt, sw1, sb1, sw2, sb2, Ssc, 16384);
      k_conv2<<<dim3(64,1), 256, 0, stream>>>(H2a, Ssc, c2w, c2b, out + (size_t)b*64*16384, 128, 128);
      k_se_partial<<<dim3(64,1), 256, 0, stream>>>(H2b, Pt, 4096);
      k_se_mlp<<<1, 256, 0, stream>>>(Pt, sw1, sb1, sw2, sb2, Ssc, 4096);
      k_conv2<<<dim3(16,1), 256, 0, stream>>>(H2b, Ssc, c2w, c2b, out + (size_t)4*64*16384 + (size_t)b*64*4096, 64, 64);
    }
  }
  if (tierA){
    bf16* H1a = (bf16*)(ws + oH1);
    bf16* H1b = (bf16*)(ws + oH1 + 33554432);
    bf16* H2a = (bf16*)(ws + oVt);
    bf16* H2b = (bf16*)(ws + oVt + 33554432);
    k_dw<<<dim3(16,32,4), 256, 0, stream>>>(H1a, dww, dwb, H2a, 128, 128);
    k_dw<<<dim3(8,16,4), 256, 0, stream>>>(H1b, dww, dwb, H2b, 64, 64);
    k_se_partial<<<dim3(64,4), 256, 0, stream>>>(H2a, Pt, 16384);
    k_se_mlp<<<4, 256, 0, stream>>>(Pt, sw1, sb1, sw2, sb2, Ssc, 16384);
    k_conv2<<<dim3(64,4), 256, 0, stream>>>(H2a, Ssc, c2w, c2b, out, 128, 128);
    k_se_partial<<<dim3(64,4), 256, 0, stream>>>(H2b, Pt, 4096);
    k_se_mlp<<<4, 256, 0, stream>>>(Pt, sw1, sb1, sw2, sb2, Ssc, 4096);
    k_conv2<<<dim3(16,4), 256, 0, stream>>>(H2b, Ssc, c2w, c2b, out + (size_t)4*64*16384, 64, 64);
  }
}

// Round 5
// 826.243 us; speedup vs baseline: 2.5006x; 1.5299x over previous
//
#include <hip/hip_runtime.h>
#include <hip/hip_bf16.h>

typedef __hip_bfloat16 bf16;
typedef short s8v __attribute__((ext_vector_type(8)));
typedef float f4v __attribute__((ext_vector_type(4)));

#if __has_builtin(__builtin_amdgcn_global_load_lds)
#define HAS_GLDS 1
#else
#define HAS_GLDS 0
#endif

__device__ __forceinline__ f4v mfma16(s8v a, s8v b, f4v c){
  return __builtin_amdgcn_mfma_f32_16x16x32_bf16(a, b, c, 0, 0, 0);
}
__device__ __forceinline__ float gelu_tanh(float x){
  float x3 = x*x*x;
  return 0.5f*x*(1.0f + tanhf(0.7978845608028654f*(x + 0.044715f*x3)));
}

// ---------------- sentinel fill (encodes ws_size in MB * 16) ----------------
__global__ void k_fill(float* out, int n, float val){
  int i = blockIdx.x*256 + threadIdx.x;
  if (i < n) out[i] = val;
}

// ---------------- weight prep ----------------
__global__ __launch_bounds__(256) void k_prep(const float* __restrict__ Wk, const float* __restrict__ Wq,
                       const float* __restrict__ c1wf,
                       bf16* __restrict__ Wkt, bf16* __restrict__ Wqt, bf16* __restrict__ c1w){
  int tid = blockIdx.x*256 + threadIdx.x; // 98304 total
  if (tid < 32768){ int d = tid >> 7, j = tid & 127; Wkt[tid] = __float2bfloat16(Wk[j*256 + d]); }
  else if (tid < 65536){ int r = tid - 32768; int d = r >> 7, j = r & 127; Wqt[r] = __float2bfloat16(Wq[j*256 + d]); }
  else { int r = tid - 65536; c1w[r] = __float2bfloat16(c1wf[r]); }
}

// ---------------- fused patchify (one batch, all 4 tensors) ----------------
__global__ __launch_bounds__(256) void k_patch4(const float* __restrict__ k0, const float* __restrict__ k1,
                         const float* __restrict__ q0, const float* __restrict__ q1,
                         bf16* __restrict__ Kp, bf16* __restrict__ Qp, bf16* __restrict__ Vt){
  __shared__ float tile[64][33];
  int gy = blockIdx.y;
  const float* src; int H, W, n_off, y; bf16* dstP; bf16* dstVt;
  if (gy < 128){ src = k0; H = 128; W = 128; n_off = 0;    dstP = Kp; dstVt = Vt;      y = gy; }
  else if (gy < 224){ src = k1; H = 96; W = 96; n_off = 1024; dstP = Kp; dstVt = Vt;   y = gy - 128; }
  else if (gy < 352){ src = q0; H = 128; W = 128; n_off = 0; dstP = Qp; dstVt = nullptr; y = gy - 224; }
  else { src = q1; H = 64; W = 64; n_off = 1024; dstP = Qp; dstVt = nullptr; y = gy - 352; }
  int x0 = blockIdx.x*32;
  if (x0 >= W) return;
  int t = threadIdx.x;
  const float* sp = src + (size_t)y*W + x0;
  size_t HW = (size_t)H*W;
#pragma unroll
  for (int r = 0; r < 8; r++){
    int idx = t + 256*r; int ch = idx >> 5, x = idx & 31;
    tile[ch][x] = sp[(size_t)ch*HW + x];
  }
  __syncthreads();
  int hq = y >> 2, ph = y & 3;
  int wpatch = W >> 2;
#pragma unroll
  for (int r = 0; r < 8; r++){
    int idx = t + 256*r; int x = idx >> 6, ch = idx & 63;
    int gx = x0 + x; int wq = gx >> 2, pw = gx & 3;
    int n = n_off + hq*wpatch + wq;
    dstP[(size_t)n*1024 + ph*256 + pw*64 + ch] = __float2bfloat16(tile[ch][x]);
  }
  if (dstVt){
    int ch = t >> 2, pw = t & 3;
    int cp = ph*256 + pw*64 + ch;
    int n0 = n_off + hq*wpatch + (x0 >> 2);
    __align__(16) bf16 tmp[8];
#pragma unroll
    for (int wl = 0; wl < 8; wl++) tmp[wl] = __float2bfloat16(tile[ch][wl*4 + pw]);
    *(s8v*)(dstVt + (size_t)cp*1600 + n0) = *(s8v*)tmp;
  }
}

// ---------------- fused embedding GEMM (one batch, K+Q); also zeroes St ----------------
__global__ __launch_bounds__(256) void k_emb2(const bf16* __restrict__ Kp, const bf16* __restrict__ Qp,
                       const bf16* __restrict__ Wkt, const bf16* __restrict__ Wqt,
                       const float* __restrict__ bk, const float* __restrict__ bq,
                       bf16* __restrict__ Ke, bf16* __restrict__ Qe, float* __restrict__ St){
  if (blockIdx.x < 40) St[blockIdx.x*256 + threadIdx.x] = 0.f;
  int bx = blockIdx.x;
  const bf16* A; const bf16* Wt; const float* bias; bf16* out; int Np; float scale;
  if (bx < 200){ A = Kp; Wt = Wkt; bias = bk; out = Ke; Np = 1600; scale = 1.0f; }
  else { bx -= 200; A = Qp; Wt = Wqt; bias = bq; out = Qe; Np = 1280; scale = 0.17677669529663687f; }
  int t = threadIdx.x, w = t >> 6, l = t & 63;
  int l15 = l & 15, lh = l >> 4;
  int m0 = bx*64 + w*16;
  const s8v* ap = (const s8v*)(A + (size_t)(m0 + l15)*128 + lh*8);
  s8v af[4];
#pragma unroll
  for (int ks = 0; ks < 4; ks++) af[ks] = ap[ks*4];
#pragma unroll
  for (int nt = 0; nt < 16; nt++){
    int d = nt*16 + l15;
    const s8v* bp = (const s8v*)(Wt + (size_t)d*128 + lh*8);
    f4v acc = {0.f,0.f,0.f,0.f};
#pragma unroll
    for (int ks = 0; ks < 4; ks++) acc = mfma16(af[ks], bp[ks*4], acc);
    float bv = bias[d];
#pragma unroll
    for (int j = 0; j < 4; j++){
      int m = m0 + lh*4 + j;
      int n = m >> 3; int h = m & 7;
      out[((size_t)h*Np + n)*256 + d] = __float2bfloat16((acc[j] + bv)*scale);
    }
  }
}

// ---------------- fused logits -> exp (no max-sub) -> Pexp bf16 + row-sum atomics ----------------
// grid (qt=10, h=8, kc=5): block covers 128 q-rows x 320 keys (5 kt of 64)
__global__ __launch_bounds__(256) void k_pexp(const bf16* __restrict__ Qe, const bf16* __restrict__ Ke,
                      bf16* __restrict__ P, float* __restrict__ St){
  __shared__ bf16 Ks[64][264];
  __shared__ bf16 Pw[4][32][134];
  int t = threadIdx.x, w = t >> 6, l = t & 63, l15 = l & 15, lh = l >> 4;
  int qt = blockIdx.x, h = blockIdx.y, kc = blockIdx.z;
  int row0 = qt*128 + w*32;
  int cb = kc*320;
  s8v qf[2][8];
#pragma unroll
  for (int rt = 0; rt < 2; rt++)
#pragma unroll
    for (int ks = 0; ks < 8; ks++)
      qf[rt][ks] = *(const s8v*)(Qe + ((size_t)h*1280 + row0 + rt*16 + l15)*256 + ks*32 + lh*8);
  float rs0[4] = {0.f,0.f,0.f,0.f}, rs1[4] = {0.f,0.f,0.f,0.f};
  int kr = t >> 2, kq = t & 3;
  size_t prow_base = (size_t)h*1280 + row0;
  for (int i = 0; i < 5; i++){
    int kt = kc*5 + i;
    const bf16* src = Ke + ((size_t)h*1600 + kt*64 + kr)*256 + kq*64;
    if (i) __syncthreads();
#pragma unroll
    for (int u = 0; u < 8; u++){
      int sw = (kq*8 + u) ^ (kr & 7);
      *(uint4*)&Ks[kr][sw*8] = *(const uint4*)(src + u*8);
    }
    __syncthreads();
    f4v a0[4], a1[4];
#pragma unroll
    for (int ct = 0; ct < 4; ct++){ a0[ct] = (f4v){0.f,0.f,0.f,0.f}; a1[ct] = (f4v){0.f,0.f,0.f,0.f}; }
#pragma unroll
    for (int ct = 0; ct < 4; ct++){
      int krow = ct*16 + l15;
#pragma unroll
      for (int ks = 0; ks < 8; ks++){
        s8v bf = *(const s8v*)&Ks[krow][((ks*4 + lh) ^ (krow & 7))*8];
        a0[ct] = mfma16(qf[0][ks], bf, a0[ct]);
        a1[ct] = mfma16(qf[1][ks], bf, a1[ct]);
      }
    }
#pragma unroll
    for (int ct = 0; ct < 4; ct++){
      int local = (i*4 + ct) & 7;
#pragma unroll
      for (int j = 0; j < 4; j++){
        float e0 = __expf(a0[ct][j]); rs0[j] += e0;
        float e1 = __expf(a1[ct][j]); rs1[j] += e1;
        Pw[w][lh*4 + j][local*16 + l15]      = __float2bfloat16(e0);
        Pw[w][16 + lh*4 + j][local*16 + l15] = __float2bfloat16(e1);
      }
    }
    if (i & 1){
      int ci = i >> 1;
#pragma unroll
      for (int p = 0; p < 8; p++){
        int s = p*8 + (l >> 3);
        int row = s >> 1, half = s & 1;
        *(uint4*)(P + (prow_base + row)*1600 + cb + ci*128 + half*64 + (l & 7)*8) =
          *(uint4*)&Pw[w][row][half*64 + (l & 7)*8];
      }
    }
  }
  // tail: last 64 cols of this block's 320 (local tiles 0..3)
#pragma unroll
  for (int p = 0; p < 4; p++){
    int row = p*8 + (l >> 3);
    *(uint4*)(P + (prow_base + row)*1600 + cb + 256 + (l & 7)*8) =
      *(uint4*)&Pw[w][row][(l & 7)*8];
  }
  // row-sum partials -> atomic
#pragma unroll
  for (int j = 0; j < 4; j++){
    float s0 = rs0[j], s1 = rs1[j];
#pragma unroll
    for (int d = 1; d < 16; d <<= 1){ s0 += __shfl_xor(s0, d); s1 += __shfl_xor(s1, d); }
    if (l15 == 0){
      atomicAdd(&St[(size_t)h*1280 + row0 + lh*4 + j], s0);
      atomicAdd(&St[(size_t)h*1280 + row0 + 16 + lh*4 + j], s1);
    }
  }
}

// ---------------- wv GEMM (one batch) + deferred softmax-norm + fused conv1+GELU -> H1 ----------------
// grid 640 1D: bid = nt*80 + h*10 + mt  (all nt of one (mt,h) share an XCD -> L2-local A-tile)
__global__ __launch_bounds__(256) void k_wv(const bf16* __restrict__ P, const bf16* __restrict__ Vt,
                     const bf16* __restrict__ c1w, const float* __restrict__ c1b,
                     const float* __restrict__ St,
                     bf16* __restrict__ h1_0, bf16* __restrict__ h1_1){
  __shared__ bf16 AB[16384];   // A[128][64] @0, B[128][64] @8192; union: Ot[256][64]
  __shared__ bf16 W1s[4096];   // [32][128] swizzled (granule ^ row&7)
  int bid = blockIdx.x;
  int nt = bid / 80;
  int r80 = bid - nt*80;
  int h = r80 / 10;
  int mt = r80 - h*10;
  int t = threadIdx.x, w = t >> 6, l = t & 63;
  int l15 = l & 15, lh = l >> 4;
  int wr = w >> 1, wc = w & 1;
  {
    int rr = t >> 3;
    int gp = (t & 7)*2;
    const bf16* src = c1w + ((size_t)h*32 + rr)*128;
    *(uint4*)&W1s[rr*128 + ((gp ^ (rr & 7))*8)]     = *(const uint4*)(src + gp*8);
    *(uint4*)&W1s[rr*128 + (((gp+1) ^ (rr & 7))*8)] = *(const uint4*)(src + (gp+1)*8);
  }
  const bf16* Ab = P + ((size_t)h*1280 + mt*128)*1600;
  const bf16* Bb = Vt + ((size_t)nt*128)*1600;
  int lrow = l >> 3;
  int gsrc8 = ((l & 7) ^ lrow)*8;
  f4v acc2[4][2];
#pragma unroll
  for (int mm = 0; mm < 4; mm++)
#pragma unroll
    for (int nn = 0; nn < 2; nn++) acc2[mm][nn] = (f4v){0.f,0.f,0.f,0.f};
#pragma unroll
  for (int ksrc = 0; ksrc < 2; ksrc++){
    int nkt = ksrc ? 9 : 16;
    int koff = ksrc ? 1024 : 0;
    f4v acc[4][4];
#pragma unroll
    for (int m = 0; m < 4; m++)
#pragma unroll
      for (int n = 0; n < 4; n++) acc[m][n] = (f4v){0.f,0.f,0.f,0.f};
    for (int kt = 0; kt < nkt; kt++){
      int kbase = koff + kt*64;
#pragma unroll
      for (int i = 0; i < 4; i++){
        int rbase = w*32 + i*8;
        int rowA = rbase + lrow;
        const bf16* gA = Ab + (size_t)rowA*1600 + kbase + gsrc8;
        const bf16* gB = Bb + (size_t)rowA*1600 + kbase + gsrc8;
#if HAS_GLDS
        __builtin_amdgcn_global_load_lds((const __attribute__((address_space(1))) unsigned int*)gA,
                                         (__attribute__((address_space(3))) unsigned int*)&AB[rbase*64], 16, 0, 0);
        __builtin_amdgcn_global_load_lds((const __attribute__((address_space(1))) unsigned int*)gB,
                                         (__attribute__((address_space(3))) unsigned int*)&AB[8192 + rbase*64], 16, 0, 0);
#else
        *(uint4*)&AB[rowA*64 + (l & 7)*8]        = *(const uint4*)gA;
        *(uint4*)&AB[8192 + rowA*64 + (l & 7)*8] = *(const uint4*)gB;
#endif
      }
      __syncthreads();
#pragma unroll
      for (int ks2 = 0; ks2 < 2; ks2++){
        s8v af[4], bfr[4];
#pragma unroll
        for (int m = 0; m < 4; m++){
          int row = wr*64 + m*16 + l15;
          af[m] = *(const s8v*)&AB[row*64 + (((ks2*4 + lh) ^ (row & 7))*8)];
        }
#pragma unroll
        for (int n = 0; n < 4; n++){
          int row = wc*64 + n*16 + l15;
          bfr[n] = *(const s8v*)&AB[8192 + row*64 + (((ks2*4 + lh) ^ (row & 7))*8)];
        }
#pragma unroll
        for (int m = 0; m < 4; m++)
#pragma unroll
          for (int n = 0; n < 4; n++) acc[m][n] = mfma16(af[m], bfr[n], acc[m][n]);
      }
      __syncthreads();
    }
    // stage normalized O half-tile into AB union: Ot[256 pix][64 ch] swizzled
#pragma unroll
    for (int m = 0; m < 4; m++){
      int rl4 = wr*64 + m*16 + lh*4;
      float ivm[4];
#pragma unroll
      for (int j = 0; j < 4; j++)
        ivm[j] = 1.0f / St[(size_t)h*1280 + mt*128 + rl4 + j];
#pragma unroll
      for (int n = 0; n < 4; n++){
        int c = n*16 + l15;
#pragma unroll
        for (int j = 0; j < 4; j++){
          int p = (rl4 + j)*2 + wc;
          AB[p*64 + (((c >> 3) ^ (p & 7))*8) + (c & 7)] = __float2bfloat16(acc[m][n][j]*ivm[j]);
        }
      }
    }
    __syncthreads();
    // conv1 partial MFMA over this 64-ch half
#pragma unroll
    for (int ks2 = 0; ks2 < 2; ks2++){
      s8v afc[4], bfc[2];
#pragma unroll
      for (int mm = 0; mm < 4; mm++){
        int p2 = w*64 + mm*16 + l15;
        afc[mm] = *(const s8v*)&AB[p2*64 + (((ks2*4 + lh) ^ (p2 & 7))*8)];
      }
#pragma unroll
      for (int nn = 0; nn < 2; nn++){
        int rw = nn*16 + l15;
        int gg = ksrc*8 + ks2*4 + lh;
        bfc[nn] = *(const s8v*)&W1s[rw*128 + ((gg ^ (rw & 7))*8)];
      }
#pragma unroll
      for (int mm = 0; mm < 4; mm++)
#pragma unroll
        for (int nn = 0; nn < 2; nn++)
          acc2[mm][nn] = mfma16(afc[mm], bfc[nn], acc2[mm][nn]);
    }
    __syncthreads();
  }
  float bia[2];
#pragma unroll
  for (int nn = 0; nn < 2; nn++) bia[nn] = c1b[h*32 + nn*16 + l15];
#pragma unroll
  for (int mm = 0; mm < 4; mm++){
#pragma unroll
    for (int nn = 0; nn < 2; nn++){
#pragma unroll
      for (int j = 0; j < 4; j++){
        float v = gelu_tanh(acc2[mm][nn][j] + bia[nn]);
        int pixl = w*64 + mm*16 + lh*4 + j;
        int rl = pixl >> 1, wc2 = pixl & 1;
        int rq = mt*128 + rl;
        int cell = nt*2 + wc2; int ph = cell >> 2, pw = cell & 3;
        int o = h*32 + nn*16 + l15;
        if (rq < 1024){
          int y = ((rq >> 5) << 2) + ph, x = ((rq & 31) << 2) + pw;
          h1_0[((size_t)y*128 + x)*256 + o] = __float2bfloat16(v);
        } else {
          int r2 = rq - 1024;
          int y = ((r2 >> 4) << 2) + ph, x = ((r2 & 15) << 2) + pw;
          h1_1[((size_t)y*64 + x)*256 + o] = __float2bfloat16(v);
        }
      }
    }
  }
}

// ---------------- depthwise 3x3 + GELU, NHWC: 8x4 pixel tile per block, full unroll ----------------
__global__ __launch_bounds__(256) void k_dw(const bf16* __restrict__ h1, const float* __restrict__ wdw,
                     const float* __restrict__ bdw, bf16* __restrict__ h2, int H, int W){
  __shared__ float wl[2304];
  __shared__ float bl[256];
  int t = threadIdx.x;
  for (int i = t; i < 2304; i += 256) wl[i] = wdw[i];
  bl[t] = bdw[t];
  __syncthreads();
  int cg = t & 31, xo = t >> 5;
  int ch0 = cg*8;
  int x = blockIdx.x*8 + xo;
  int y0 = blockIdx.y*4;
  int b = blockIdx.z;
  const bf16* base = h1 + (size_t)b*H*W*256;
  bf16* obase = h2 + (size_t)b*H*W*256;
  s8v ld[6][3];
  const s8v zz = (s8v){0,0,0,0,0,0,0,0};
#pragma unroll
  for (int r = 0; r < 6; r++){
    int yy = y0 - 1 + r;
    bool vy = (yy >= 0) && (yy < H);
    int yc = vy ? yy : 0;
#pragma unroll
    for (int d = 0; d < 3; d++){
      int xx = x - 1 + d;
      bool vx = (xx >= 0) && (xx < W);
      int xc = vx ? xx : 0;
      s8v v = *(const s8v*)(base + ((size_t)yc*W + xc)*256 + ch0);
      ld[r][d] = (vy && vx) ? v : zz;
    }
  }
#pragma unroll
  for (int p = 0; p < 4; p++){
    float acc[8];
#pragma unroll
    for (int i = 0; i < 8; i++) acc[i] = bl[ch0 + i];
#pragma unroll
    for (int dy = 0; dy < 3; dy++){
#pragma unroll
      for (int d = 0; d < 3; d++){
        s8v v = ld[p + dy][d];
#pragma unroll
        for (int i = 0; i < 8; i++){
          acc[i] += __bfloat162float(((const bf16*)&v)[i]) * wl[(ch0 + i)*9 + dy*3 + d];
        }
      }
    }
    __align__(16) bf16 outv[8];
#pragma unroll
    for (int i = 0; i < 8; i++) outv[i] = __float2bfloat16(gelu_tanh(acc[i]));
    *(s8v*)(obase + ((size_t)(y0 + p)*W + x)*256 + ch0) = *(s8v*)outv;
  }
}

// ---------------- SE partial sums, grid (64, nb), vectorized ----------------
__global__ __launch_bounds__(256) void k_se_partial(const bf16* __restrict__ h2, float* __restrict__ partial, int HW){
  __shared__ float red[8][256];
  int chunk = blockIdx.x, b = blockIdx.y, t = threadIdx.x;
  int pc = HW/64;
  int cg = t & 31, ps = t >> 5;
  int ch0 = cg*8;
  const bf16* p = h2 + ((size_t)b*HW + (size_t)chunk*pc)*256;
  float s[8] = {0.f,0.f,0.f,0.f,0.f,0.f,0.f,0.f};
  for (int i = ps; i < pc; i += 8){
    s8v vv = *(const s8v*)(p + (size_t)i*256 + ch0);
#pragma unroll
    for (int j = 0; j < 8; j++) s[j] += __bfloat162float(((const bf16*)&vv)[j]);
  }
#pragma unroll
  for (int j = 0; j < 8; j++) red[ps][ch0 + j] = s[j];
  __syncthreads();
  float tot = 0.f;
#pragma unroll
  for (int r = 0; r < 8; r++) tot += red[r][t];
  partial[((size_t)b*64 + chunk)*256 + t] = tot;
}

// ---------------- SE MLP, grid (nb) ----------------
__global__ __launch_bounds__(256) void k_se_mlp(const float* __restrict__ partial, const float* __restrict__ w1,
                         const float* __restrict__ b1, const float* __restrict__ w2, const float* __restrict__ b2,
                         float* __restrict__ sca, int HW){
  __shared__ float mean[256];
  __shared__ float s1[64];
  int b = blockIdx.x, t = threadIdx.x;
  float s = 0.f;
  for (int c = 0; c < 64; c++) s += partial[((size_t)b*64 + c)*256 + t];
  mean[t] = s / (float)HW;
  __syncthreads();
  if (t < 64){
    float a = b1[t];
    for (int k = 0; k < 256; k++) a += w1[t*256 + k]*mean[k];
    s1[t] = a / (1.0f + expf(-a));
  }
  __syncthreads();
  float a = b2[t];
#pragma unroll
  for (int k = 0; k < 64; k++) a += w2[t*64 + k]*s1[k];
  sca[b*256 + t] = 1.0f/(1.0f + expf(-a));
}

// ---------------- SE scale + conv2 -> NCHW f32, grid (HW/256, nb) ----------------
__global__ __launch_bounds__(256) void k_conv2(const bf16* __restrict__ h2, const float* __restrict__ sca,
                        const float* __restrict__ w2c, const float* __restrict__ b2c,
                        float* __restrict__ out, int H, int W){
  __shared__ float wsm[64][32];
  __shared__ float scs[256];
  int t = threadIdx.x, b = blockIdx.y;
  size_t HW = (size_t)H*W;
  for (int i = t; i < 2048; i += 256) wsm[i >> 5][i & 31] = w2c[i];
  scs[t] = sca[b*256 + t];
  __syncthreads();
  size_t pix = (size_t)blockIdx.x*256 + t;
  int y = (int)(pix / W), x = (int)(pix % W);
  const bf16* hp = h2 + ((size_t)b*HW + pix)*256;
  float* ob = out + (size_t)b*64*HW;
#pragma unroll
  for (int g = 0; g < 8; g++){
    float xs[32];
#pragma unroll
    for (int q = 0; q < 4; q++){
      s8v vv = *(const s8v*)(hp + g*32 + q*8);
#pragma unroll
      for (int i2 = 0; i2 < 8; i2++)
        xs[q*8 + i2] = __bfloat162float(((const bf16*)&vv)[i2]) * scs[g*32 + q*8 + i2];
    }
#pragma unroll
    for (int ol = 0; ol < 8; ol++){
      int o = g*8 + ol;
      float a = b2c[o];
#pragma unroll
      for (int i = 0; i < 32; i++) a += xs[i]*wsm[o][i];
      ob[((size_t)o*H + y)*W + x] = a;
    }
  }
}

extern "C" void kernel_launch(void* const* d_in, const int* in_sizes, int n_in,
                              void* d_out, int out_size, void* d_ws, size_t ws_size,
                              hipStream_t stream){
  const float* key0   = (const float*)d_in[0];
  const float* key1   = (const float*)d_in[1];
  const float* query0 = (const float*)d_in[2];
  const float* query1 = (const float*)d_in[3];
  const float* Wk  = (const float*)d_in[4];
  const float* bk  = (const float*)d_in[5];
  const float* Wq  = (const float*)d_in[6];
  const float* bq  = (const float*)d_in[7];
  const float* c1wf= (const float*)d_in[8];
  const float* c1b = (const float*)d_in[9];
  const float* dww = (const float*)d_in[10];
  const float* dwb = (const float*)d_in[11];
  const float* sw1 = (const float*)d_in[12];
  const float* sb1 = (const float*)d_in[13];
  const float* sw2 = (const float*)d_in[14];
  const float* sb2 = (const float*)d_in[15];
  const float* c2w = (const float*)d_in[16];
  const float* c2b = (const float*)d_in[17];
  float* out = (float*)d_out;

  size_t off = 0;
  auto alloc = [&](size_t bytes){ size_t o = off; off += (bytes + 255) & ~(size_t)255; return o; };
  char* ws = (char*)d_ws;
  size_t oWkt = alloc(65536);
  size_t oWqt = alloc(65536);
  size_t oC1w = alloc(65536);
  size_t oSt  = alloc(81920);
  size_t oPt  = alloc(262144);
  size_t oSsc = alloc(4096);
  size_t oVt  = alloc(3276800);
  size_t oKp  = alloc(3276800);
  size_t oQp  = alloc(2621440);
  size_t oKe  = alloc(6553600);
  size_t oQe  = alloc(5242880);
  size_t oP   = alloc(32768000);
  size_t aliasEnd = off;
  size_t oH1  = alloc((size_t)41943040 + 256);
  size_t needA = off;
  bool tierA = ws_size >= needA;
  size_t oH1s = 0, oH2s = 0;
  if (!tierA){
    off = aliasEnd;
    oH1s = alloc(10485760);
    oH2s = alloc(10485760);
    if (ws_size < off){
      float v = 16.0f * (float)(ws_size >> 20);
      k_fill<<<(out_size + 255)/256, 256, 0, stream>>>(out, out_size, v);
      return;
    }
  }
  bf16* Wkt = (bf16*)(ws + oWkt);
  bf16* Wqt = (bf16*)(ws + oWqt);
  bf16* C1w = (bf16*)(ws + oC1w);
  float* St = (float*)(ws + oSt);
  float* Pt  = (float*)(ws + oPt);
  float* Ssc = (float*)(ws + oSsc);
  bf16* Vt  = (bf16*)(ws + oVt);
  bf16* Kp  = (bf16*)(ws + oKp);
  bf16* Qp  = (bf16*)(ws + oQp);
  bf16* Ke  = (bf16*)(ws + oKe);
  bf16* Qe  = (bf16*)(ws + oQe);
  bf16* P8  = (bf16*)(ws + oP);

  k_prep<<<384, 256, 0, stream>>>(Wk, Wq, c1wf, Wkt, Wqt, C1w);

  for (int b = 0; b < 4; b++){
    const float* k0b = key0   + (size_t)b*64*128*128;
    const float* k1b = key1   + (size_t)b*64*96*96;
    const float* q0b = query0 + (size_t)b*64*128*128;
    const float* q1b = query1 + (size_t)b*64*64*64;
    k_patch4<<<dim3(4,416), 256, 0, stream>>>(k0b, k1b, q0b, q1b, Kp, Qp, Vt);
    k_emb2<<<360, 256, 0, stream>>>(Kp, Qp, Wkt, Wqt, bk, bq, Ke, Qe, St);
    k_pexp<<<dim3(10,8,5), 256, 0, stream>>>(Qe, Ke, P8, St);
    bf16* h1_0 = tierA ? (bf16*)(ws + oH1) + (size_t)b*16384*256
                       : (bf16*)(ws + oH1s);
    bf16* h1_1 = tierA ? (bf16*)(ws + oH1 + 33554432) + (size_t)b*4096*256
                       : (bf16*)(ws + oH1s + 8388608);
    k_wv<<<640, 256, 0, stream>>>(P8, Vt, C1w, c1b, St, h1_0, h1_1);
    if (!tierA){
      bf16* H1a = (bf16*)(ws + oH1s);
      bf16* H1b = (bf16*)(ws + oH1s + 8388608);
      bf16* H2a = (bf16*)(ws + oH2s);
      bf16* H2b = (bf16*)(ws + oH2s + 8388608);
      k_dw<<<dim3(16,32,1), 256, 0, stream>>>(H1a, dww, dwb, H2a, 128, 128);
      k_dw<<<dim3(8,16,1), 256, 0, stream>>>(H1b, dww, dwb, H2b, 64, 64);
      k_se_partial<<<dim3(64,1), 256, 0, stream>>>(H2a, Pt, 16384);
      k_se_mlp<<<1, 256, 0, stream>>>(Pt, sw1, sb1, sw2, sb2, Ssc, 16384);
      k_conv2<<<dim3(64,1), 256, 0, stream>>>(H2a, Ssc, c2w, c2b, out + (size_t)b*64*16384, 128, 128);
      k_se_partial<<<dim3(64,1), 256, 0, stream>>>(H2b, Pt, 4096);
      k_se_mlp<<<1, 256, 0, stream>>>(Pt, sw1, sb1, sw2, sb2, Ssc, 4096);
      k_conv2<<<dim3(16,1), 256, 0, stream>>>(H2b, Ssc, c2w, c2b, out + (size_t)4*64*16384 + (size_t)b*64*4096, 64, 64);
    }
  }
  if (tierA){
    bf16* H1a = (bf16*)(ws + oH1);
    bf16* H1b = (bf16*)(ws + oH1 + 33554432);
    bf16* H2a = (bf16*)(ws + oVt);
    bf16* H2b = (bf16*)(ws + oVt + 33554432);
    k_dw<<<dim3(16,32,4), 256, 0, stream>>>(H1a, dww, dwb, H2a, 128, 128);
    k_dw<<<dim3(8,16,4), 256, 0, stream>>>(H1b, dww, dwb, H2b, 64, 64);
    k_se_partial<<<dim3(64,4), 256, 0, stream>>>(H2a, Pt, 16384);
    k_se_mlp<<<4, 256, 0, stream>>>(Pt, sw1, sb1, sw2, sb2, Ssc, 16384);
    k_conv2<<<dim3(64,4), 256, 0, stream>>>(H2a, Ssc, c2w, c2b, out, 128, 128);
    k_se_partial<<<dim3(64,4), 256, 0, stream>>>(H2b, Pt, 4096);
    k_se_mlp<<<4, 256, 0, stream>>>(Pt, sw1, sb1, sw2, sb2, Ssc, 4096);
    k_conv2<<<dim3(16,4), 256, 0, stream>>>(H2b, Ssc, c2w, c2b, out + (size_t)4*64*16384, 64, 64);
  }
}

// Round 6
// 795.297 us; speedup vs baseline: 2.5979x; 1.0389x over previous
//
#include <hip/hip_runtime.h>
#include <hip/hip_bf16.h>

typedef __hip_bfloat16 bf16;
typedef short s8v __attribute__((ext_vector_type(8)));
typedef float f4v __attribute__((ext_vector_type(4)));

__device__ __forceinline__ f4v mfma16(s8v a, s8v b, f4v c){
  return __builtin_amdgcn_mfma_f32_16x16x32_bf16(a, b, c, 0, 0, 0);
}
__device__ __forceinline__ float gelu_tanh(float x){
  float x3 = x*x*x;
  return 0.5f*x*(1.0f + tanhf(0.7978845608028654f*(x + 0.044715f*x3)));
}

// ---------------- sentinel fill (encodes ws_size in MB * 16) ----------------
__global__ void k_fill(float* out, int n, float val){
  int i = blockIdx.x*256 + threadIdx.x;
  if (i < n) out[i] = val;
}

// ---------------- weight prep ----------------
__global__ __launch_bounds__(256) void k_prep(const float* __restrict__ Wk, const float* __restrict__ Wq,
                       const float* __restrict__ c1wf,
                       bf16* __restrict__ Wkt, bf16* __restrict__ Wqt, bf16* __restrict__ c1w){
  int tid = blockIdx.x*256 + threadIdx.x; // 98304 total
  if (tid < 32768){ int d = tid >> 7, j = tid & 127; Wkt[tid] = __float2bfloat16(Wk[j*256 + d]); }
  else if (tid < 65536){ int r = tid - 32768; int d = r >> 7, j = r & 127; Wqt[r] = __float2bfloat16(Wq[j*256 + d]); }
  else { int r = tid - 65536; c1w[r] = __float2bfloat16(c1wf[r]); }
}

// ---------------- fused patchify (one batch, all 4 tensors) ----------------
__global__ __launch_bounds__(256) void k_patch4(const float* __restrict__ k0, const float* __restrict__ k1,
                         const float* __restrict__ q0, const float* __restrict__ q1,
                         bf16* __restrict__ Kp, bf16* __restrict__ Qp, bf16* __restrict__ Vt){
  __shared__ float tile[64][33];
  int gy = blockIdx.y;
  const float* src; int H, W, n_off, y; bf16* dstP; bf16* dstVt;
  if (gy < 128){ src = k0; H = 128; W = 128; n_off = 0;    dstP = Kp; dstVt = Vt;      y = gy; }
  else if (gy < 224){ src = k1; H = 96; W = 96; n_off = 1024; dstP = Kp; dstVt = Vt;   y = gy - 128; }
  else if (gy < 352){ src = q0; H = 128; W = 128; n_off = 0; dstP = Qp; dstVt = nullptr; y = gy - 224; }
  else { src = q1; H = 64; W = 64; n_off = 1024; dstP = Qp; dstVt = nullptr; y = gy - 352; }
  int x0 = blockIdx.x*32;
  if (x0 >= W) return;
  int t = threadIdx.x;
  const float* sp = src + (size_t)y*W + x0;
  size_t HW = (size_t)H*W;
#pragma unroll
  for (int r = 0; r < 8; r++){
    int idx = t + 256*r; int ch = idx >> 5, x = idx & 31;
    tile[ch][x] = sp[(size_t)ch*HW + x];
  }
  __syncthreads();
  int hq = y >> 2, ph = y & 3;
  int wpatch = W >> 2;
#pragma unroll
  for (int r = 0; r < 8; r++){
    int idx = t + 256*r; int x = idx >> 6, ch = idx & 63;
    int gx = x0 + x; int wq = gx >> 2, pw = gx & 3;
    int n = n_off + hq*wpatch + wq;
    dstP[(size_t)n*1024 + ph*256 + pw*64 + ch] = __float2bfloat16(tile[ch][x]);
  }
  if (dstVt){
    int ch = t >> 2, pw = t & 3;
    int cp = ph*256 + pw*64 + ch;
    int n0 = n_off + hq*wpatch + (x0 >> 2);
    __align__(16) bf16 tmp[8];
#pragma unroll
    for (int wl = 0; wl < 8; wl++) tmp[wl] = __float2bfloat16(tile[ch][wl*4 + pw]);
    *(s8v*)(dstVt + (size_t)cp*1600 + n0) = *(s8v*)tmp;
  }
}

// ---------------- fused embedding GEMM (one batch, K+Q); also zeroes St ----------------
__global__ __launch_bounds__(256) void k_emb2(const bf16* __restrict__ Kp, const bf16* __restrict__ Qp,
                       const bf16* __restrict__ Wkt, const bf16* __restrict__ Wqt,
                       const float* __restrict__ bk, const float* __restrict__ bq,
                       bf16* __restrict__ Ke, bf16* __restrict__ Qe, float* __restrict__ St){
  if (blockIdx.x < 40) St[blockIdx.x*256 + threadIdx.x] = 0.f;
  int bx = blockIdx.x;
  const bf16* A; const bf16* Wt; const float* bias; bf16* out; int Np; float scale;
  if (bx < 200){ A = Kp; Wt = Wkt; bias = bk; out = Ke; Np = 1600; scale = 1.0f; }
  else { bx -= 200; A = Qp; Wt = Wqt; bias = bq; out = Qe; Np = 1280; scale = 0.17677669529663687f; }
  int t = threadIdx.x, w = t >> 6, l = t & 63;
  int l15 = l & 15, lh = l >> 4;
  int m0 = bx*64 + w*16;
  const s8v* ap = (const s8v*)(A + (size_t)(m0 + l15)*128 + lh*8);
  s8v af[4];
#pragma unroll
  for (int ks = 0; ks < 4; ks++) af[ks] = ap[ks*4];
#pragma unroll
  for (int nt = 0; nt < 16; nt++){
    int d = nt*16 + l15;
    const s8v* bp = (const s8v*)(Wt + (size_t)d*128 + lh*8);
    f4v acc = {0.f,0.f,0.f,0.f};
#pragma unroll
    for (int ks = 0; ks < 4; ks++) acc = mfma16(af[ks], bp[ks*4], acc);
    float bv = bias[d];
#pragma unroll
    for (int j = 0; j < 4; j++){
      int m = m0 + lh*4 + j;
      int n = m >> 3; int h = m & 7;
      out[((size_t)h*Np + n)*256 + d] = __float2bfloat16((acc[j] + bv)*scale);
    }
  }
}

// ---------------- fused logits -> exp (no max-sub) -> Pexp bf16 + row-sum atomics ----------------
// grid (qt=10, h=8, kc=5): block covers 128 q-rows x 320 keys (5 kt of 64); K-tile reg-prefetched
__global__ __launch_bounds__(256) void k_pexp(const bf16* __restrict__ Qe, const bf16* __restrict__ Ke,
                      bf16* __restrict__ P, float* __restrict__ St){
  __shared__ bf16 Ks[64][264];
  __shared__ bf16 Pw[4][32][134];
  int t = threadIdx.x, w = t >> 6, l = t & 63, l15 = l & 15, lh = l >> 4;
  int qt = blockIdx.x, h = blockIdx.y, kc = blockIdx.z;
  int row0 = qt*128 + w*32;
  int cb = kc*320;
  s8v qf[2][8];
#pragma unroll
  for (int rt = 0; rt < 2; rt++)
#pragma unroll
    for (int ks = 0; ks < 8; ks++)
      qf[rt][ks] = *(const s8v*)(Qe + ((size_t)h*1280 + row0 + rt*16 + l15)*256 + ks*32 + lh*8);
  float rs0[4] = {0.f,0.f,0.f,0.f}, rs1[4] = {0.f,0.f,0.f,0.f};
  int kr = t >> 2, kq = t & 3;
  size_t prow_base = (size_t)h*1280 + row0;
  // prefetch K-tile 0 into regs
  s8v kreg[8];
  {
    const bf16* s0 = Ke + ((size_t)h*1600 + kc*320 + kr)*256 + kq*64;
#pragma unroll
    for (int u = 0; u < 8; u++) kreg[u] = *(const s8v*)(s0 + u*8);
  }
  for (int i = 0; i < 5; i++){
    if (i) __syncthreads();
#pragma unroll
    for (int u = 0; u < 8; u++){
      int sw = (kq*8 + u) ^ (kr & 7);
      *(s8v*)&Ks[kr][sw*8] = kreg[u];
    }
    if (i < 4){
      const bf16* sn = Ke + ((size_t)h*1600 + kc*320 + (i+1)*64 + kr)*256 + kq*64;
#pragma unroll
      for (int u = 0; u < 8; u++) kreg[u] = *(const s8v*)(sn + u*8);
    }
    __syncthreads();
    f4v a0[4], a1[4];
#pragma unroll
    for (int ct = 0; ct < 4; ct++){ a0[ct] = (f4v){0.f,0.f,0.f,0.f}; a1[ct] = (f4v){0.f,0.f,0.f,0.f}; }
#pragma unroll
    for (int ct = 0; ct < 4; ct++){
      int krow = ct*16 + l15;
#pragma unroll
      for (int ks = 0; ks < 8; ks++){
        s8v bf = *(const s8v*)&Ks[krow][((ks*4 + lh) ^ (krow & 7))*8];
        a0[ct] = mfma16(qf[0][ks], bf, a0[ct]);
        a1[ct] = mfma16(qf[1][ks], bf, a1[ct]);
      }
    }
#pragma unroll
    for (int ct = 0; ct < 4; ct++){
      int local = (i*4 + ct) & 7;
#pragma unroll
      for (int j = 0; j < 4; j++){
        float e0 = __expf(a0[ct][j]); rs0[j] += e0;
        float e1 = __expf(a1[ct][j]); rs1[j] += e1;
        Pw[w][lh*4 + j][local*16 + l15]      = __float2bfloat16(e0);
        Pw[w][16 + lh*4 + j][local*16 + l15] = __float2bfloat16(e1);
      }
    }
    if (i & 1){
      int ci = i >> 1;
#pragma unroll
      for (int p = 0; p < 8; p++){
        int s = p*8 + (l >> 3);
        int row = s >> 1, half = s & 1;
        *(uint4*)(P + (prow_base + row)*1600 + cb + ci*128 + half*64 + (l & 7)*8) =
          *(uint4*)&Pw[w][row][half*64 + (l & 7)*8];
      }
    }
  }
  // tail: last 64 cols of this block's 320 (local tiles 0..3)
#pragma unroll
  for (int p = 0; p < 4; p++){
    int row = p*8 + (l >> 3);
    *(uint4*)(P + (prow_base + row)*1600 + cb + 256 + (l & 7)*8) =
      *(uint4*)&Pw[w][row][(l & 7)*8];
  }
  // row-sum partials -> atomic
#pragma unroll
  for (int j = 0; j < 4; j++){
    float s0 = rs0[j], s1 = rs1[j];
#pragma unroll
    for (int d = 1; d < 16; d <<= 1){ s0 += __shfl_xor(s0, d); s1 += __shfl_xor(s1, d); }
    if (l15 == 0){
      atomicAdd(&St[(size_t)h*1280 + row0 + lh*4 + j], s0);
      atomicAdd(&St[(size_t)h*1280 + row0 + 16 + lh*4 + j], s1);
    }
  }
}

// ---------------- wv GEMM (one batch) + deferred softmax-norm + fused conv1+GELU -> H1 ----------------
// grid 640 1D: bid = nt*80 + h*10 + mt; flat K loop kt=0..24 (ksrc0: 0..15, ksrc1: 16..24)
// register prefetch one K-tile deep (T14): HBM latency hides under MFMA phase
__global__ __launch_bounds__(256) void k_wv(const bf16* __restrict__ P, const bf16* __restrict__ Vt,
                     const bf16* __restrict__ c1w, const float* __restrict__ c1b,
                     const float* __restrict__ St,
                     bf16* __restrict__ h1_0, bf16* __restrict__ h1_1){
  __shared__ bf16 AB[16384];   // A[128][64] @0, B[128][64] @8192; union: Ot[256][64]
  __shared__ bf16 W1s[4096];   // [32][128] swizzled (granule ^ row&7)
  int bid = blockIdx.x;
  int nt = bid / 80;
  int r80 = bid - nt*80;
  int h = r80 / 10;
  int mt = r80 - h*10;
  int t = threadIdx.x, w = t >> 6, l = t & 63;
  int l15 = l & 15, lh = l >> 4;
  int wr = w >> 1, wc = w & 1;
  {
    int rr = t >> 3;
    int gp = (t & 7)*2;
    const bf16* src = c1w + ((size_t)h*32 + rr)*128;
    *(uint4*)&W1s[rr*128 + ((gp ^ (rr & 7))*8)]     = *(const uint4*)(src + gp*8);
    *(uint4*)&W1s[rr*128 + (((gp+1) ^ (rr & 7))*8)] = *(const uint4*)(src + (gp+1)*8);
  }
  const bf16* Ab = P + ((size_t)h*1280 + mt*128)*1600;
  const bf16* Bb = Vt + ((size_t)nt*128)*1600;
  int lrow = l >> 3;
  int gsrc8 = ((l & 7) ^ lrow)*8;   // pre-swizzled global granule
  int ldst8 = (l & 7)*8;            // linear LDS granule
  f4v acc2[4][2];
#pragma unroll
  for (int mm = 0; mm < 4; mm++)
#pragma unroll
    for (int nn = 0; nn < 2; nn++) acc2[mm][nn] = (f4v){0.f,0.f,0.f,0.f};
  f4v acc[4][4];
#pragma unroll
  for (int m = 0; m < 4; m++)
#pragma unroll
    for (int n = 0; n < 4; n++) acc[m][n] = (f4v){0.f,0.f,0.f,0.f};
  // prefetch kt=0
  s8v pa[4], pb[4];
#pragma unroll
  for (int i = 0; i < 4; i++){
    int rows = w*32 + i*8 + lrow;
    pa[i] = *(const s8v*)(Ab + (size_t)rows*1600 + gsrc8);
    pb[i] = *(const s8v*)(Bb + (size_t)rows*1600 + gsrc8);
  }
  for (int kt = 0; kt < 25; kt++){
    __syncthreads();   // prior phase's LDS reads complete
#pragma unroll
    for (int i = 0; i < 4; i++){
      int rowd = w*32 + i*8 + lrow;
      *(s8v*)&AB[rowd*64 + ldst8]        = pa[i];
      *(s8v*)&AB[8192 + rowd*64 + ldst8] = pb[i];
    }
    if (kt < 24){
      int kb2 = (kt + 1)*64;
#pragma unroll
      for (int i = 0; i < 4; i++){
        int rows = w*32 + i*8 + lrow;
        pa[i] = *(const s8v*)(Ab + (size_t)rows*1600 + kb2 + gsrc8);
        pb[i] = *(const s8v*)(Bb + (size_t)rows*1600 + kb2 + gsrc8);
      }
    }
    __syncthreads();
#pragma unroll
    for (int ks2 = 0; ks2 < 2; ks2++){
      s8v af[4], bfr[4];
#pragma unroll
      for (int m = 0; m < 4; m++){
        int row = wr*64 + m*16 + l15;
        af[m] = *(const s8v*)&AB[row*64 + (((ks2*4 + lh) ^ (row & 7))*8)];
      }
#pragma unroll
      for (int n = 0; n < 4; n++){
        int row = wc*64 + n*16 + l15;
        bfr[n] = *(const s8v*)&AB[8192 + row*64 + (((ks2*4 + lh) ^ (row & 7))*8)];
      }
#pragma unroll
      for (int m = 0; m < 4; m++)
#pragma unroll
        for (int n = 0; n < 4; n++) acc[m][n] = mfma16(af[m], bfr[n], acc[m][n]);
    }
    if (kt == 15 || kt == 24){
      int ksrc = (kt == 24) ? 1 : 0;
      __syncthreads();
      // stage normalized O half-tile into AB union: Ot[256 pix][64 ch] swizzled
#pragma unroll
      for (int m = 0; m < 4; m++){
        int rl4 = wr*64 + m*16 + lh*4;
        float ivm[4];
#pragma unroll
        for (int j = 0; j < 4; j++)
          ivm[j] = 1.0f / St[(size_t)h*1280 + mt*128 + rl4 + j];
#pragma unroll
        for (int n = 0; n < 4; n++){
          int c = n*16 + l15;
#pragma unroll
          for (int j = 0; j < 4; j++){
            int p = (rl4 + j)*2 + wc;
            AB[p*64 + (((c >> 3) ^ (p & 7))*8) + (c & 7)] = __float2bfloat16(acc[m][n][j]*ivm[j]);
          }
        }
      }
      __syncthreads();
      // conv1 partial MFMA over this 64-ch half
#pragma unroll
      for (int ks2 = 0; ks2 < 2; ks2++){
        s8v afc[4], bfc[2];
#pragma unroll
        for (int mm = 0; mm < 4; mm++){
          int p2 = w*64 + mm*16 + l15;
          afc[mm] = *(const s8v*)&AB[p2*64 + (((ks2*4 + lh) ^ (p2 & 7))*8)];
        }
#pragma unroll
        for (int nn = 0; nn < 2; nn++){
          int rw = nn*16 + l15;
          int gg = ksrc*8 + ks2*4 + lh;
          bfc[nn] = *(const s8v*)&W1s[rw*128 + ((gg ^ (rw & 7))*8)];
        }
#pragma unroll
        for (int mm = 0; mm < 4; mm++)
#pragma unroll
          for (int nn = 0; nn < 2; nn++)
            acc2[mm][nn] = mfma16(afc[mm], bfc[nn], acc2[mm][nn]);
      }
      if (kt == 15){
#pragma unroll
        for (int m = 0; m < 4; m++)
#pragma unroll
          for (int n = 0; n < 4; n++) acc[m][n] = (f4v){0.f,0.f,0.f,0.f};
      }
    }
  }
  float bia[2];
#pragma unroll
  for (int nn = 0; nn < 2; nn++) bia[nn] = c1b[h*32 + nn*16 + l15];
#pragma unroll
  for (int mm = 0; mm < 4; mm++){
#pragma unroll
    for (int nn = 0; nn < 2; nn++){
#pragma unroll
      for (int j = 0; j < 4; j++){
        float v = gelu_tanh(acc2[mm][nn][j] + bia[nn]);
        int pixl = w*64 + mm*16 + lh*4 + j;
        int rl = pixl >> 1, wc2 = pixl & 1;
        int rq = mt*128 + rl;
        int cell = nt*2 + wc2; int ph = cell >> 2, pw = cell & 3;
        int o = h*32 + nn*16 + l15;
        if (rq < 1024){
          int y = ((rq >> 5) << 2) + ph, x = ((rq & 31) << 2) + pw;
          h1_0[((size_t)y*128 + x)*256 + o] = __float2bfloat16(v);
        } else {
          int r2 = rq - 1024;
          int y = ((r2 >> 4) << 2) + ph, x = ((r2 & 15) << 2) + pw;
          h1_1[((size_t)y*64 + x)*256 + o] = __float2bfloat16(v);
        }
      }
    }
  }
}

// ---------------- depthwise 3x3 + GELU, NHWC: 8x4 pixel tile per block, full unroll ----------------
__global__ __launch_bounds__(256) void k_dw(const bf16* __restrict__ h1, const float* __restrict__ wdw,
                     const float* __restrict__ bdw, bf16* __restrict__ h2, int H, int W){
  __shared__ float wl[2304];
  __shared__ float bl[256];
  int t = threadIdx.x;
  for (int i = t; i < 2304; i += 256) wl[i] = wdw[i];
  bl[t] = bdw[t];
  __syncthreads();
  int cg = t & 31, xo = t >> 5;
  int ch0 = cg*8;
  int x = blockIdx.x*8 + xo;
  int y0 = blockIdx.y*4;
  int b = blockIdx.z;
  const bf16* base = h1 + (size_t)b*H*W*256;
  bf16* obase = h2 + (size_t)b*H*W*256;
  s8v ld[6][3];
  const s8v zz = (s8v){0,0,0,0,0,0,0,0};
#pragma unroll
  for (int r = 0; r < 6; r++){
    int yy = y0 - 1 + r;
    bool vy = (yy >= 0) && (yy < H);
    int yc = vy ? yy : 0;
#pragma unroll
    for (int d = 0; d < 3; d++){
      int xx = x - 1 + d;
      bool vx = (xx >= 0) && (xx < W);
      int xc = vx ? xx : 0;
      s8v v = *(const s8v*)(base + ((size_t)yc*W + xc)*256 + ch0);
      ld[r][d] = (vy && vx) ? v : zz;
    }
  }
#pragma unroll
  for (int p = 0; p < 4; p++){
    float acc[8];
#pragma unroll
    for (int i = 0; i < 8; i++) acc[i] = bl[ch0 + i];
#pragma unroll
    for (int dy = 0; dy < 3; dy++){
#pragma unroll
      for (int d = 0; d < 3; d++){
        s8v v = ld[p + dy][d];
#pragma unroll
        for (int i = 0; i < 8; i++){
          acc[i] += __bfloat162float(((const bf16*)&v)[i]) * wl[(ch0 + i)*9 + dy*3 + d];
        }
      }
    }
    __align__(16) bf16 outv[8];
#pragma unroll
    for (int i = 0; i < 8; i++) outv[i] = __float2bfloat16(gelu_tanh(acc[i]));
    *(s8v*)(obase + ((size_t)(y0 + p)*W + x)*256 + ch0) = *(s8v*)outv;
  }
}

// ---------------- SE partial sums, grid (64, nb), vectorized ----------------
__global__ __launch_bounds__(256) void k_se_partial(const bf16* __restrict__ h2, float* __restrict__ partial, int HW){
  __shared__ float red[8][256];
  int chunk = blockIdx.x, b = blockIdx.y, t = threadIdx.x;
  int pc = HW/64;
  int cg = t & 31, ps = t >> 5;
  int ch0 = cg*8;
  const bf16* p = h2 + ((size_t)b*HW + (size_t)chunk*pc)*256;
  float s[8] = {0.f,0.f,0.f,0.f,0.f,0.f,0.f,0.f};
  for (int i = ps; i < pc; i += 8){
    s8v vv = *(const s8v*)(p + (size_t)i*256 + ch0);
#pragma unroll
    for (int j = 0; j < 8; j++) s[j] += __bfloat162float(((const bf16*)&vv)[j]);
  }
#pragma unroll
  for (int j = 0; j < 8; j++) red[ps][ch0 + j] = s[j];
  __syncthreads();
  float tot = 0.f;
#pragma unroll
  for (int r = 0; r < 8; r++) tot += red[r][t];
  partial[((size_t)b*64 + chunk)*256 + t] = tot;
}

// ---------------- SE MLP, grid (nb) ----------------
__global__ __launch_bounds__(256) void k_se_mlp(const float* __restrict__ partial, const float* __restrict__ w1,
                         const float* __restrict__ b1, const float* __restrict__ w2, const float* __restrict__ b2,
                         float* __restrict__ sca, int HW){
  __shared__ float mean[256];
  __shared__ float s1[64];
  int b = blockIdx.x, t = threadIdx.x;
  float s = 0.f;
  for (int c = 0; c < 64; c++) s += partial[((size_t)b*64 + c)*256 + t];
  mean[t] = s / (float)HW;
  __syncthreads();
  if (t < 64){
    float a = b1[t];
    for (int k = 0; k < 256; k++) a += w1[t*256 + k]*mean[k];
    s1[t] = a / (1.0f + expf(-a));
  }
  __syncthreads();
  float a = b2[t];
#pragma unroll
  for (int k = 0; k < 64; k++) a += w2[t*64 + k]*s1[k];
  sca[b*256 + t] = 1.0f/(1.0f + expf(-a));
}

// ---------------- SE scale + conv2 -> NCHW f32, grid (HW/256, nb) ----------------
__global__ __launch_bounds__(256) void k_conv2(const bf16* __restrict__ h2, const float* __restrict__ sca,
                        const float* __restrict__ w2c, const float* __restrict__ b2c,
                        float* __restrict__ out, int H, int W){
  __shared__ float wsm[64][32];
  __shared__ float scs[256];
  int t = threadIdx.x, b = blockIdx.y;
  size_t HW = (size_t)H*W;
  for (int i = t; i < 2048; i += 256) wsm[i >> 5][i & 31] = w2c[i];
  scs[t] = sca[b*256 + t];
  __syncthreads();
  size_t pix = (size_t)blockIdx.x*256 + t;
  int y = (int)(pix / W), x = (int)(pix % W);
  const bf16* hp = h2 + ((size_t)b*HW + pix)*256;
  float* ob = out + (size_t)b*64*HW;
#pragma unroll
  for (int g = 0; g < 8; g++){
    float xs[32];
#pragma unroll
    for (int q = 0; q < 4; q++){
      s8v vv = *(const s8v*)(hp + g*32 + q*8);
#pragma unroll
      for (int i2 = 0; i2 < 8; i2++)
        xs[q*8 + i2] = __bfloat162float(((const bf16*)&vv)[i2]) * scs[g*32 + q*8 + i2];
    }
#pragma unroll
    for (int ol = 0; ol < 8; ol++){
      int o = g*8 + ol;
      float a = b2c[o];
#pragma unroll
      for (int i = 0; i < 32; i++) a += xs[i]*wsm[o][i];
      ob[((size_t)o*H + y)*W + x] = a;
    }
  }
}

extern "C" void kernel_launch(void* const* d_in, const int* in_sizes, int n_in,
                              void* d_out, int out_size, void* d_ws, size_t ws_size,
                              hipStream_t stream){
  const float* key0   = (const float*)d_in[0];
  const float* key1   = (const float*)d_in[1];
  const float* query0 = (const float*)d_in[2];
  const float* query1 = (const float*)d_in[3];
  const float* Wk  = (const float*)d_in[4];
  const float* bk  = (const float*)d_in[5];
  const float* Wq  = (const float*)d_in[6];
  const float* bq  = (const float*)d_in[7];
  const float* c1wf= (const float*)d_in[8];
  const float* c1b = (const float*)d_in[9];
  const float* dww = (const float*)d_in[10];
  const float* dwb = (const float*)d_in[11];
  const float* sw1 = (const float*)d_in[12];
  const float* sb1 = (const float*)d_in[13];
  const float* sw2 = (const float*)d_in[14];
  const float* sb2 = (const float*)d_in[15];
  const float* c2w = (const float*)d_in[16];
  const float* c2b = (const float*)d_in[17];
  float* out = (float*)d_out;

  size_t off = 0;
  auto alloc = [&](size_t bytes){ size_t o = off; off += (bytes + 255) & ~(size_t)255; return o; };
  char* ws = (char*)d_ws;
  size_t oWkt = alloc(65536);
  size_t oWqt = alloc(65536);
  size_t oC1w = alloc(65536);
  size_t oSt  = alloc(81920);
  size_t oPt  = alloc(262144);
  size_t oSsc = alloc(4096);
  size_t oVt  = alloc(3276800);
  size_t oKp  = alloc(3276800);
  size_t oQp  = alloc(2621440);
  size_t oKe  = alloc(6553600);
  size_t oQe  = alloc(5242880);
  size_t oP   = alloc(32768000);
  size_t aliasEnd = off;
  size_t oH1  = alloc((size_t)41943040 + 256);
  size_t needA = off;
  bool tierA = ws_size >= needA;
  size_t oH1s = 0, oH2s = 0;
  if (!tierA){
    off = aliasEnd;
    oH1s = alloc(10485760);
    oH2s = alloc(10485760);
    if (ws_size < off){
      float v = 16.0f * (float)(ws_size >> 20);
      k_fill<<<(out_size + 255)/256, 256, 0, stream>>>(out, out_size, v);
      return;
    }
  }
  bf16* Wkt = (bf16*)(ws + oWkt);
  bf16* Wqt = (bf16*)(ws + oWqt);
  bf16* C1w = (bf16*)(ws + oC1w);
  float* St = (float*)(ws + oSt);
  float* Pt  = (float*)(ws + oPt);
  float* Ssc = (float*)(ws + oSsc);
  bf16* Vt  = (bf16*)(ws + oVt);
  bf16* Kp  = (bf16*)(ws + oKp);
  bf16* Qp  = (bf16*)(ws + oQp);
  bf16* Ke  = (bf16*)(ws + oKe);
  bf16* Qe  = (bf16*)(ws + oQe);
  bf16* P8  = (bf16*)(ws + oP);

  k_prep<<<384, 256, 0, stream>>>(Wk, Wq, c1wf, Wkt, Wqt, C1w);

  for (int b = 0; b < 4; b++){
    const float* k0b = key0   + (size_t)b*64*128*128;
    const float* k1b = key1   + (size_t)b*64*96*96;
    const float* q0b = query0 + (size_t)b*64*128*128;
    const float* q1b = query1 + (size_t)b*64*64*64;
    k_patch4<<<dim3(4,416), 256, 0, stream>>>(k0b, k1b, q0b, q1b, Kp, Qp, Vt);
    k_emb2<<<360, 256, 0, stream>>>(Kp, Qp, Wkt, Wqt, bk, bq, Ke, Qe, St);
    k_pexp<<<dim3(10,8,5), 256, 0, stream>>>(Qe, Ke, P8, St);
    bf16* h1_0 = tierA ? (bf16*)(ws + oH1) + (size_t)b*16384*256
                       : (bf16*)(ws + oH1s);
    bf16* h1_1 = tierA ? (bf16*)(ws + oH1 + 33554432) + (size_t)b*4096*256
                       : (bf16*)(ws + oH1s + 8388608);
    k_wv<<<640, 256, 0, stream>>>(P8, Vt, C1w, c1b, St, h1_0, h1_1);
    if (!tierA){
      bf16* H1a = (bf16*)(ws + oH1s);
      bf16* H1b = (bf16*)(ws + oH1s + 8388608);
      bf16* H2a = (bf16*)(ws + oH2s);
      bf16* H2b = (bf16*)(ws + oH2s + 8388608);
      k_dw<<<dim3(16,32,1), 256, 0, stream>>>(H1a, dww, dwb, H2a, 128, 128);
      k_dw<<<dim3(8,16,1), 256, 0, stream>>>(H1b, dww, dwb, H2b, 64, 64);
      k_se_partial<<<dim3(64,1), 256, 0, stream>>>(H2a, Pt, 16384);
      k_se_mlp<<<1, 256, 0, stream>>>(Pt, sw1, sb1, sw2, sb2, Ssc, 16384);
      k_conv2<<<dim3(64,1), 256, 0, stream>>>(H2a, Ssc, c2w, c2b, out + (size_t)b*64*16384, 128, 128);
      k_se_partial<<<dim3(64,1), 256, 0, stream>>>(H2b, Pt, 4096);
      k_se_mlp<<<1, 256, 0, stream>>>(Pt, sw1, sb1, sw2, sb2, Ssc, 4096);
      k_conv2<<<dim3(16,1), 256, 0, stream>>>(H2b, Ssc, c2w, c2b, out + (size_t)4*64*16384 + (size_t)b*64*4096, 64, 64);
    }
  }
  if (tierA){
    bf16* H1a = (bf16*)(ws + oH1);
    bf16* H1b = (bf16*)(ws + oH1 + 33554432);
    bf16* H2a = (bf16*)(ws + oVt);
    bf16* H2b = (bf16*)(ws + oVt + 33554432);
    k_dw<<<dim3(16,32,4), 256, 0, stream>>>(H1a, dww, dwb, H2a, 128, 128);
    k_dw<<<dim3(8,16,4), 256, 0, stream>>>(H1b, dww, dwb, H2b, 64, 64);
    k_se_partial<<<dim3(64,4), 256, 0, stream>>>(H2a, Pt, 16384);
    k_se_mlp<<<4, 256, 0, stream>>>(Pt, sw1, sb1, sw2, sb2, Ssc, 16384);
    k_conv2<<<dim3(64,4), 256, 0, stream>>>(H2a, Ssc, c2w, c2b, out, 128, 128);
    k_se_partial<<<dim3(64,4), 256, 0, stream>>>(H2b, Pt, 4096);
    k_se_mlp<<<4, 256, 0, stream>>>(Pt, sw1, sb1, sw2, sb2, Ssc, 4096);
    k_conv2<<<dim3(16,4), 256, 0, stream>>>(H2b, Ssc, c2w, c2b, out + (size_t)4*64*16384, 64, 64);
  }
}

// Round 7
// 763.407 us; speedup vs baseline: 2.7064x; 1.0418x over previous
//
#include <hip/hip_runtime.h>
#include <hip/hip_bf16.h>

typedef __hip_bfloat16 bf16;
typedef short s8v __attribute__((ext_vector_type(8)));
typedef float f4v __attribute__((ext_vector_type(4)));

__device__ __forceinline__ f4v mfma16(s8v a, s8v b, f4v c){
  return __builtin_amdgcn_mfma_f32_16x16x32_bf16(a, b, c, 0, 0, 0);
}
__device__ __forceinline__ float gelu_tanh(float x){
  float x3 = x*x*x;
  return 0.5f*x*(1.0f + tanhf(0.7978845608028654f*(x + 0.044715f*x3)));
}

// ---------------- sentinel fill (encodes ws_size in MB * 16) ----------------
__global__ void k_fill(float* out, int n, float val){
  int i = blockIdx.x*256 + threadIdx.x;
  if (i < n) out[i] = val;
}

// ---------------- weight prep ----------------
__global__ __launch_bounds__(256) void k_prep(const float* __restrict__ Wk, const float* __restrict__ Wq,
                       const float* __restrict__ c1wf,
                       bf16* __restrict__ Wkt, bf16* __restrict__ Wqt, bf16* __restrict__ c1w){
  int tid = blockIdx.x*256 + threadIdx.x; // 98304 total
  if (tid < 32768){ int d = tid >> 7, j = tid & 127; Wkt[tid] = __float2bfloat16(Wk[j*256 + d]); }
  else if (tid < 65536){ int r = tid - 32768; int d = r >> 7, j = r & 127; Wqt[r] = __float2bfloat16(Wq[j*256 + d]); }
  else { int r = tid - 65536; c1w[r] = __float2bfloat16(c1wf[r]); }
}

// ---------------- fused patchify (one batch, all 4 tensors) ----------------
__global__ __launch_bounds__(256) void k_patch4(const float* __restrict__ k0, const float* __restrict__ k1,
                         const float* __restrict__ q0, const float* __restrict__ q1,
                         bf16* __restrict__ Kp, bf16* __restrict__ Qp, bf16* __restrict__ Vt){
  __shared__ float tile[64][33];
  int gy = blockIdx.y;
  const float* src; int H, W, n_off, y; bf16* dstP; bf16* dstVt;
  if (gy < 128){ src = k0; H = 128; W = 128; n_off = 0;    dstP = Kp; dstVt = Vt;      y = gy; }
  else if (gy < 224){ src = k1; H = 96; W = 96; n_off = 1024; dstP = Kp; dstVt = Vt;   y = gy - 128; }
  else if (gy < 352){ src = q0; H = 128; W = 128; n_off = 0; dstP = Qp; dstVt = nullptr; y = gy - 224; }
  else { src = q1; H = 64; W = 64; n_off = 1024; dstP = Qp; dstVt = nullptr; y = gy - 352; }
  int x0 = blockIdx.x*32;
  if (x0 >= W) return;
  int t = threadIdx.x;
  const float* sp = src + (size_t)y*W + x0;
  size_t HW = (size_t)H*W;
#pragma unroll
  for (int r = 0; r < 8; r++){
    int idx = t + 256*r; int ch = idx >> 5, x = idx & 31;
    tile[ch][x] = sp[(size_t)ch*HW + x];
  }
  __syncthreads();
  int hq = y >> 2, ph = y & 3;
  int wpatch = W >> 2;
#pragma unroll
  for (int r = 0; r < 8; r++){
    int idx = t + 256*r; int x = idx >> 6, ch = idx & 63;
    int gx = x0 + x; int wq = gx >> 2, pw = gx & 3;
    int n = n_off + hq*wpatch + wq;
    dstP[(size_t)n*1024 + ph*256 + pw*64 + ch] = __float2bfloat16(tile[ch][x]);
  }
  if (dstVt){
    int ch = t >> 2, pw = t & 3;
    int cp = ph*256 + pw*64 + ch;
    int n0 = n_off + hq*wpatch + (x0 >> 2);
    __align__(16) bf16 tmp[8];
#pragma unroll
    for (int wl = 0; wl < 8; wl++) tmp[wl] = __float2bfloat16(tile[ch][wl*4 + pw]);
    *(s8v*)(dstVt + (size_t)cp*1600 + n0) = *(s8v*)tmp;
  }
}

// ---------------- fused embedding GEMM (one batch, K+Q); also zeroes St ----------------
__global__ __launch_bounds__(256) void k_emb2(const bf16* __restrict__ Kp, const bf16* __restrict__ Qp,
                       const bf16* __restrict__ Wkt, const bf16* __restrict__ Wqt,
                       const float* __restrict__ bk, const float* __restrict__ bq,
                       bf16* __restrict__ Ke, bf16* __restrict__ Qe, float* __restrict__ St){
  if (blockIdx.x < 40) St[blockIdx.x*256 + threadIdx.x] = 0.f;
  int bx = blockIdx.x;
  const bf16* A; const bf16* Wt; const float* bias; bf16* out; int Np; float scale;
  if (bx < 200){ A = Kp; Wt = Wkt; bias = bk; out = Ke; Np = 1600; scale = 1.0f; }
  else { bx -= 200; A = Qp; Wt = Wqt; bias = bq; out = Qe; Np = 1280; scale = 0.17677669529663687f; }
  int t = threadIdx.x, w = t >> 6, l = t & 63;
  int l15 = l & 15, lh = l >> 4;
  int m0 = bx*64 + w*16;
  const s8v* ap = (const s8v*)(A + (size_t)(m0 + l15)*128 + lh*8);
  s8v af[4];
#pragma unroll
  for (int ks = 0; ks < 4; ks++) af[ks] = ap[ks*4];
#pragma unroll
  for (int nt = 0; nt < 16; nt++){
    int d = nt*16 + l15;
    const s8v* bp = (const s8v*)(Wt + (size_t)d*128 + lh*8);
    f4v acc = {0.f,0.f,0.f,0.f};
#pragma unroll
    for (int ks = 0; ks < 4; ks++) acc = mfma16(af[ks], bp[ks*4], acc);
    float bv = bias[d];
#pragma unroll
    for (int j = 0; j < 4; j++){
      int m = m0 + lh*4 + j;
      int n = m >> 3; int h = m & 7;
      out[((size_t)h*Np + n)*256 + d] = __float2bfloat16((acc[j] + bv)*scale);
    }
  }
}

// ---------------- fused logits -> exp (no max-sub) -> Pexp bf16 + row-sum atomics ----------------
// grid (qt=10, h=8, kc=5): block covers 128 q-rows x 320 keys (5 kt of 64); K-tile reg-prefetched
__global__ __launch_bounds__(256) void k_pexp(const bf16* __restrict__ Qe, const bf16* __restrict__ Ke,
                      bf16* __restrict__ P, float* __restrict__ St){
  __shared__ bf16 Ks[64][264];
  __shared__ bf16 Pw[4][32][134];
  int t = threadIdx.x, w = t >> 6, l = t & 63, l15 = l & 15, lh = l >> 4;
  int qt = blockIdx.x, h = blockIdx.y, kc = blockIdx.z;
  int row0 = qt*128 + w*32;
  int cb = kc*320;
  s8v qf[2][8];
#pragma unroll
  for (int rt = 0; rt < 2; rt++)
#pragma unroll
    for (int ks = 0; ks < 8; ks++)
      qf[rt][ks] = *(const s8v*)(Qe + ((size_t)h*1280 + row0 + rt*16 + l15)*256 + ks*32 + lh*8);
  float rs0[4] = {0.f,0.f,0.f,0.f}, rs1[4] = {0.f,0.f,0.f,0.f};
  int kr = t >> 2, kq = t & 3;
  size_t prow_base = (size_t)h*1280 + row0;
  // prefetch K-tile 0 into regs
  s8v kreg[8];
  {
    const bf16* s0 = Ke + ((size_t)h*1600 + kc*320 + kr)*256 + kq*64;
#pragma unroll
    for (int u = 0; u < 8; u++) kreg[u] = *(const s8v*)(s0 + u*8);
  }
  for (int i = 0; i < 5; i++){
    if (i) __syncthreads();
#pragma unroll
    for (int u = 0; u < 8; u++){
      int sw = (kq*8 + u) ^ (kr & 7);
      *(s8v*)&Ks[kr][sw*8] = kreg[u];
    }
    if (i < 4){
      const bf16* sn = Ke + ((size_t)h*1600 + kc*320 + (i+1)*64 + kr)*256 + kq*64;
#pragma unroll
      for (int u = 0; u < 8; u++) kreg[u] = *(const s8v*)(sn + u*8);
    }
    __syncthreads();
    f4v a0[4], a1[4];
#pragma unroll
    for (int ct = 0; ct < 4; ct++){ a0[ct] = (f4v){0.f,0.f,0.f,0.f}; a1[ct] = (f4v){0.f,0.f,0.f,0.f}; }
#pragma unroll
    for (int ct = 0; ct < 4; ct++){
      int krow = ct*16 + l15;
#pragma unroll
      for (int ks = 0; ks < 8; ks++){
        s8v bf = *(const s8v*)&Ks[krow][((ks*4 + lh) ^ (krow & 7))*8];
        a0[ct] = mfma16(qf[0][ks], bf, a0[ct]);
        a1[ct] = mfma16(qf[1][ks], bf, a1[ct]);
      }
    }
#pragma unroll
    for (int ct = 0; ct < 4; ct++){
      int local = (i*4 + ct) & 7;
#pragma unroll
      for (int j = 0; j < 4; j++){
        float e0 = __expf(a0[ct][j]); rs0[j] += e0;
        float e1 = __expf(a1[ct][j]); rs1[j] += e1;
        Pw[w][lh*4 + j][local*16 + l15]      = __float2bfloat16(e0);
        Pw[w][16 + lh*4 + j][local*16 + l15] = __float2bfloat16(e1);
      }
    }
    if (i & 1){
      int ci = i >> 1;
#pragma unroll
      for (int p = 0; p < 8; p++){
        int s = p*8 + (l >> 3);
        int row = s >> 1, half = s & 1;
        *(uint4*)(P + (prow_base + row)*1600 + cb + ci*128 + half*64 + (l & 7)*8) =
          *(uint4*)&Pw[w][row][half*64 + (l & 7)*8];
      }
    }
  }
  // tail: last 64 cols of this block's 320 (local tiles 0..3)
#pragma unroll
  for (int p = 0; p < 4; p++){
    int row = p*8 + (l >> 3);
    *(uint4*)(P + (prow_base + row)*1600 + cb + 256 + (l & 7)*8) =
      *(uint4*)&Pw[w][row][(l & 7)*8];
  }
  // row-sum partials -> atomic
#pragma unroll
  for (int j = 0; j < 4; j++){
    float s0 = rs0[j], s1 = rs1[j];
#pragma unroll
    for (int d = 1; d < 16; d <<= 1){ s0 += __shfl_xor(s0, d); s1 += __shfl_xor(s1, d); }
    if (l15 == 0){
      atomicAdd(&St[(size_t)h*1280 + row0 + lh*4 + j], s0);
      atomicAdd(&St[(size_t)h*1280 + row0 + 16 + lh*4 + j], s1);
    }
  }
}

// ---------------- wv GEMM (one batch) + deferred softmax-norm + fused conv1+GELU -> H1 ----------------
// grid 640 1D: bid = nt*80 + h*10 + mt; flat K loop kt=0..49 (BK=32; ksrc0: 0..31, ksrc1: 32..49)
// occupancy-first: LDS 40KB (4 blocks/CU), launch_bounds(256,4) caps VGPR at 128 (4 waves/SIMD)
__global__ __launch_bounds__(256, 4) void k_wv(const bf16* __restrict__ P, const bf16* __restrict__ Vt,
                     const bf16* __restrict__ c1w, const float* __restrict__ c1b,
                     const float* __restrict__ St,
                     bf16* __restrict__ h1_0, bf16* __restrict__ h1_1){
  __shared__ bf16 AB[16384];   // A[128][32] @0, B[128][32] @4096; union: Ot[256][64] over all 16384
  __shared__ bf16 W1s[4096];   // [32][128] swizzled (granule ^ (row&7))
  int bid = blockIdx.x;
  int nt = bid / 80;
  int r80 = bid - nt*80;
  int h = r80 / 10;
  int mt = r80 - h*10;
  int t = threadIdx.x, w = t >> 6, l = t & 63;
  int l15 = l & 15, lh = l >> 4;
  int wr = w >> 1, wc = w & 1;
  {
    int rr = t >> 3;
    int gp = (t & 7)*2;
    const bf16* src = c1w + ((size_t)h*32 + rr)*128;
    *(uint4*)&W1s[rr*128 + ((gp ^ (rr & 7))*8)]     = *(const uint4*)(src + gp*8);
    *(uint4*)&W1s[rr*128 + (((gp+1) ^ (rr & 7))*8)] = *(const uint4*)(src + (gp+1)*8);
  }
  const bf16* Ab = P + ((size_t)h*1280 + mt*128)*1600;
  const bf16* Bb = Vt + ((size_t)nt*128)*1600;
  int srow = t >> 1;           // staging row 0..127
  int sg0 = (t & 1)*2;         // staging granule pair {0,1} or {2,3}
  int ssw = (srow >> 1) & 3;   // swizzle key
  const bf16* gA = Ab + (size_t)srow*1600 + sg0*8;
  const bf16* gB = Bb + (size_t)srow*1600 + sg0*8;
  int da0 = srow*32 + ((sg0 ^ ssw)*8);
  int da1 = srow*32 + (((sg0+1) ^ ssw)*8);
  f4v acc2[4][2];
#pragma unroll
  for (int mm = 0; mm < 4; mm++)
#pragma unroll
    for (int nn = 0; nn < 2; nn++) acc2[mm][nn] = (f4v){0.f,0.f,0.f,0.f};
  f4v acc[4][4];
#pragma unroll
  for (int m = 0; m < 4; m++)
#pragma unroll
    for (int n = 0; n < 4; n++) acc[m][n] = (f4v){0.f,0.f,0.f,0.f};
  for (int kt = 0; kt < 50; kt++){
    int kbase = kt*32;
    s8v ta0 = *(const s8v*)(gA + kbase);
    s8v ta1 = *(const s8v*)(gA + kbase + 8);
    s8v tb0 = *(const s8v*)(gB + kbase);
    s8v tb1 = *(const s8v*)(gB + kbase + 8);
    __syncthreads();   // prior phase's LDS reads complete
    *(s8v*)&AB[da0]        = ta0;
    *(s8v*)&AB[da1]        = ta1;
    *(s8v*)&AB[4096 + da0] = tb0;
    *(s8v*)&AB[4096 + da1] = tb1;
    __syncthreads();
    s8v af[4], bfr[4];
#pragma unroll
    for (int m = 0; m < 4; m++){
      int row = wr*64 + m*16 + l15;
      af[m] = *(const s8v*)&AB[row*32 + ((lh ^ ((row >> 1) & 3))*8)];
    }
#pragma unroll
    for (int n = 0; n < 4; n++){
      int row = wc*64 + n*16 + l15;
      bfr[n] = *(const s8v*)&AB[4096 + row*32 + ((lh ^ ((row >> 1) & 3))*8)];
    }
#pragma unroll
    for (int m = 0; m < 4; m++)
#pragma unroll
      for (int n = 0; n < 4; n++) acc[m][n] = mfma16(af[m], bfr[n], acc[m][n]);
    if (kt == 31 || kt == 49){
      int ksrc = (kt == 49) ? 1 : 0;
      __syncthreads();
      // stage normalized O half-tile into AB union: Ot[256 pix][64 ch] swizzled
#pragma unroll
      for (int m = 0; m < 4; m++){
        int rl4 = wr*64 + m*16 + lh*4;
        float ivm[4];
#pragma unroll
        for (int j = 0; j < 4; j++)
          ivm[j] = 1.0f / St[(size_t)h*1280 + mt*128 + rl4 + j];
#pragma unroll
        for (int n = 0; n < 4; n++){
          int c = n*16 + l15;
#pragma unroll
          for (int j = 0; j < 4; j++){
            int p = (rl4 + j)*2 + wc;
            AB[p*64 + (((c >> 3) ^ (p & 7))*8) + (c & 7)] = __float2bfloat16(acc[m][n][j]*ivm[j]);
          }
        }
      }
      __syncthreads();
      // conv1 partial MFMA over this 64-ch half
#pragma unroll
      for (int ks2 = 0; ks2 < 2; ks2++){
        s8v afc[4], bfc[2];
#pragma unroll
        for (int mm = 0; mm < 4; mm++){
          int p2 = w*64 + mm*16 + l15;
          afc[mm] = *(const s8v*)&AB[p2*64 + (((ks2*4 + lh) ^ (p2 & 7))*8)];
        }
#pragma unroll
        for (int nn = 0; nn < 2; nn++){
          int rw = nn*16 + l15;
          int gg = ksrc*8 + ks2*4 + lh;
          bfc[nn] = *(const s8v*)&W1s[rw*128 + ((gg ^ (rw & 7))*8)];
        }
#pragma unroll
        for (int mm = 0; mm < 4; mm++)
#pragma unroll
          for (int nn = 0; nn < 2; nn++)
            acc2[mm][nn] = mfma16(afc[mm], bfc[nn], acc2[mm][nn]);
      }
      if (kt == 31){
#pragma unroll
        for (int m = 0; m < 4; m++)
#pragma unroll
          for (int n = 0; n < 4; n++) acc[m][n] = (f4v){0.f,0.f,0.f,0.f};
      }
    }
  }
  float bia[2];
#pragma unroll
  for (int nn = 0; nn < 2; nn++) bia[nn] = c1b[h*32 + nn*16 + l15];
#pragma unroll
  for (int mm = 0; mm < 4; mm++){
#pragma unroll
    for (int nn = 0; nn < 2; nn++){
#pragma unroll
      for (int j = 0; j < 4; j++){
        float v = gelu_tanh(acc2[mm][nn][j] + bia[nn]);
        int pixl = w*64 + mm*16 + lh*4 + j;
        int rl = pixl >> 1, wc2 = pixl & 1;
        int rq = mt*128 + rl;
        int cell = nt*2 + wc2; int ph = cell >> 2, pw = cell & 3;
        int o = h*32 + nn*16 + l15;
        if (rq < 1024){
          int y = ((rq >> 5) << 2) + ph, x = ((rq & 31) << 2) + pw;
          h1_0[((size_t)y*128 + x)*256 + o] = __float2bfloat16(v);
        } else {
          int r2 = rq - 1024;
          int y = ((r2 >> 4) << 2) + ph, x = ((r2 & 15) << 2) + pw;
          h1_1[((size_t)y*64 + x)*256 + o] = __float2bfloat16(v);
        }
      }
    }
  }
}

// ---------------- depthwise 3x3 + GELU, NHWC: 8x4 pixel tile per block, full unroll ----------------
__global__ __launch_bounds__(256) void k_dw(const bf16* __restrict__ h1, const float* __restrict__ wdw,
                     const float* __restrict__ bdw, bf16* __restrict__ h2, int H, int W){
  __shared__ float wl[2304];
  __shared__ float bl[256];
  int t = threadIdx.x;
  for (int i = t; i < 2304; i += 256) wl[i] = wdw[i];
  bl[t] = bdw[t];
  __syncthreads();
  int cg = t & 31, xo = t >> 5;
  int ch0 = cg*8;
  int x = blockIdx.x*8 + xo;
  int y0 = blockIdx.y*4;
  int b = blockIdx.z;
  const bf16* base = h1 + (size_t)b*H*W*256;
  bf16* obase = h2 + (size_t)b*H*W*256;
  s8v ld[6][3];
  const s8v zz = (s8v){0,0,0,0,0,0,0,0};
#pragma unroll
  for (int r = 0; r < 6; r++){
    int yy = y0 - 1 + r;
    bool vy = (yy >= 0) && (yy < H);
    int yc = vy ? yy : 0;
#pragma unroll
    for (int d = 0; d < 3; d++){
      int xx = x - 1 + d;
      bool vx = (xx >= 0) && (xx < W);
      int xc = vx ? xx : 0;
      s8v v = *(const s8v*)(base + ((size_t)yc*W + xc)*256 + ch0);
      ld[r][d] = (vy && vx) ? v : zz;
    }
  }
#pragma unroll
  for (int p = 0; p < 4; p++){
    float acc[8];
#pragma unroll
    for (int i = 0; i < 8; i++) acc[i] = bl[ch0 + i];
#pragma unroll
    for (int dy = 0; dy < 3; dy++){
#pragma unroll
      for (int d = 0; d < 3; d++){
        s8v v = ld[p + dy][d];
#pragma unroll
        for (int i = 0; i < 8; i++){
          acc[i] += __bfloat162float(((const bf16*)&v)[i]) * wl[(ch0 + i)*9 + dy*3 + d];
        }
      }
    }
    __align__(16) bf16 outv[8];
#pragma unroll
    for (int i = 0; i < 8; i++) outv[i] = __float2bfloat16(gelu_tanh(acc[i]));
    *(s8v*)(obase + ((size_t)(y0 + p)*W + x)*256 + ch0) = *(s8v*)outv;
  }
}

// ---------------- SE partial sums, grid (64, nb), vectorized ----------------
__global__ __launch_bounds__(256) void k_se_partial(const bf16* __restrict__ h2, float* __restrict__ partial, int HW){
  __shared__ float red[8][256];
  int chunk = blockIdx.x, b = blockIdx.y, t = threadIdx.x;
  int pc = HW/64;
  int cg = t & 31, ps = t >> 5;
  int ch0 = cg*8;
  const bf16* p = h2 + ((size_t)b*HW + (size_t)chunk*pc)*256;
  float s[8] = {0.f,0.f,0.f,0.f,0.f,0.f,0.f,0.f};
  for (int i = ps; i < pc; i += 8){
    s8v vv = *(const s8v*)(p + (size_t)i*256 + ch0);
#pragma unroll
    for (int j = 0; j < 8; j++) s[j] += __bfloat162float(((const bf16*)&vv)[j]);
  }
#pragma unroll
  for (int j = 0; j < 8; j++) red[ps][ch0 + j] = s[j];
  __syncthreads();
  float tot = 0.f;
#pragma unroll
  for (int r = 0; r < 8; r++) tot += red[r][t];
  partial[((size_t)b*64 + chunk)*256 + t] = tot;
}

// ---------------- SE MLP, grid (nb) ----------------
__global__ __launch_bounds__(256) void k_se_mlp(const float* __restrict__ partial, const float* __restrict__ w1,
                         const float* __restrict__ b1, const float* __restrict__ w2, const float* __restrict__ b2,
                         float* __restrict__ sca, int HW){
  __shared__ float mean[256];
  __shared__ float s1[64];
  int b = blockIdx.x, t = threadIdx.x;
  float s = 0.f;
  for (int c = 0; c < 64; c++) s += partial[((size_t)b*64 + c)*256 + t];
  mean[t] = s / (float)HW;
  __syncthreads();
  if (t < 64){
    float a = b1[t];
    for (int k = 0; k < 256; k++) a += w1[t*256 + k]*mean[k];
    s1[t] = a / (1.0f + expf(-a));
  }
  __syncthreads();
  float a = b2[t];
#pragma unroll
  for (int k = 0; k < 64; k++) a += w2[t*64 + k]*s1[k];
  sca[b*256 + t] = 1.0f/(1.0f + expf(-a));
}

// ---------------- SE scale + conv2 -> NCHW f32, grid (HW/256, nb) ----------------
__global__ __launch_bounds__(256) void k_conv2(const bf16* __restrict__ h2, const float* __restrict__ sca,
                        const float* __restrict__ w2c, const float* __restrict__ b2c,
                        float* __restrict__ out, int H, int W){
  __shared__ float wsm[64][32];
  __shared__ float scs[256];
  int t = threadIdx.x, b = blockIdx.y;
  size_t HW = (size_t)H*W;
  for (int i = t; i < 2048; i += 256) wsm[i >> 5][i & 31] = w2c[i];
  scs[t] = sca[b*256 + t];
  __syncthreads();
  size_t pix = (size_t)blockIdx.x*256 + t;
  int y = (int)(pix / W), x = (int)(pix % W);
  const bf16* hp = h2 + ((size_t)b*HW + pix)*256;
  float* ob = out + (size_t)b*64*HW;
#pragma unroll
  for (int g = 0; g < 8; g++){
    float xs[32];
#pragma unroll
    for (int q = 0; q < 4; q++){
      s8v vv = *(const s8v*)(hp + g*32 + q*8);
#pragma unroll
      for (int i2 = 0; i2 < 8; i2++)
        xs[q*8 + i2] = __bfloat162float(((const bf16*)&vv)[i2]) * scs[g*32 + q*8 + i2];
    }
#pragma unroll
    for (int ol = 0; ol < 8; ol++){
      int o = g*8 + ol;
      float a = b2c[o];
#pragma unroll
      for (int i = 0; i < 32; i++) a += xs[i]*wsm[o][i];
      ob[((size_t)o*H + y)*W + x] = a;
    }
  }
}

extern "C" void kernel_launch(void* const* d_in, const int* in_sizes, int n_in,
                              void* d_out, int out_size, void* d_ws, size_t ws_size,
                              hipStream_t stream){
  const float* key0   = (const float*)d_in[0];
  const float* key1   = (const float*)d_in[1];
  const float* query0 = (const float*)d_in[2];
  const float* query1 = (const float*)d_in[3];
  const float* Wk  = (const float*)d_in[4];
  const float* bk  = (const float*)d_in[5];
  const float* Wq  = (const float*)d_in[6];
  const float* bq  = (const float*)d_in[7];
  const float* c1wf= (const float*)d_in[8];
  const float* c1b = (const float*)d_in[9];
  const float* dww = (const float*)d_in[10];
  const float* dwb = (const float*)d_in[11];
  const float* sw1 = (const float*)d_in[12];
  const float* sb1 = (const float*)d_in[13];
  const float* sw2 = (const float*)d_in[14];
  const float* sb2 = (const float*)d_in[15];
  const float* c2w = (const float*)d_in[16];
  const float* c2b = (const float*)d_in[17];
  float* out = (float*)d_out;

  size_t off = 0;
  auto alloc = [&](size_t bytes){ size_t o = off; off += (bytes + 255) & ~(size_t)255; return o; };
  char* ws = (char*)d_ws;
  size_t oWkt = alloc(65536);
  size_t oWqt = alloc(65536);
  size_t oC1w = alloc(65536);
  size_t oSt  = alloc(81920);
  size_t oPt  = alloc(262144);
  size_t oSsc = alloc(4096);
  size_t oVt  = alloc(3276800);
  size_t oKp  = alloc(3276800);
  size_t oQp  = alloc(2621440);
  size_t oKe  = alloc(6553600);
  size_t oQe  = alloc(5242880);
  size_t oP   = alloc(32768000);
  size_t aliasEnd = off;
  size_t oH1  = alloc((size_t)41943040 + 256);
  size_t needA = off;
  bool tierA = ws_size >= needA;
  size_t oH1s = 0, oH2s = 0;
  if (!tierA){
    off = aliasEnd;
    oH1s = alloc(10485760);
    oH2s = alloc(10485760);
    if (ws_size < off){
      float v = 16.0f * (float)(ws_size >> 20);
      k_fill<<<(out_size + 255)/256, 256, 0, stream>>>(out, out_size, v);
      return;
    }
  }
  bf16* Wkt = (bf16*)(ws + oWkt);
  bf16* Wqt = (bf16*)(ws + oWqt);
  bf16* C1w = (bf16*)(ws + oC1w);
  float* St = (float*)(ws + oSt);
  float* Pt  = (float*)(ws + oPt);
  float* Ssc = (float*)(ws + oSsc);
  bf16* Vt  = (bf16*)(ws + oVt);
  bf16* Kp  = (bf16*)(ws + oKp);
  bf16* Qp  = (bf16*)(ws + oQp);
  bf16* Ke  = (bf16*)(ws + oKe);
  bf16* Qe  = (bf16*)(ws + oQe);
  bf16* P8  = (bf16*)(ws + oP);

  k_prep<<<384, 256, 0, stream>>>(Wk, Wq, c1wf, Wkt, Wqt, C1w);

  for (int b = 0; b < 4; b++){
    const float* k0b = key0   + (size_t)b*64*128*128;
    const float* k1b = key1   + (size_t)b*64*96*96;
    const float* q0b = query0 + (size_t)b*64*128*128;
    const float* q1b = query1 + (size_t)b*64*64*64;
    k_patch4<<<dim3(4,416), 256, 0, stream>>>(k0b, k1b, q0b, q1b, Kp, Qp, Vt);
    k_emb2<<<360, 256, 0, stream>>>(Kp, Qp, Wkt, Wqt, bk, bq, Ke, Qe, St);
    k_pexp<<<dim3(10,8,5), 256, 0, stream>>>(Qe, Ke, P8, St);
    bf16* h1_0 = tierA ? (bf16*)(ws + oH1) + (size_t)b*16384*256
                       : (bf16*)(ws + oH1s);
    bf16* h1_1 = tierA ? (bf16*)(ws + oH1 + 33554432) + (size_t)b*4096*256
                       : (bf16*)(ws + oH1s + 8388608);
    k_wv<<<640, 256, 0, stream>>>(P8, Vt, C1w, c1b, St, h1_0, h1_1);
    if (!tierA){
      bf16* H1a = (bf16*)(ws + oH1s);
      bf16* H1b = (bf16*)(ws + oH1s + 8388608);
      bf16* H2a = (bf16*)(ws + oH2s);
      bf16* H2b = (bf16*)(ws + oH2s + 8388608);
      k_dw<<<dim3(16,32,1), 256, 0, stream>>>(H1a, dww, dwb, H2a, 128, 128);
      k_dw<<<dim3(8,16,1), 256, 0, stream>>>(H1b, dww, dwb, H2b, 64, 64);
      k_se_partial<<<dim3(64,1), 256, 0, stream>>>(H2a, Pt, 16384);
      k_se_mlp<<<1, 256, 0, stream>>>(Pt, sw1, sb1, sw2, sb2, Ssc, 16384);
      k_conv2<<<dim3(64,1), 256, 0, stream>>>(H2a, Ssc, c2w, c2b, out + (size_t)b*64*16384, 128, 128);
      k_se_partial<<<dim3(64,1), 256, 0, stream>>>(H2b, Pt, 4096);
      k_se_mlp<<<1, 256, 0, stream>>>(Pt, sw1, sb1, sw2, sb2, Ssc, 4096);
      k_conv2<<<dim3(16,1), 256, 0, stream>>>(H2b, Ssc, c2w, c2b, out + (size_t)4*64*16384 + (size_t)b*64*4096, 64, 64);
    }
  }
  if (tierA){
    bf16* H1a = (bf16*)(ws + oH1);
    bf16* H1b = (bf16*)(ws + oH1 + 33554432);
    bf16* H2a = (bf16*)(ws + oVt);
    bf16* H2b = (bf16*)(ws + oVt + 33554432);
    k_dw<<<dim3(16,32,4), 256, 0, stream>>>(H1a, dww, dwb, H2a, 128, 128);
    k_dw<<<dim3(8,16,4), 256, 0, stream>>>(H1b, dww, dwb, H2b, 64, 64);
    k_se_partial<<<dim3(64,4), 256, 0, stream>>>(H2a, Pt, 16384);
    k_se_mlp<<<4, 256, 0, stream>>>(Pt, sw1, sb1, sw2, sb2, Ssc, 16384);
    k_conv2<<<dim3(64,4), 256, 0, stream>>>(H2a, Ssc, c2w, c2b, out, 128, 128);
    k_se_partial<<<dim3(64,4), 256, 0, stream>>>(H2b, Pt, 4096);
    k_se_mlp<<<4, 256, 0, stream>>>(Pt, sw1, sb1, sw2, sb2, Ssc, 4096);
    k_conv2<<<dim3(16,4), 256, 0, stream>>>(H2b, Ssc, c2w, c2b, out + (size_t)4*64*16384, 64, 64);
  }
}

// Round 8
// 703.301 us; speedup vs baseline: 2.9377x; 1.0855x over previous
//
#include <hip/hip_runtime.h>
#include <hip/hip_bf16.h>

typedef __hip_bfloat16 bf16;
typedef short s8v __attribute__((ext_vector_type(8)));
typedef float f4v __attribute__((ext_vector_type(4)));

__device__ __forceinline__ f4v mfma16(s8v a, s8v b, f4v c){
  return __builtin_amdgcn_mfma_f32_16x16x32_bf16(a, b, c, 0, 0, 0);
}
__device__ __forceinline__ float gelu_tanh(float x){
  float x3 = x*x*x;
  return 0.5f*x*(1.0f + tanhf(0.7978845608028654f*(x + 0.044715f*x3)));
}

// ---------------- sentinel fill (encodes ws_size in MB * 16) ----------------
__global__ void k_fill(float* out, int n, float val){
  int i = blockIdx.x*256 + threadIdx.x;
  if (i < n) out[i] = val;
}

// ---------------- weight prep ----------------
__global__ __launch_bounds__(256) void k_prep(const float* __restrict__ Wk, const float* __restrict__ Wq,
                       const float* __restrict__ c1wf,
                       bf16* __restrict__ Wkt, bf16* __restrict__ Wqt, bf16* __restrict__ c1w){
  int tid = blockIdx.x*256 + threadIdx.x; // 98304 total
  if (tid < 32768){ int d = tid >> 7, j = tid & 127; Wkt[tid] = __float2bfloat16(Wk[j*256 + d]); }
  else if (tid < 65536){ int r = tid - 32768; int d = r >> 7, j = r & 127; Wqt[r] = __float2bfloat16(Wq[j*256 + d]); }
  else { int r = tid - 65536; c1w[r] = __float2bfloat16(c1wf[r]); }
}

// ---------------- fused patchify (one batch, all 4 tensors) ----------------
__global__ __launch_bounds__(256) void k_patch4(const float* __restrict__ k0, const float* __restrict__ k1,
                         const float* __restrict__ q0, const float* __restrict__ q1,
                         bf16* __restrict__ Kp, bf16* __restrict__ Qp, bf16* __restrict__ Vt){
  __shared__ float tile[64][33];
  int gy = blockIdx.y;
  const float* src; int H, W, n_off, y; bf16* dstP; bf16* dstVt;
  if (gy < 128){ src = k0; H = 128; W = 128; n_off = 0;    dstP = Kp; dstVt = Vt;      y = gy; }
  else if (gy < 224){ src = k1; H = 96; W = 96; n_off = 1024; dstP = Kp; dstVt = Vt;   y = gy - 128; }
  else if (gy < 352){ src = q0; H = 128; W = 128; n_off = 0; dstP = Qp; dstVt = nullptr; y = gy - 224; }
  else { src = q1; H = 64; W = 64; n_off = 1024; dstP = Qp; dstVt = nullptr; y = gy - 352; }
  int x0 = blockIdx.x*32;
  if (x0 >= W) return;
  int t = threadIdx.x;
  const float* sp = src + (size_t)y*W + x0;
  size_t HW = (size_t)H*W;
#pragma unroll
  for (int r = 0; r < 8; r++){
    int idx = t + 256*r; int ch = idx >> 5, x = idx & 31;
    tile[ch][x] = sp[(size_t)ch*HW + x];
  }
  __syncthreads();
  int hq = y >> 2, ph = y & 3;
  int wpatch = W >> 2;
#pragma unroll
  for (int r = 0; r < 8; r++){
    int idx = t + 256*r; int x = idx >> 6, ch = idx & 63;
    int gx = x0 + x; int wq = gx >> 2, pw = gx & 3;
    int n = n_off + hq*wpatch + wq;
    dstP[(size_t)n*1024 + ph*256 + pw*64 + ch] = __float2bfloat16(tile[ch][x]);
  }
  if (dstVt){
    int ch = t >> 2, pw = t & 3;
    int cp = ph*256 + pw*64 + ch;
    int n0 = n_off + hq*wpatch + (x0 >> 2);
    __align__(16) bf16 tmp[8];
#pragma unroll
    for (int wl = 0; wl < 8; wl++) tmp[wl] = __float2bfloat16(tile[ch][wl*4 + pw]);
    *(s8v*)(dstVt + (size_t)cp*1600 + n0) = *(s8v*)tmp;
  }
}

// ---------------- fused embedding GEMM (one batch, K+Q); also zeroes St ----------------
__global__ __launch_bounds__(256) void k_emb2(const bf16* __restrict__ Kp, const bf16* __restrict__ Qp,
                       const bf16* __restrict__ Wkt, const bf16* __restrict__ Wqt,
                       const float* __restrict__ bk, const float* __restrict__ bq,
                       bf16* __restrict__ Ke, bf16* __restrict__ Qe, float* __restrict__ St){
  if (blockIdx.x < 40) St[blockIdx.x*256 + threadIdx.x] = 0.f;
  int bx = blockIdx.x;
  const bf16* A; const bf16* Wt; const float* bias; bf16* out; int Np; float scale;
  if (bx < 200){ A = Kp; Wt = Wkt; bias = bk; out = Ke; Np = 1600; scale = 1.0f; }
  else { bx -= 200; A = Qp; Wt = Wqt; bias = bq; out = Qe; Np = 1280; scale = 0.17677669529663687f; }
  int t = threadIdx.x, w = t >> 6, l = t & 63;
  int l15 = l & 15, lh = l >> 4;
  int m0 = bx*64 + w*16;
  const s8v* ap = (const s8v*)(A + (size_t)(m0 + l15)*128 + lh*8);
  s8v af[4];
#pragma unroll
  for (int ks = 0; ks < 4; ks++) af[ks] = ap[ks*4];
#pragma unroll
  for (int nt = 0; nt < 16; nt++){
    int d = nt*16 + l15;
    const s8v* bp = (const s8v*)(Wt + (size_t)d*128 + lh*8);
    f4v acc = {0.f,0.f,0.f,0.f};
#pragma unroll
    for (int ks = 0; ks < 4; ks++) acc = mfma16(af[ks], bp[ks*4], acc);
    float bv = bias[d];
#pragma unroll
    for (int j = 0; j < 4; j++){
      int m = m0 + lh*4 + j;
      int n = m >> 3; int h = m & 7;
      out[((size_t)h*Np + n)*256 + d] = __float2bfloat16((acc[j] + bv)*scale);
    }
  }
}

// ---------------- fused logits -> exp (no max-sub) -> Pexp bf16 + row-sum atomics ----------------
// grid (qt=10, h=8, kc=5): block covers 128 q-rows x 320 keys (5 kt of 64); K-tile reg-prefetched
__global__ __launch_bounds__(256) void k_pexp(const bf16* __restrict__ Qe, const bf16* __restrict__ Ke,
                      bf16* __restrict__ P, float* __restrict__ St){
  __shared__ bf16 Ks[64][264];
  __shared__ bf16 Pw[4][32][134];
  int t = threadIdx.x, w = t >> 6, l = t & 63, l15 = l & 15, lh = l >> 4;
  int qt = blockIdx.x, h = blockIdx.y, kc = blockIdx.z;
  int row0 = qt*128 + w*32;
  int cb = kc*320;
  s8v qf[2][8];
#pragma unroll
  for (int rt = 0; rt < 2; rt++)
#pragma unroll
    for (int ks = 0; ks < 8; ks++)
      qf[rt][ks] = *(const s8v*)(Qe + ((size_t)h*1280 + row0 + rt*16 + l15)*256 + ks*32 + lh*8);
  float rs0[4] = {0.f,0.f,0.f,0.f}, rs1[4] = {0.f,0.f,0.f,0.f};
  int kr = t >> 2, kq = t & 3;
  size_t prow_base = (size_t)h*1280 + row0;
  // prefetch K-tile 0 into regs
  s8v kreg[8];
  {
    const bf16* s0 = Ke + ((size_t)h*1600 + kc*320 + kr)*256 + kq*64;
#pragma unroll
    for (int u = 0; u < 8; u++) kreg[u] = *(const s8v*)(s0 + u*8);
  }
  for (int i = 0; i < 5; i++){
    if (i) __syncthreads();
#pragma unroll
    for (int u = 0; u < 8; u++){
      int sw = (kq*8 + u) ^ (kr & 7);
      *(s8v*)&Ks[kr][sw*8] = kreg[u];
    }
    if (i < 4){
      const bf16* sn = Ke + ((size_t)h*1600 + kc*320 + (i+1)*64 + kr)*256 + kq*64;
#pragma unroll
      for (int u = 0; u < 8; u++) kreg[u] = *(const s8v*)(sn + u*8);
    }
    __syncthreads();
    f4v a0[4], a1[4];
#pragma unroll
    for (int ct = 0; ct < 4; ct++){ a0[ct] = (f4v){0.f,0.f,0.f,0.f}; a1[ct] = (f4v){0.f,0.f,0.f,0.f}; }
#pragma unroll
    for (int ct = 0; ct < 4; ct++){
      int krow = ct*16 + l15;
#pragma unroll
      for (int ks = 0; ks < 8; ks++){
        s8v bf = *(const s8v*)&Ks[krow][((ks*4 + lh) ^ (krow & 7))*8];
        a0[ct] = mfma16(qf[0][ks], bf, a0[ct]);
        a1[ct] = mfma16(qf[1][ks], bf, a1[ct]);
      }
    }
#pragma unroll
    for (int ct = 0; ct < 4; ct++){
      int local = (i*4 + ct) & 7;
#pragma unroll
      for (int j = 0; j < 4; j++){
        float e0 = __expf(a0[ct][j]); rs0[j] += e0;
        float e1 = __expf(a1[ct][j]); rs1[j] += e1;
        Pw[w][lh*4 + j][local*16 + l15]      = __float2bfloat16(e0);
        Pw[w][16 + lh*4 + j][local*16 + l15] = __float2bfloat16(e1);
      }
    }
    if (i & 1){
      int ci = i >> 1;
#pragma unroll
      for (int p = 0; p < 8; p++){
        int s = p*8 + (l >> 3);
        int row = s >> 1, half = s & 1;
        *(uint4*)(P + (prow_base + row)*1600 + cb + ci*128 + half*64 + (l & 7)*8) =
          *(uint4*)&Pw[w][row][half*64 + (l & 7)*8];
      }
    }
  }
  // tail: last 64 cols of this block's 320 (local tiles 0..3)
#pragma unroll
  for (int p = 0; p < 4; p++){
    int row = p*8 + (l >> 3);
    *(uint4*)(P + (prow_base + row)*1600 + cb + 256 + (l & 7)*8) =
      *(uint4*)&Pw[w][row][(l & 7)*8];
  }
  // row-sum partials -> atomic
#pragma unroll
  for (int j = 0; j < 4; j++){
    float s0 = rs0[j], s1 = rs1[j];
#pragma unroll
    for (int d = 1; d < 16; d <<= 1){ s0 += __shfl_xor(s0, d); s1 += __shfl_xor(s1, d); }
    if (l15 == 0){
      atomicAdd(&St[(size_t)h*1280 + row0 + lh*4 + j], s0);
      atomicAdd(&St[(size_t)h*1280 + row0 + 16 + lh*4 + j], s1);
    }
  }
}

// ---------------- wv GEMM (one batch) + deferred softmax-norm + fused conv1+GELU -> H1 ----------------
// grid 640 1D: bid = nt*80 + h*10 + mt; flat K loop kt=0..49 (BK=32; ksrc0: 0..31, ksrc1: 32..49)
// launch_bounds(256,3): <=170 VGPR, NO spill (r7's (256,4) forced 64MB of scratch spill traffic).
// load(kt+1) issued BEFORE MFMA(kt) so HBM/L2 latency hides under the MFMA phase.
__global__ __launch_bounds__(256, 3) void k_wv(const bf16* __restrict__ P, const bf16* __restrict__ Vt,
                     const bf16* __restrict__ c1w, const float* __restrict__ c1b,
                     const float* __restrict__ St,
                     bf16* __restrict__ h1_0, bf16* __restrict__ h1_1){
  __shared__ bf16 AB[16384];   // A[128][32] @0, B[128][32] @4096; union: Ot[256][64] over all 16384
  __shared__ bf16 W1s[4096];   // [32][128] swizzled (granule ^ (row&7))
  int bid = blockIdx.x;
  int nt = bid / 80;
  int r80 = bid - nt*80;
  int h = r80 / 10;
  int mt = r80 - h*10;
  int t = threadIdx.x, w = t >> 6, l = t & 63;
  int l15 = l & 15, lh = l >> 4;
  int wr = w >> 1, wc = w & 1;
  {
    int rr = t >> 3;
    int gp = (t & 7)*2;
    const bf16* src = c1w + ((size_t)h*32 + rr)*128;
    *(uint4*)&W1s[rr*128 + ((gp ^ (rr & 7))*8)]     = *(const uint4*)(src + gp*8);
    *(uint4*)&W1s[rr*128 + (((gp+1) ^ (rr & 7))*8)] = *(const uint4*)(src + (gp+1)*8);
  }
  const bf16* Ab = P + ((size_t)h*1280 + mt*128)*1600;
  const bf16* Bb = Vt + ((size_t)nt*128)*1600;
  int srow = t >> 1;           // staging row 0..127
  int sg0 = (t & 1)*2;         // staging granule pair {0,1} or {2,3}
  int ssw = (srow >> 1) & 3;   // swizzle key
  const bf16* gA = Ab + (size_t)srow*1600 + sg0*8;
  const bf16* gB = Bb + (size_t)srow*1600 + sg0*8;
  int da0 = srow*32 + ((sg0 ^ ssw)*8);
  int da1 = srow*32 + (((sg0+1) ^ ssw)*8);
  f4v acc2[4][2];
#pragma unroll
  for (int mm = 0; mm < 4; mm++)
#pragma unroll
    for (int nn = 0; nn < 2; nn++) acc2[mm][nn] = (f4v){0.f,0.f,0.f,0.f};
  f4v acc[4][4];
#pragma unroll
  for (int m = 0; m < 4; m++)
#pragma unroll
    for (int n = 0; n < 4; n++) acc[m][n] = (f4v){0.f,0.f,0.f,0.f};
  // prefetch kt=0 into regs
  s8v ta0 = *(const s8v*)(gA);
  s8v ta1 = *(const s8v*)(gA + 8);
  s8v tb0 = *(const s8v*)(gB);
  s8v tb1 = *(const s8v*)(gB + 8);
  for (int kt = 0; kt < 50; kt++){
    __syncthreads();   // prior MFMA phase's LDS reads complete
    *(s8v*)&AB[da0]        = ta0;
    *(s8v*)&AB[da1]        = ta1;
    *(s8v*)&AB[4096 + da0] = tb0;
    *(s8v*)&AB[4096 + da1] = tb1;
    __syncthreads();
    if (kt < 49){
      int kb2 = (kt + 1)*32;
      ta0 = *(const s8v*)(gA + kb2);
      ta1 = *(const s8v*)(gA + kb2 + 8);
      tb0 = *(const s8v*)(gB + kb2);
      tb1 = *(const s8v*)(gB + kb2 + 8);
    }
    s8v af[4], bfr[4];
#pragma unroll
    for (int m = 0; m < 4; m++){
      int row = wr*64 + m*16 + l15;
      af[m] = *(const s8v*)&AB[row*32 + ((lh ^ ((row >> 1) & 3))*8)];
    }
#pragma unroll
    for (int n = 0; n < 4; n++){
      int row = wc*64 + n*16 + l15;
      bfr[n] = *(const s8v*)&AB[4096 + row*32 + ((lh ^ ((row >> 1) & 3))*8)];
    }
#pragma unroll
    for (int m = 0; m < 4; m++)
#pragma unroll
      for (int n = 0; n < 4; n++) acc[m][n] = mfma16(af[m], bfr[n], acc[m][n]);
    if (kt == 31 || kt == 49){
      int ksrc = (kt == 49) ? 1 : 0;
      __syncthreads();
      // stage normalized O half-tile into AB union: Ot[256 pix][64 ch] swizzled
#pragma unroll
      for (int m = 0; m < 4; m++){
        int rl4 = wr*64 + m*16 + lh*4;
        float ivm[4];
#pragma unroll
        for (int j = 0; j < 4; j++)
          ivm[j] = 1.0f / St[(size_t)h*1280 + mt*128 + rl4 + j];
#pragma unroll
        for (int n = 0; n < 4; n++){
          int c = n*16 + l15;
#pragma unroll
          for (int j = 0; j < 4; j++){
            int p = (rl4 + j)*2 + wc;
            AB[p*64 + (((c >> 3) ^ (p & 7))*8) + (c & 7)] = __float2bfloat16(acc[m][n][j]*ivm[j]);
          }
        }
      }
      __syncthreads();
      // conv1 partial MFMA over this 64-ch half
#pragma unroll
      for (int ks2 = 0; ks2 < 2; ks2++){
        s8v afc[4], bfc[2];
#pragma unroll
        for (int mm = 0; mm < 4; mm++){
          int p2 = w*64 + mm*16 + l15;
          afc[mm] = *(const s8v*)&AB[p2*64 + (((ks2*4 + lh) ^ (p2 & 7))*8)];
        }
#pragma unroll
        for (int nn = 0; nn < 2; nn++){
          int rw = nn*16 + l15;
          int gg = ksrc*8 + ks2*4 + lh;
          bfc[nn] = *(const s8v*)&W1s[rw*128 + ((gg ^ (rw & 7))*8)];
        }
#pragma unroll
        for (int mm = 0; mm < 4; mm++)
#pragma unroll
          for (int nn = 0; nn < 2; nn++)
            acc2[mm][nn] = mfma16(afc[mm], bfc[nn], acc2[mm][nn]);
      }
      if (kt == 31){
#pragma unroll
        for (int m = 0; m < 4; m++)
#pragma unroll
          for (int n = 0; n < 4; n++) acc[m][n] = (f4v){0.f,0.f,0.f,0.f};
      }
    }
  }
  float bia[2];
#pragma unroll
  for (int nn = 0; nn < 2; nn++) bia[nn] = c1b[h*32 + nn*16 + l15];
#pragma unroll
  for (int mm = 0; mm < 4; mm++){
#pragma unroll
    for (int nn = 0; nn < 2; nn++){
#pragma unroll
      for (int j = 0; j < 4; j++){
        float v = gelu_tanh(acc2[mm][nn][j] + bia[nn]);
        int pixl = w*64 + mm*16 + lh*4 + j;
        int rl = pixl >> 1, wc2 = pixl & 1;
        int rq = mt*128 + rl;
        int cell = nt*2 + wc2; int ph = cell >> 2, pw = cell & 3;
        int o = h*32 + nn*16 + l15;
        if (rq < 1024){
          int y = ((rq >> 5) << 2) + ph, x = ((rq & 31) << 2) + pw;
          h1_0[((size_t)y*128 + x)*256 + o] = __float2bfloat16(v);
        } else {
          int r2 = rq - 1024;
          int y = ((r2 >> 4) << 2) + ph, x = ((r2 & 15) << 2) + pw;
          h1_1[((size_t)y*64 + x)*256 + o] = __float2bfloat16(v);
        }
      }
    }
  }
}

// ---------------- depthwise 3x3 + GELU, NHWC: 8x4 pixel tile per block, full unroll ----------------
__global__ __launch_bounds__(256) void k_dw(const bf16* __restrict__ h1, const float* __restrict__ wdw,
                     const float* __restrict__ bdw, bf16* __restrict__ h2, int H, int W){
  __shared__ float wl[2304];
  __shared__ float bl[256];
  int t = threadIdx.x;
  for (int i = t; i < 2304; i += 256) wl[i] = wdw[i];
  bl[t] = bdw[t];
  __syncthreads();
  int cg = t & 31, xo = t >> 5;
  int ch0 = cg*8;
  int x = blockIdx.x*8 + xo;
  int y0 = blockIdx.y*4;
  int b = blockIdx.z;
  const bf16* base = h1 + (size_t)b*H*W*256;
  bf16* obase = h2 + (size_t)b*H*W*256;
  s8v ld[6][3];
  const s8v zz = (s8v){0,0,0,0,0,0,0,0};
#pragma unroll
  for (int r = 0; r < 6; r++){
    int yy = y0 - 1 + r;
    bool vy = (yy >= 0) && (yy < H);
    int yc = vy ? yy : 0;
#pragma unroll
    for (int d = 0; d < 3; d++){
      int xx = x - 1 + d;
      bool vx = (xx >= 0) && (xx < W);
      int xc = vx ? xx : 0;
      s8v v = *(const s8v*)(base + ((size_t)yc*W + xc)*256 + ch0);
      ld[r][d] = (vy && vx) ? v : zz;
    }
  }
#pragma unroll
  for (int p = 0; p < 4; p++){
    float acc[8];
#pragma unroll
    for (int i = 0; i < 8; i++) acc[i] = bl[ch0 + i];
#pragma unroll
    for (int dy = 0; dy < 3; dy++){
#pragma unroll
      for (int d = 0; d < 3; d++){
        s8v v = ld[p + dy][d];
#pragma unroll
        for (int i = 0; i < 8; i++){
          acc[i] += __bfloat162float(((const bf16*)&v)[i]) * wl[(ch0 + i)*9 + dy*3 + d];
        }
      }
    }
    __align__(16) bf16 outv[8];
#pragma unroll
    for (int i = 0; i < 8; i++) outv[i] = __float2bfloat16(gelu_tanh(acc[i]));
    *(s8v*)(obase + ((size_t)(y0 + p)*W + x)*256 + ch0) = *(s8v*)outv;
  }
}

// ---------------- SE partial sums, grid (64, nb), vectorized ----------------
__global__ __launch_bounds__(256) void k_se_partial(const bf16* __restrict__ h2, float* __restrict__ partial, int HW){
  __shared__ float red[8][256];
  int chunk = blockIdx.x, b = blockIdx.y, t = threadIdx.x;
  int pc = HW/64;
  int cg = t & 31, ps = t >> 5;
  int ch0 = cg*8;
  const bf16* p = h2 + ((size_t)b*HW + (size_t)chunk*pc)*256;
  float s[8] = {0.f,0.f,0.f,0.f,0.f,0.f,0.f,0.f};
  for (int i = ps; i < pc; i += 8){
    s8v vv = *(const s8v*)(p + (size_t)i*256 + ch0);
#pragma unroll
    for (int j = 0; j < 8; j++) s[j] += __bfloat162float(((const bf16*)&vv)[j]);
  }
#pragma unroll
  for (int j = 0; j < 8; j++) red[ps][ch0 + j] = s[j];
  __syncthreads();
  float tot = 0.f;
#pragma unroll
  for (int r = 0; r < 8; r++) tot += red[r][t];
  partial[((size_t)b*64 + chunk)*256 + t] = tot;
}

// ---------------- SE MLP, grid (nb) ----------------
__global__ __launch_bounds__(256) void k_se_mlp(const float* __restrict__ partial, const float* __restrict__ w1,
                         const float* __restrict__ b1, const float* __restrict__ w2, const float* __restrict__ b2,
                         float* __restrict__ sca, int HW){
  __shared__ float mean[256];
  __shared__ float s1[64];
  int b = blockIdx.x, t = threadIdx.x;
  float s = 0.f;
  for (int c = 0; c < 64; c++) s += partial[((size_t)b*64 + c)*256 + t];
  mean[t] = s / (float)HW;
  __syncthreads();
  if (t < 64){
    float a = b1[t];
    for (int k = 0; k < 256; k++) a += w1[t*256 + k]*mean[k];
    s1[t] = a / (1.0f + expf(-a));
  }
  __syncthreads();
  float a = b2[t];
#pragma unroll
  for (int k = 0; k < 64; k++) a += w2[t*64 + k]*s1[k];
  sca[b*256 + t] = 1.0f/(1.0f + expf(-a));
}

// ---------------- SE scale + conv2 -> NCHW f32, grid (HW/256, nb) ----------------
__global__ __launch_bounds__(256) void k_conv2(const bf16* __restrict__ h2, const float* __restrict__ sca,
                        const float* __restrict__ w2c, const float* __restrict__ b2c,
                        float* __restrict__ out, int H, int W){
  __shared__ float wsm[64][32];
  __shared__ float scs[256];
  int t = threadIdx.x, b = blockIdx.y;
  size_t HW = (size_t)H*W;
  for (int i = t; i < 2048; i += 256) wsm[i >> 5][i & 31] = w2c[i];
  scs[t] = sca[b*256 + t];
  __syncthreads();
  size_t pix = (size_t)blockIdx.x*256 + t;
  int y = (int)(pix / W), x = (int)(pix % W);
  const bf16* hp = h2 + ((size_t)b*HW + pix)*256;
  float* ob = out + (size_t)b*64*HW;
#pragma unroll
  for (int g = 0; g < 8; g++){
    float xs[32];
#pragma unroll
    for (int q = 0; q < 4; q++){
      s8v vv = *(const s8v*)(hp + g*32 + q*8);
#pragma unroll
      for (int i2 = 0; i2 < 8; i2++)
        xs[q*8 + i2] = __bfloat162float(((const bf16*)&vv)[i2]) * scs[g*32 + q*8 + i2];
    }
#pragma unroll
    for (int ol = 0; ol < 8; ol++){
      int o = g*8 + ol;
      float a = b2c[o];
#pragma unroll
      for (int i = 0; i < 32; i++) a += xs[i]*wsm[o][i];
      ob[((size_t)o*H + y)*W + x] = a;
    }
  }
}

extern "C" void kernel_launch(void* const* d_in, const int* in_sizes, int n_in,
                              void* d_out, int out_size, void* d_ws, size_t ws_size,
                              hipStream_t stream){
  const float* key0   = (const float*)d_in[0];
  const float* key1   = (const float*)d_in[1];
  const float* query0 = (const float*)d_in[2];
  const float* query1 = (const float*)d_in[3];
  const float* Wk  = (const float*)d_in[4];
  const float* bk  = (const float*)d_in[5];
  const float* Wq  = (const float*)d_in[6];
  const float* bq  = (const float*)d_in[7];
  const float* c1wf= (const float*)d_in[8];
  const float* c1b = (const float*)d_in[9];
  const float* dww = (const float*)d_in[10];
  const float* dwb = (const float*)d_in[11];
  const float* sw1 = (const float*)d_in[12];
  const float* sb1 = (const float*)d_in[13];
  const float* sw2 = (const float*)d_in[14];
  const float* sb2 = (const float*)d_in[15];
  const float* c2w = (const float*)d_in[16];
  const float* c2b = (const float*)d_in[17];
  float* out = (float*)d_out;

  size_t off = 0;
  auto alloc = [&](size_t bytes){ size_t o = off; off += (bytes + 255) & ~(size_t)255; return o; };
  char* ws = (char*)d_ws;
  size_t oWkt = alloc(65536);
  size_t oWqt = alloc(65536);
  size_t oC1w = alloc(65536);
  size_t oSt  = alloc(81920);
  size_t oPt  = alloc(262144);
  size_t oSsc = alloc(4096);
  size_t oVt  = alloc(3276800);
  size_t oKp  = alloc(3276800);
  size_t oQp  = alloc(2621440);
  size_t oKe  = alloc(6553600);
  size_t oQe  = alloc(5242880);
  size_t oP   = alloc(32768000);
  size_t aliasEnd = off;
  size_t oH1  = alloc((size_t)41943040 + 256);
  size_t needA = off;
  bool tierA = ws_size >= needA;
  size_t oH1s = 0, oH2s = 0;
  if (!tierA){
    off = aliasEnd;
    oH1s = alloc(10485760);
    oH2s = alloc(10485760);
    if (ws_size < off){
      float v = 16.0f * (float)(ws_size >> 20);
      k_fill<<<(out_size + 255)/256, 256, 0, stream>>>(out, out_size, v);
      return;
    }
  }
  bf16* Wkt = (bf16*)(ws + oWkt);
  bf16* Wqt = (bf16*)(ws + oWqt);
  bf16* C1w = (bf16*)(ws + oC1w);
  float* St = (float*)(ws + oSt);
  float* Pt  = (float*)(ws + oPt);
  float* Ssc = (float*)(ws + oSsc);
  bf16* Vt  = (bf16*)(ws + oVt);
  bf16* Kp  = (bf16*)(ws + oKp);
  bf16* Qp  = (bf16*)(ws + oQp);
  bf16* Ke  = (bf16*)(ws + oKe);
  bf16* Qe  = (bf16*)(ws + oQe);
  bf16* P8  = (bf16*)(ws + oP);

  k_prep<<<384, 256, 0, stream>>>(Wk, Wq, c1wf, Wkt, Wqt, C1w);

  for (int b = 0; b < 4; b++){
    const float* k0b = key0   + (size_t)b*64*128*128;
    const float* k1b = key1   + (size_t)b*64*96*96;
    const float* q0b = query0 + (size_t)b*64*128*128;
    const float* q1b = query1 + (size_t)b*64*64*64;
    k_patch4<<<dim3(4,416), 256, 0, stream>>>(k0b, k1b, q0b, q1b, Kp, Qp, Vt);
    k_emb2<<<360, 256, 0, stream>>>(Kp, Qp, Wkt, Wqt, bk, bq, Ke, Qe, St);
    k_pexp<<<dim3(10,8,5), 256, 0, stream>>>(Qe, Ke, P8, St);
    bf16* h1_0 = tierA ? (bf16*)(ws + oH1) + (size_t)b*16384*256
                       : (bf16*)(ws + oH1s);
    bf16* h1_1 = tierA ? (bf16*)(ws + oH1 + 33554432) + (size_t)b*4096*256
                       : (bf16*)(ws + oH1s + 8388608);
    k_wv<<<640, 256, 0, stream>>>(P8, Vt, C1w, c1b, St, h1_0, h1_1);
    if (!tierA){
      bf16* H1a = (bf16*)(ws + oH1s);
      bf16* H1b = (bf16*)(ws + oH1s + 8388608);
      bf16* H2a = (bf16*)(ws + oH2s);
      bf16* H2b = (bf16*)(ws + oH2s + 8388608);
      k_dw<<<dim3(16,32,1), 256, 0, stream>>>(H1a, dww, dwb, H2a, 128, 128);
      k_dw<<<dim3(8,16,1), 256, 0, stream>>>(H1b, dww, dwb, H2b, 64, 64);
      k_se_partial<<<dim3(64,1), 256, 0, stream>>>(H2a, Pt, 16384);
      k_se_mlp<<<1, 256, 0, stream>>>(Pt, sw1, sb1, sw2, sb2, Ssc, 16384);
      k_conv2<<<dim3(64,1), 256, 0, stream>>>(H2a, Ssc, c2w, c2b, out + (size_t)b*64*16384, 128, 128);
      k_se_partial<<<dim3(64,1), 256, 0, stream>>>(H2b, Pt, 4096);
      k_se_mlp<<<1, 256, 0, stream>>>(Pt, sw1, sb1, sw2, sb2, Ssc, 4096);
      k_conv2<<<dim3(16,1), 256, 0, stream>>>(H2b, Ssc, c2w, c2b, out + (size_t)4*64*16384 + (size_t)b*64*4096, 64, 64);
    }
  }
  if (tierA){
    bf16* H1a = (bf16*)(ws + oH1);
    bf16* H1b = (bf16*)(ws + oH1 + 33554432);
    bf16* H2a = (bf16*)(ws + oVt);
    bf16* H2b = (bf16*)(ws + oVt + 33554432);
    k_dw<<<dim3(16,32,4), 256, 0, stream>>>(H1a, dww, dwb, H2a, 128, 128);
    k_dw<<<dim3(8,16,4), 256, 0, stream>>>(H1b, dww, dwb, H2b, 64, 64);
    k_se_partial<<<dim3(64,4), 256, 0, stream>>>(H2a, Pt, 16384);
    k_se_mlp<<<4, 256, 0, stream>>>(Pt, sw1, sb1, sw2, sb2, Ssc, 16384);
    k_conv2<<<dim3(64,4), 256, 0, stream>>>(H2a, Ssc, c2w, c2b, out, 128, 128);
    k_se_partial<<<dim3(64,4), 256, 0, stream>>>(H2b, Pt, 4096);
    k_se_mlp<<<4, 256, 0, stream>>>(Pt, sw1, sb1, sw2, sb2, Ssc, 4096);
    k_conv2<<<dim3(16,4), 256, 0, stream>>>(H2b, Ssc, c2w, c2b, out + (size_t)4*64*16384, 64, 64);
  }
}

// Round 9
// 654.600 us; speedup vs baseline: 3.1563x; 1.0744x over previous
//
#include <hip/hip_runtime.h>
#include <hip/hip_bf16.h>

typedef __hip_bfloat16 bf16;
typedef short s8v __attribute__((ext_vector_type(8)));
typedef float f4v __attribute__((ext_vector_type(4)));

__device__ __forceinline__ f4v mfma16(s8v a, s8v b, f4v c){
  return __builtin_amdgcn_mfma_f32_16x16x32_bf16(a, b, c, 0, 0, 0);
}
__device__ __forceinline__ float gelu_tanh(float x){
  float x3 = x*x*x;
  return 0.5f*x*(1.0f + tanhf(0.7978845608028654f*(x + 0.044715f*x3)));
}

// ---------------- sentinel fill (encodes ws_size in MB * 16) ----------------
__global__ void k_fill(float* out, int n, float val){
  int i = blockIdx.x*256 + threadIdx.x;
  if (i < n) out[i] = val;
}

// ---------------- weight prep ----------------
__global__ __launch_bounds__(256) void k_prep(const float* __restrict__ Wk, const float* __restrict__ Wq,
                       const float* __restrict__ c1wf,
                       bf16* __restrict__ Wkt, bf16* __restrict__ Wqt, bf16* __restrict__ c1w){
  int tid = blockIdx.x*256 + threadIdx.x; // 98304 total
  if (tid < 32768){ int d = tid >> 7, j = tid & 127; Wkt[tid] = __float2bfloat16(Wk[j*256 + d]); }
  else if (tid < 65536){ int r = tid - 32768; int d = r >> 7, j = r & 127; Wqt[r] = __float2bfloat16(Wq[j*256 + d]); }
  else { int r = tid - 65536; c1w[r] = __float2bfloat16(c1wf[r]); }
}

// ---------------- fused patchify (one batch, all 4 tensors) ----------------
__global__ __launch_bounds__(256) void k_patch4(const float* __restrict__ k0, const float* __restrict__ k1,
                         const float* __restrict__ q0, const float* __restrict__ q1,
                         bf16* __restrict__ Kp, bf16* __restrict__ Qp, bf16* __restrict__ Vt){
  __shared__ float tile[64][33];
  int gy = blockIdx.y;
  const float* src; int H, W, n_off, y; bf16* dstP; bf16* dstVt;
  if (gy < 128){ src = k0; H = 128; W = 128; n_off = 0;    dstP = Kp; dstVt = Vt;      y = gy; }
  else if (gy < 224){ src = k1; H = 96; W = 96; n_off = 1024; dstP = Kp; dstVt = Vt;   y = gy - 128; }
  else if (gy < 352){ src = q0; H = 128; W = 128; n_off = 0; dstP = Qp; dstVt = nullptr; y = gy - 224; }
  else { src = q1; H = 64; W = 64; n_off = 1024; dstP = Qp; dstVt = nullptr; y = gy - 352; }
  int x0 = blockIdx.x*32;
  if (x0 >= W) return;
  int t = threadIdx.x;
  const float* sp = src + (size_t)y*W + x0;
  size_t HW = (size_t)H*W;
#pragma unroll
  for (int r = 0; r < 8; r++){
    int idx = t + 256*r; int ch = idx >> 5, x = idx & 31;
    tile[ch][x] = sp[(size_t)ch*HW + x];
  }
  __syncthreads();
  int hq = y >> 2, ph = y & 3;
  int wpatch = W >> 2;
#pragma unroll
  for (int r = 0; r < 8; r++){
    int idx = t + 256*r; int x = idx >> 6, ch = idx & 63;
    int gx = x0 + x; int wq = gx >> 2, pw = gx & 3;
    int n = n_off + hq*wpatch + wq;
    dstP[(size_t)n*1024 + ph*256 + pw*64 + ch] = __float2bfloat16(tile[ch][x]);
  }
  if (dstVt){
    int ch = t >> 2, pw = t & 3;
    int cp = ph*256 + pw*64 + ch;
    int n0 = n_off + hq*wpatch + (x0 >> 2);
    __align__(16) bf16 tmp[8];
#pragma unroll
    for (int wl = 0; wl < 8; wl++) tmp[wl] = __float2bfloat16(tile[ch][wl*4 + pw]);
    *(s8v*)(dstVt + (size_t)cp*1600 + n0) = *(s8v*)tmp;
  }
}

// ---------------- fused embedding GEMM (one batch, K+Q); also zeroes St ----------------
__global__ __launch_bounds__(256) void k_emb2(const bf16* __restrict__ Kp, const bf16* __restrict__ Qp,
                       const bf16* __restrict__ Wkt, const bf16* __restrict__ Wqt,
                       const float* __restrict__ bk, const float* __restrict__ bq,
                       bf16* __restrict__ Ke, bf16* __restrict__ Qe, float* __restrict__ St){
  if (blockIdx.x < 40) St[blockIdx.x*256 + threadIdx.x] = 0.f;
  int bx = blockIdx.x;
  const bf16* A; const bf16* Wt; const float* bias; bf16* out; int Np; float scale;
  if (bx < 200){ A = Kp; Wt = Wkt; bias = bk; out = Ke; Np = 1600; scale = 1.0f; }
  else { bx -= 200; A = Qp; Wt = Wqt; bias = bq; out = Qe; Np = 1280; scale = 0.17677669529663687f; }
  int t = threadIdx.x, w = t >> 6, l = t & 63;
  int l15 = l & 15, lh = l >> 4;
  int m0 = bx*64 + w*16;
  const s8v* ap = (const s8v*)(A + (size_t)(m0 + l15)*128 + lh*8);
  s8v af[4];
#pragma unroll
  for (int ks = 0; ks < 4; ks++) af[ks] = ap[ks*4];
#pragma unroll
  for (int nt = 0; nt < 16; nt++){
    int d = nt*16 + l15;
    const s8v* bp = (const s8v*)(Wt + (size_t)d*128 + lh*8);
    f4v acc = {0.f,0.f,0.f,0.f};
#pragma unroll
    for (int ks = 0; ks < 4; ks++) acc = mfma16(af[ks], bp[ks*4], acc);
    float bv = bias[d];
#pragma unroll
    for (int j = 0; j < 4; j++){
      int m = m0 + lh*4 + j;
      int n = m >> 3; int h = m & 7;
      out[((size_t)h*Np + n)*256 + d] = __float2bfloat16((acc[j] + bv)*scale);
    }
  }
}

// ---------------- fused logits -> exp (no max-sub) -> Pexp bf16 + row-sum atomics ----------------
// grid (qt=10, h=8, kc=5): block covers 128 q-rows x 320 keys (5 kt of 64); K-tile reg-prefetched
__global__ __launch_bounds__(256) void k_pexp(const bf16* __restrict__ Qe, const bf16* __restrict__ Ke,
                      bf16* __restrict__ P, float* __restrict__ St){
  __shared__ bf16 Ks[64][264];
  __shared__ bf16 Pw[4][32][134];
  int t = threadIdx.x, w = t >> 6, l = t & 63, l15 = l & 15, lh = l >> 4;
  int qt = blockIdx.x, h = blockIdx.y, kc = blockIdx.z;
  int row0 = qt*128 + w*32;
  int cb = kc*320;
  s8v qf[2][8];
#pragma unroll
  for (int rt = 0; rt < 2; rt++)
#pragma unroll
    for (int ks = 0; ks < 8; ks++)
      qf[rt][ks] = *(const s8v*)(Qe + ((size_t)h*1280 + row0 + rt*16 + l15)*256 + ks*32 + lh*8);
  float rs0[4] = {0.f,0.f,0.f,0.f}, rs1[4] = {0.f,0.f,0.f,0.f};
  int kr = t >> 2, kq = t & 3;
  size_t prow_base = (size_t)h*1280 + row0;
  // prefetch K-tile 0 into regs
  s8v kreg[8];
  {
    const bf16* s0 = Ke + ((size_t)h*1600 + kc*320 + kr)*256 + kq*64;
#pragma unroll
    for (int u = 0; u < 8; u++) kreg[u] = *(const s8v*)(s0 + u*8);
  }
  for (int i = 0; i < 5; i++){
    if (i) __syncthreads();
#pragma unroll
    for (int u = 0; u < 8; u++){
      int sw = (kq*8 + u) ^ (kr & 7);
      *(s8v*)&Ks[kr][sw*8] = kreg[u];
    }
    if (i < 4){
      const bf16* sn = Ke + ((size_t)h*1600 + kc*320 + (i+1)*64 + kr)*256 + kq*64;
#pragma unroll
      for (int u = 0; u < 8; u++) kreg[u] = *(const s8v*)(sn + u*8);
    }
    __syncthreads();
    f4v a0[4], a1[4];
#pragma unroll
    for (int ct = 0; ct < 4; ct++){ a0[ct] = (f4v){0.f,0.f,0.f,0.f}; a1[ct] = (f4v){0.f,0.f,0.f,0.f}; }
#pragma unroll
    for (int ct = 0; ct < 4; ct++){
      int krow = ct*16 + l15;
#pragma unroll
      for (int ks = 0; ks < 8; ks++){
        s8v bf = *(const s8v*)&Ks[krow][((ks*4 + lh) ^ (krow & 7))*8];
        a0[ct] = mfma16(qf[0][ks], bf, a0[ct]);
        a1[ct] = mfma16(qf[1][ks], bf, a1[ct]);
      }
    }
#pragma unroll
    for (int ct = 0; ct < 4; ct++){
      int local = (i*4 + ct) & 7;
#pragma unroll
      for (int j = 0; j < 4; j++){
        float e0 = __expf(a0[ct][j]); rs0[j] += e0;
        float e1 = __expf(a1[ct][j]); rs1[j] += e1;
        Pw[w][lh*4 + j][local*16 + l15]      = __float2bfloat16(e0);
        Pw[w][16 + lh*4 + j][local*16 + l15] = __float2bfloat16(e1);
      }
    }
    if (i & 1){
      int ci = i >> 1;
#pragma unroll
      for (int p = 0; p < 8; p++){
        int s = p*8 + (l >> 3);
        int row = s >> 1, half = s & 1;
        *(uint4*)(P + (prow_base + row)*1600 + cb + ci*128 + half*64 + (l & 7)*8) =
          *(uint4*)&Pw[w][row][half*64 + (l & 7)*8];
      }
    }
  }
  // tail: last 64 cols of this block's 320 (local tiles 0..3)
#pragma unroll
  for (int p = 0; p < 4; p++){
    int row = p*8 + (l >> 3);
    *(uint4*)(P + (prow_base + row)*1600 + cb + 256 + (l & 7)*8) =
      *(uint4*)&Pw[w][row][(l & 7)*8];
  }
  // row-sum partials -> atomic
#pragma unroll
  for (int j = 0; j < 4; j++){
    float s0 = rs0[j], s1 = rs1[j];
#pragma unroll
    for (int d = 1; d < 16; d <<= 1){ s0 += __shfl_xor(s0, d); s1 += __shfl_xor(s1, d); }
    if (l15 == 0){
      atomicAdd(&St[(size_t)h*1280 + row0 + lh*4 + j], s0);
      atomicAdd(&St[(size_t)h*1280 + row0 + 16 + lh*4 + j], s1);
    }
  }
}

// ---------------- wv GEMM (one batch) + deferred softmax-norm + fused conv1+GELU -> H1 ----------------
// grid 1280 1D: h = bid&7 (XCD-pinned head), nt = (bid>>3)&15, mt = bid>>7.
// Per-XCD: 16 consecutive nt-blocks share one P A-tile (L2-resident, fetched once).
// Block tile 128x64, wave 64x32: acc[4][2]=32 VGPR + acc2[2][2]=16 -> no spill at (256,3).
__global__ __launch_bounds__(256, 3) void k_wv(const bf16* __restrict__ P, const bf16* __restrict__ Vt,
                     const bf16* __restrict__ c1w, const float* __restrict__ c1b,
                     const float* __restrict__ St,
                     bf16* __restrict__ h1_0, bf16* __restrict__ h1_1){
  __shared__ bf16 AB[8192];    // A[128][32] @0, B[64][32] @4096; union: Ot[128][64]
  __shared__ bf16 W1s[4096];   // [32][128] swizzled (granule ^ (row&7))
  int bid = blockIdx.x;
  int h  = bid & 7;
  int nt = (bid >> 3) & 15;
  int mt = bid >> 7;
  int t = threadIdx.x, w = t >> 6, l = t & 63;
  int l15 = l & 15, lh = l >> 4;
  int wr = w >> 1, wc = w & 1;
  {
    int rr = t >> 3;
    int gp = (t & 7)*2;
    const bf16* src = c1w + ((size_t)h*32 + rr)*128;
    *(uint4*)&W1s[rr*128 + ((gp ^ (rr & 7))*8)]     = *(const uint4*)(src + gp*8);
    *(uint4*)&W1s[rr*128 + (((gp+1) ^ (rr & 7))*8)] = *(const uint4*)(src + (gp+1)*8);
  }
  const bf16* Ab = P + ((size_t)h*1280 + mt*128)*1600;
  const bf16* Bb = Vt + ((size_t)nt*64)*1600;
  // A staging: 2 granules/thread (128 rows x 4 granules)
  int srowA = t >> 1;
  int sgA = (t & 1)*2;
  int swzA = (srowA >> 1) & 3;
  const bf16* gA = Ab + (size_t)srowA*1600 + sgA*8;
  int da0 = srowA*32 + ((sgA ^ swzA)*8);
  int da1 = srowA*32 + (((sgA+1) ^ swzA)*8);
  // B staging: 1 granule/thread (64 rows x 4 granules)
  int srowB = t >> 2;
  int sgB = t & 3;
  int swzB = (srowB >> 1) & 3;
  const bf16* gB = Bb + (size_t)srowB*1600 + sgB*8;
  int db = 4096 + srowB*32 + ((sgB ^ swzB)*8);
  f4v acc2[2][2];
#pragma unroll
  for (int mm = 0; mm < 2; mm++)
#pragma unroll
    for (int nn = 0; nn < 2; nn++) acc2[mm][nn] = (f4v){0.f,0.f,0.f,0.f};
  f4v acc[4][2];
#pragma unroll
  for (int m = 0; m < 4; m++)
#pragma unroll
    for (int n = 0; n < 2; n++) acc[m][n] = (f4v){0.f,0.f,0.f,0.f};
  // prefetch kt=0 into regs
  s8v ta0 = *(const s8v*)(gA);
  s8v ta1 = *(const s8v*)(gA + 8);
  s8v tb  = *(const s8v*)(gB);
  for (int kt = 0; kt < 50; kt++){
    __syncthreads();   // prior phase's LDS reads complete
    *(s8v*)&AB[da0] = ta0;
    *(s8v*)&AB[da1] = ta1;
    *(s8v*)&AB[db]  = tb;
    __syncthreads();
    if (kt < 49){
      int kb2 = (kt + 1)*32;
      ta0 = *(const s8v*)(gA + kb2);
      ta1 = *(const s8v*)(gA + kb2 + 8);
      tb  = *(const s8v*)(gB + kb2);
    }
    s8v af[4], bfr[2];
#pragma unroll
    for (int m = 0; m < 4; m++){
      int row = wr*64 + m*16 + l15;
      af[m] = *(const s8v*)&AB[row*32 + ((lh ^ ((row >> 1) & 3))*8)];
    }
#pragma unroll
    for (int n = 0; n < 2; n++){
      int row = wc*32 + n*16 + l15;
      bfr[n] = *(const s8v*)&AB[4096 + row*32 + ((lh ^ ((row >> 1) & 3))*8)];
    }
#pragma unroll
    for (int m = 0; m < 4; m++)
#pragma unroll
      for (int n = 0; n < 2; n++) acc[m][n] = mfma16(af[m], bfr[n], acc[m][n]);
    if (kt == 31 || kt == 49){
      int ksrc = (kt == 49) ? 1 : 0;
      __syncthreads();
      // stage normalized O half-tile into AB union: Ot[128 pix][64 ch] swizzled
#pragma unroll
      for (int m = 0; m < 4; m++){
        int rl4 = wr*64 + m*16 + lh*4;
        float ivm[4];
#pragma unroll
        for (int j = 0; j < 4; j++)
          ivm[j] = 1.0f / St[(size_t)h*1280 + mt*128 + rl4 + j];
#pragma unroll
        for (int n = 0; n < 2; n++){
          int c = wc*32 + n*16 + l15;
#pragma unroll
          for (int j = 0; j < 4; j++){
            int p = rl4 + j;
            AB[p*64 + (((c >> 3) ^ (p & 7))*8) + (c & 7)] = __float2bfloat16(acc[m][n][j]*ivm[j]);
          }
        }
      }
      __syncthreads();
      // conv1 partial MFMA over this 64-ch half
#pragma unroll
      for (int ks2 = 0; ks2 < 2; ks2++){
        s8v afc[2], bfc[2];
#pragma unroll
        for (int mm = 0; mm < 2; mm++){
          int p2 = w*32 + mm*16 + l15;
          afc[mm] = *(const s8v*)&AB[p2*64 + (((ks2*4 + lh) ^ (p2 & 7))*8)];
        }
#pragma unroll
        for (int nn = 0; nn < 2; nn++){
          int rw = nn*16 + l15;
          int gg = ksrc*8 + ks2*4 + lh;
          bfc[nn] = *(const s8v*)&W1s[rw*128 + ((gg ^ (rw & 7))*8)];
        }
#pragma unroll
        for (int mm = 0; mm < 2; mm++)
#pragma unroll
          for (int nn = 0; nn < 2; nn++)
            acc2[mm][nn] = mfma16(afc[mm], bfc[nn], acc2[mm][nn]);
      }
      if (kt == 31){
#pragma unroll
        for (int m = 0; m < 4; m++)
#pragma unroll
          for (int n = 0; n < 2; n++) acc[m][n] = (f4v){0.f,0.f,0.f,0.f};
      }
    }
  }
  float bia[2];
#pragma unroll
  for (int nn = 0; nn < 2; nn++) bia[nn] = c1b[h*32 + nn*16 + l15];
  int ph = nt >> 2, pw = nt & 3;
#pragma unroll
  for (int mm = 0; mm < 2; mm++){
#pragma unroll
    for (int nn = 0; nn < 2; nn++){
#pragma unroll
      for (int j = 0; j < 4; j++){
        float v = gelu_tanh(acc2[mm][nn][j] + bia[nn]);
        int pixl = w*32 + mm*16 + lh*4 + j;
        int rq = mt*128 + pixl;
        int o = h*32 + nn*16 + l15;
        if (rq < 1024){
          int y = ((rq >> 5) << 2) + ph, x = ((rq & 31) << 2) + pw;
          h1_0[((size_t)y*128 + x)*256 + o] = __float2bfloat16(v);
        } else {
          int r2 = rq - 1024;
          int y = ((r2 >> 4) << 2) + ph, x = ((r2 & 15) << 2) + pw;
          h1_1[((size_t)y*64 + x)*256 + o] = __float2bfloat16(v);
        }
      }
    }
  }
}

// ---------------- depthwise 3x3 + GELU, NHWC: 8x4 pixel tile per block, full unroll ----------------
__global__ __launch_bounds__(256) void k_dw(const bf16* __restrict__ h1, const float* __restrict__ wdw,
                     const float* __restrict__ bdw, bf16* __restrict__ h2, int H, int W){
  __shared__ float wl[2304];
  __shared__ float bl[256];
  int t = threadIdx.x;
  for (int i = t; i < 2304; i += 256) wl[i] = wdw[i];
  bl[t] = bdw[t];
  __syncthreads();
  int cg = t & 31, xo = t >> 5;
  int ch0 = cg*8;
  int x = blockIdx.x*8 + xo;
  int y0 = blockIdx.y*4;
  int b = blockIdx.z;
  const bf16* base = h1 + (size_t)b*H*W*256;
  bf16* obase = h2 + (size_t)b*H*W*256;
  s8v ld[6][3];
  const s8v zz = (s8v){0,0,0,0,0,0,0,0};
#pragma unroll
  for (int r = 0; r < 6; r++){
    int yy = y0 - 1 + r;
    bool vy = (yy >= 0) && (yy < H);
    int yc = vy ? yy : 0;
#pragma unroll
    for (int d = 0; d < 3; d++){
      int xx = x - 1 + d;
      bool vx = (xx >= 0) && (xx < W);
      int xc = vx ? xx : 0;
      s8v v = *(const s8v*)(base + ((size_t)yc*W + xc)*256 + ch0);
      ld[r][d] = (vy && vx) ? v : zz;
    }
  }
#pragma unroll
  for (int p = 0; p < 4; p++){
    float acc[8];
#pragma unroll
    for (int i = 0; i < 8; i++) acc[i] = bl[ch0 + i];
#pragma unroll
    for (int dy = 0; dy < 3; dy++){
#pragma unroll
      for (int d = 0; d < 3; d++){
        s8v v = ld[p + dy][d];
#pragma unroll
        for (int i = 0; i < 8; i++){
          acc[i] += __bfloat162float(((const bf16*)&v)[i]) * wl[(ch0 + i)*9 + dy*3 + d];
        }
      }
    }
    __align__(16) bf16 outv[8];
#pragma unroll
    for (int i = 0; i < 8; i++) outv[i] = __float2bfloat16(gelu_tanh(acc[i]));
    *(s8v*)(obase + ((size_t)(y0 + p)*W + x)*256 + ch0) = *(s8v*)outv;
  }
}

// ---------------- SE partial sums, grid (64, nb), vectorized ----------------
__global__ __launch_bounds__(256) void k_se_partial(const bf16* __restrict__ h2, float* __restrict__ partial, int HW){
  __shared__ float red[8][256];
  int chunk = blockIdx.x, b = blockIdx.y, t = threadIdx.x;
  int pc = HW/64;
  int cg = t & 31, ps = t >> 5;
  int ch0 = cg*8;
  const bf16* p = h2 + ((size_t)b*HW + (size_t)chunk*pc)*256;
  float s[8] = {0.f,0.f,0.f,0.f,0.f,0.f,0.f,0.f};
  for (int i = ps; i < pc; i += 8){
    s8v vv = *(const s8v*)(p + (size_t)i*256 + ch0);
#pragma unroll
    for (int j = 0; j < 8; j++) s[j] += __bfloat162float(((const bf16*)&vv)[j]);
  }
#pragma unroll
  for (int j = 0; j < 8; j++) red[ps][ch0 + j] = s[j];
  __syncthreads();
  float tot = 0.f;
#pragma unroll
  for (int r = 0; r < 8; r++) tot += red[r][t];
  partial[((size_t)b*64 + chunk)*256 + t] = tot;
}

// ---------------- SE MLP, grid (nb) ----------------
__global__ __launch_bounds__(256) void k_se_mlp(const float* __restrict__ partial, const float* __restrict__ w1,
                         const float* __restrict__ b1, const float* __restrict__ w2, const float* __restrict__ b2,
                         float* __restrict__ sca, int HW){
  __shared__ float mean[256];
  __shared__ float s1[64];
  int b = blockIdx.x, t = threadIdx.x;
  float s = 0.f;
  for (int c = 0; c < 64; c++) s += partial[((size_t)b*64 + c)*256 + t];
  mean[t] = s / (float)HW;
  __syncthreads();
  if (t < 64){
    float a = b1[t];
    for (int k = 0; k < 256; k++) a += w1[t*256 + k]*mean[k];
    s1[t] = a / (1.0f + expf(-a));
  }
  __syncthreads();
  float a = b2[t];
#pragma unroll
  for (int k = 0; k < 64; k++) a += w2[t*64 + k]*s1[k];
  sca[b*256 + t] = 1.0f/(1.0f + expf(-a));
}

// ---------------- SE scale + conv2 -> NCHW f32, grid (HW/256, nb) ----------------
__global__ __launch_bounds__(256) void k_conv2(const bf16* __restrict__ h2, const float* __restrict__ sca,
                        const float* __restrict__ w2c, const float* __restrict__ b2c,
                        float* __restrict__ out, int H, int W){
  __shared__ float wsm[64][32];
  __shared__ float scs[256];
  int t = threadIdx.x, b = blockIdx.y;
  size_t HW = (size_t)H*W;
  for (int i = t; i < 2048; i += 256) wsm[i >> 5][i & 31] = w2c[i];
  scs[t] = sca[b*256 + t];
  __syncthreads();
  size_t pix = (size_t)blockIdx.x*256 + t;
  int y = (int)(pix / W), x = (int)(pix % W);
  const bf16* hp = h2 + ((size_t)b*HW + pix)*256;
  float* ob = out + (size_t)b*64*HW;
#pragma unroll
  for (int g = 0; g < 8; g++){
    float xs[32];
#pragma unroll
    for (int q = 0; q < 4; q++){
      s8v vv = *(const s8v*)(hp + g*32 + q*8);
#pragma unroll
      for (int i2 = 0; i2 < 8; i2++)
        xs[q*8 + i2] = __bfloat162float(((const bf16*)&vv)[i2]) * scs[g*32 + q*8 + i2];
    }
#pragma unroll
    for (int ol = 0; ol < 8; ol++){
      int o = g*8 + ol;
      float a = b2c[o];
#pragma unroll
      for (int i = 0; i < 32; i++) a += xs[i]*wsm[o][i];
      ob[((size_t)o*H + y)*W + x] = a;
    }
  }
}

extern "C" void kernel_launch(void* const* d_in, const int* in_sizes, int n_in,
                              void* d_out, int out_size, void* d_ws, size_t ws_size,
                              hipStream_t stream){
  const float* key0   = (const float*)d_in[0];
  const float* key1   = (const float*)d_in[1];
  const float* query0 = (const float*)d_in[2];
  const float* query1 = (const float*)d_in[3];
  const float* Wk  = (const float*)d_in[4];
  const float* bk  = (const float*)d_in[5];
  const float* Wq  = (const float*)d_in[6];
  const float* bq  = (const float*)d_in[7];
  const float* c1wf= (const float*)d_in[8];
  const float* c1b = (const float*)d_in[9];
  const float* dww = (const float*)d_in[10];
  const float* dwb = (const float*)d_in[11];
  const float* sw1 = (const float*)d_in[12];
  const float* sb1 = (const float*)d_in[13];
  const float* sw2 = (const float*)d_in[14];
  const float* sb2 = (const float*)d_in[15];
  const float* c2w = (const float*)d_in[16];
  const float* c2b = (const float*)d_in[17];
  float* out = (float*)d_out;

  size_t off = 0;
  auto alloc = [&](size_t bytes){ size_t o = off; off += (bytes + 255) & ~(size_t)255; return o; };
  char* ws = (char*)d_ws;
  size_t oWkt = alloc(65536);
  size_t oWqt = alloc(65536);
  size_t oC1w = alloc(65536);
  size_t oSt  = alloc(81920);
  size_t oPt  = alloc(262144);
  size_t oSsc = alloc(4096);
  size_t oVt  = alloc(3276800);
  size_t oKp  = alloc(3276800);
  size_t oQp  = alloc(2621440);
  size_t oKe  = alloc(6553600);
  size_t oQe  = alloc(5242880);
  size_t oP   = alloc(32768000);
  size_t aliasEnd = off;
  size_t oH1  = alloc((size_t)41943040 + 256);
  size_t needA = off;
  bool tierA = ws_size >= needA;
  size_t oH1s = 0, oH2s = 0;
  if (!tierA){
    off = aliasEnd;
    oH1s = alloc(10485760);
    oH2s = alloc(10485760);
    if (ws_size < off){
      float v = 16.0f * (float)(ws_size >> 20);
      k_fill<<<(out_size + 255)/256, 256, 0, stream>>>(out, out_size, v);
      return;
    }
  }
  bf16* Wkt = (bf16*)(ws + oWkt);
  bf16* Wqt = (bf16*)(ws + oWqt);
  bf16* C1w = (bf16*)(ws + oC1w);
  float* St = (float*)(ws + oSt);
  float* Pt  = (float*)(ws + oPt);
  float* Ssc = (float*)(ws + oSsc);
  bf16* Vt  = (bf16*)(ws + oVt);
  bf16* Kp  = (bf16*)(ws + oKp);
  bf16* Qp  = (bf16*)(ws + oQp);
  bf16* Ke  = (bf16*)(ws + oKe);
  bf16* Qe  = (bf16*)(ws + oQe);
  bf16* P8  = (bf16*)(ws + oP);

  k_prep<<<384, 256, 0, stream>>>(Wk, Wq, c1wf, Wkt, Wqt, C1w);

  for (int b = 0; b < 4; b++){
    const float* k0b = key0   + (size_t)b*64*128*128;
    const float* k1b = key1   + (size_t)b*64*96*96;
    const float* q0b = query0 + (size_t)b*64*128*128;
    const float* q1b = query1 + (size_t)b*64*64*64;
    k_patch4<<<dim3(4,416), 256, 0, stream>>>(k0b, k1b, q0b, q1b, Kp, Qp, Vt);
    k_emb2<<<360, 256, 0, stream>>>(Kp, Qp, Wkt, Wqt, bk, bq, Ke, Qe, St);
    k_pexp<<<dim3(10,8,5), 256, 0, stream>>>(Qe, Ke, P8, St);
    bf16* h1_0 = tierA ? (bf16*)(ws + oH1) + (size_t)b*16384*256
                       : (bf16*)(ws + oH1s);
    bf16* h1_1 = tierA ? (bf16*)(ws + oH1 + 33554432) + (size_t)b*4096*256
                       : (bf16*)(ws + oH1s + 8388608);
    k_wv<<<1280, 256, 0, stream>>>(P8, Vt, C1w, c1b, St, h1_0, h1_1);
    if (!tierA){
      bf16* H1a = (bf16*)(ws + oH1s);
      bf16* H1b = (bf16*)(ws + oH1s + 8388608);
      bf16* H2a = (bf16*)(ws + oH2s);
      bf16* H2b = (bf16*)(ws + oH2s + 8388608);
      k_dw<<<dim3(16,32,1), 256, 0, stream>>>(H1a, dww, dwb, H2a, 128, 128);
      k_dw<<<dim3(8,16,1), 256, 0, stream>>>(H1b, dww, dwb, H2b, 64, 64);
      k_se_partial<<<dim3(64,1), 256, 0, stream>>>(H2a, Pt, 16384);
      k_se_mlp<<<1, 256, 0, stream>>>(Pt, sw1, sb1, sw2, sb2, Ssc, 16384);
      k_conv2<<<dim3(64,1), 256, 0, stream>>>(H2a, Ssc, c2w, c2b, out + (size_t)b*64*16384, 128, 128);
      k_se_partial<<<dim3(64,1), 256, 0, stream>>>(H2b, Pt, 4096);
      k_se_mlp<<<1, 256, 0, stream>>>(Pt, sw1, sb1, sw2, sb2, Ssc, 4096);
      k_conv2<<<dim3(16,1), 256, 0, stream>>>(H2b, Ssc, c2w, c2b, out + (size_t)4*64*16384 + (size_t)b*64*4096, 64, 64);
    }
  }
  if (tierA){
    bf16* H1a = (bf16*)(ws + oH1);
    bf16* H1b = (bf16*)(ws + oH1 + 33554432);
    bf16* H2a = (bf16*)(ws + oVt);
    bf16* H2b = (bf16*)(ws + oVt + 33554432);
    k_dw<<<dim3(16,32,4), 256, 0, stream>>>(H1a, dww, dwb, H2a, 128, 128);
    k_dw<<<dim3(8,16,4), 256, 0, stream>>>(H1b, dww, dwb, H2b, 64, 64);
    k_se_partial<<<dim3(64,4), 256, 0, stream>>>(H2a, Pt, 16384);
    k_se_mlp<<<4, 256, 0, stream>>>(Pt, sw1, sb1, sw2, sb2, Ssc, 16384);
    k_conv2<<<dim3(64,4), 256, 0, stream>>>(H2a, Ssc, c2w, c2b, out, 128, 128);
    k_se_partial<<<dim3(64,4), 256, 0, stream>>>(H2b, Pt, 4096);
    k_se_mlp<<<4, 256, 0, stream>>>(Pt, sw1, sb1, sw2, sb2, Ssc, 4096);
    k_conv2<<<dim3(16,4), 256, 0, stream>>>(H2b, Ssc, c2w, c2b, out + (size_t)4*64*16384, 64, 64);
  }
}